// Round 11
// baseline (688.789 us; speedup 1.0000x reference)
//
#include <hip/hip_runtime.h>
#include <hip/hip_bf16.h>
#include <math.h>

// CrossCBR R11: padded rows (dummy zero cols) -> unconditional SpMM inner loop
// with direct per-quarter col loads (no shfl/min/cndmask); k_acc fused into
// layer-2 SpMM epilogue; GEMM+LSE fused via per-strip partials (no S matrix).
static constexpr int NUc  = 50000;
static constexpr int NBUc = 20000;
static constexpr int NIc  = 100000;
static constexpr int NILc = 150000;           // UI graph nodes
static constexpr int NBLc = 70000;            // UB graph nodes
// global padded rows: UI [0,150016), UB [150016,220032), BI [220032,240128)
static constexpr int GUB0   = 150016;         // 1172*128
static constexpr int GBI0   = 220032;         // 1719*128
static constexpr int BK_UB0 = 1172;
static constexpr int BK_BI0 = 1719;
static constexpr int NBK    = 1876;
static constexpr int GTOT   = NBK * 128;      // 240128

__device__ __forceinline__ float wredsum(float v) {
  #pragma unroll
  for (int m = 32; m >= 1; m >>= 1) v += __shfl_xor(v, m, 64);
  return v;
}
__device__ __forceinline__ float bf2f(unsigned short h) {
  return __uint_as_float(((unsigned int)h) << 16);
}
__device__ __forceinline__ unsigned short f2bf(float f) {  // RNE
  unsigned int u = __float_as_uint(f);
  return (unsigned short)((u + 0x7FFFu + ((u >> 16) & 1u)) >> 16);
}

// ---------------- bucket counts (all 3 graphs, one launch) ----------------
__global__ void k_bcount_all(const int* __restrict__ ui_u, const int* __restrict__ ui_i,
                             const int* __restrict__ ub_u, const int* __restrict__ ub_b,
                             const int* __restrict__ bi_b,
                             int E_ui, int E_ub, int E_bi, int* __restrict__ bCnt) {
  __shared__ int hist[NBK];
  for (int i = threadIdx.x; i < NBK; i += 256) hist[i] = 0;
  __syncthreads();
  int b = blockIdx.x;
  if (b < 512) {
    int chunk = (E_ui + 511) / 512, c0 = b * chunk, c1 = min(E_ui, c0 + chunk);
    for (int e = c0 + (int)threadIdx.x; e < c1; e += 256) {
      atomicAdd(&hist[ui_u[e] >> 7], 1);
      atomicAdd(&hist[(ui_i[e] + NUc) >> 7], 1);
    }
  } else if (b < 768) {
    int lb = b - 512, chunk = (E_ub + 255) / 256, c0 = lb * chunk, c1 = min(E_ub, c0 + chunk);
    for (int e = c0 + (int)threadIdx.x; e < c1; e += 256) {
      atomicAdd(&hist[(GUB0 + ub_u[e]) >> 7], 1);
      atomicAdd(&hist[(GUB0 + NUc + ub_b[e]) >> 7], 1);
    }
  } else {
    int lb = b - 768, chunk = (E_bi + 255) / 256, c0 = lb * chunk, c1 = min(E_bi, c0 + chunk);
    for (int e = c0 + (int)threadIdx.x; e < c1; e += 256)
      atomicAdd(&hist[(GBI0 + bi_b[e]) >> 7], 1);
  }
  __syncthreads();
  for (int i = threadIdx.x; i < NBK; i += 256)
    if (hist[i]) atomicAdd(&bCnt[i], hist[i]);
}

// exclusive scan of n<=2048 elements, 1 block x 512
__global__ void k_scan2048(const int* __restrict__ in, int n,
                           int* __restrict__ outBase, int* __restrict__ outCur) {
  __shared__ int sh[512];
  int t = threadIdx.x, i0 = 4 * t;
  int v0 = (i0 < n) ? in[i0] : 0;
  int v1 = (i0 + 1 < n) ? in[i0 + 1] : 0;
  int v2 = (i0 + 2 < n) ? in[i0 + 2] : 0;
  int v3 = (i0 + 3 < n) ? in[i0 + 3] : 0;
  int ts = v0 + v1 + v2 + v3;
  sh[t] = ts;
  __syncthreads();
  for (int o = 1; o < 512; o <<= 1) {
    int x = (t >= o) ? sh[t - o] : 0;
    __syncthreads();
    sh[t] += x;
    __syncthreads();
  }
  int ex = sh[t] - ts;
  if (i0 < n)     { outBase[i0] = ex;                    outCur[i0] = ex; }
  if (i0 + 1 < n) { outBase[i0 + 1] = ex + v0;           outCur[i0 + 1] = ex + v0; }
  if (i0 + 2 < n) { outBase[i0 + 2] = ex + v0 + v1;      outCur[i0 + 2] = ex + v0 + v1; }
  if (i0 + 3 < n) { outBase[i0 + 3] = ex + v0 + v1 + v2; outCur[i0 + 3] = ex + v0 + v1 + v2; }
  if (t == 511) outBase[n] = sh[511];
}

// ---------------- bin all edges -> bucket-sorted (row,col) pairs ----------------
__global__ void k_bin_all(const int* __restrict__ ui_u, const int* __restrict__ ui_i,
                          const int* __restrict__ ub_u, const int* __restrict__ ub_b,
                          const int* __restrict__ bi_b, const int* __restrict__ bi_i,
                          int E_ui, int E_ub, int E_bi,
                          int* __restrict__ bCur, int2* __restrict__ binned) {
  __shared__ int hist[NBK];
  __shared__ int base[NBK];
  for (int i = threadIdx.x; i < NBK; i += 256) hist[i] = 0;
  __syncthreads();
  int b = blockIdx.x;
  int c0, c1, seg;
  if (b < 512)      { seg = 0; int ch = (E_ui + 511) / 512; c0 = b * ch; c1 = min(E_ui, c0 + ch); }
  else if (b < 768) { seg = 1; int ch = (E_ub + 255) / 256; c0 = (b - 512) * ch; c1 = min(E_ub, c0 + ch); }
  else              { seg = 2; int ch = (E_bi + 255) / 256; c0 = (b - 768) * ch; c1 = min(E_bi, c0 + ch); }
  for (int e = c0 + (int)threadIdx.x; e < c1; e += 256) {
    if (seg == 0) {
      atomicAdd(&hist[ui_u[e] >> 7], 1);
      atomicAdd(&hist[(ui_i[e] + NUc) >> 7], 1);
    } else if (seg == 1) {
      atomicAdd(&hist[(GUB0 + ub_u[e]) >> 7], 1);
      atomicAdd(&hist[(GUB0 + NUc + ub_b[e]) >> 7], 1);
    } else {
      atomicAdd(&hist[(GBI0 + bi_b[e]) >> 7], 1);
    }
  }
  __syncthreads();
  for (int i = threadIdx.x; i < NBK; i += 256) {
    int h = hist[i];
    base[i] = h ? atomicAdd(&bCur[i], h) : 0;
    hist[i] = 0;
  }
  __syncthreads();
  for (int e = c0 + (int)threadIdx.x; e < c1; e += 256) {
    if (seg == 0) {
      int u = ui_u[e], x = ui_i[e] + NUc;
      int b1 = u >> 7; binned[base[b1] + atomicAdd(&hist[b1], 1)] = make_int2(u, x);
      int b2 = x >> 7; binned[base[b2] + atomicAdd(&hist[b2], 1)] = make_int2(x, u);
    } else if (seg == 1) {
      int ul = ub_u[e], bl = NUc + ub_b[e];
      int r1 = GUB0 + ul, r2 = GUB0 + bl;
      int b1 = r1 >> 7; binned[base[b1] + atomicAdd(&hist[b1], 1)] = make_int2(r1, bl);
      int b2 = r2 >> 7; binned[base[b2] + atomicAdd(&hist[b2], 1)] = make_int2(r2, ul);
    } else {
      int r = GBI0 + bi_b[e];
      int b1 = r >> 7; binned[base[b1] + atomicAdd(&hist[b1], 1)] = make_int2(r, bi_i[e]);
    }
  }
}

// per-row degree (covers all padded rows)
__global__ void k_rowhist_all(const int2* __restrict__ binned, const int* __restrict__ bBase,
                              int* __restrict__ cnt) {
  __shared__ int hist[128];
  int bk = blockIdx.x, rowbase = bk << 7;
  int s = bBase[bk], e = bBase[bk + 1];
  if (threadIdx.x < 128) hist[threadIdx.x] = 0;
  __syncthreads();
  for (int i = s + (int)threadIdx.x; i < e; i += 256)
    atomicAdd(&hist[binned[i].x & 127], 1);
  __syncthreads();
  if (threadIdx.x < 128) cnt[rowbase + (int)threadIdx.x] = hist[threadIdx.x];
}

// hierarchical scan of PADDED counts: pcnt = (cnt+3)&~3
__global__ void k_scan_block_pad(const int* __restrict__ in, int n, int* __restrict__ out,
                                 int* __restrict__ bsum) {
  __shared__ int sh[256];
  int t = threadIdx.x;
  long base = (long)blockIdx.x * 1024 + (long)t * 4;
  int v0 = (base     < n) ? ((in[base]     + 3) & ~3) : 0;
  int v1 = (base + 1 < n) ? ((in[base + 1] + 3) & ~3) : 0;
  int v2 = (base + 2 < n) ? ((in[base + 2] + 3) & ~3) : 0;
  int v3 = (base + 3 < n) ? ((in[base + 3] + 3) & ~3) : 0;
  int tsum = v0 + v1 + v2 + v3;
  sh[t] = tsum;
  __syncthreads();
  for (int o = 1; o < 256; o <<= 1) {
    int x = (t >= o) ? sh[t - o] : 0;
    __syncthreads();
    sh[t] += x;
    __syncthreads();
  }
  int excl = sh[t] - tsum;
  if (t == 255) bsum[blockIdx.x] = sh[255];
  if (base     < n) out[base]     = excl;
  if (base + 1 < n) out[base + 1] = excl + v0;
  if (base + 2 < n) out[base + 2] = excl + v0 + v1;
  if (base + 3 < n) out[base + 3] = excl + v0 + v1 + v2;
}

__global__ void k_scan_bsum(int* __restrict__ bsum, int nb) {  // nb <= 256
  __shared__ int sh[256];
  int t = threadIdx.x;
  int v = (t < nb) ? bsum[t] : 0;
  sh[t] = v;
  __syncthreads();
  for (int o = 1; o < 256; o <<= 1) {
    int x = (t >= o) ? sh[t - o] : 0;
    __syncthreads();
    sh[t] += x;
    __syncthreads();
  }
  if (t < nb) bsum[t] = sh[t] - v;
}

__global__ void k_scan_add(int* __restrict__ out, int n, const int* __restrict__ bsum) {
  long i = (long)blockIdx.x * 256 + threadIdx.x;
  if (i < n) out[i] += bsum[i >> 10];
}

// per-bucket CSR fill + tail padding with zero-row dummy cols
__global__ void k_csrfill_all(const int2* __restrict__ binned, const int* __restrict__ bBase,
                              const int* __restrict__ rp, int* __restrict__ colv) {
  __shared__ int cur[128];
  int bk = blockIdx.x, rowbase = bk << 7;
  int xb, zpad;
  if (bk < BK_UB0)      { xb = 0;    zpad = NILc; }          // X zero row
  else if (bk < BK_BI0) { xb = GUB0; zpad = GUB0 + NBLc; }   // X zero row (UB pad)
  else                  { xb = 0;    zpad = NIc; }           // MACC zero row
  int s = bBase[bk], e = bBase[bk + 1];
  if (threadIdx.x < 128) cur[threadIdx.x] = rp[rowbase + (int)threadIdx.x];
  __syncthreads();
  for (int i = s + (int)threadIdx.x; i < e; i += 256) {
    int2 rc = binned[i];
    int pos = atomicAdd(&cur[rc.x & 127], 1);
    colv[pos] = xb + rc.y;
  }
  __syncthreads();
  if (threadIdx.x < 128) {
    int r = rowbase + (int)threadIdx.x;
    int end = rp[r + 1];
    for (int k = cur[threadIdx.x]; k < end; k++) colv[k] = zpad;
  }
}

// X[g] = f2bf(feat[g] * dinv[g]) over [0, GBI0); padding rows -> 0
__global__ void k_prescale_all(const int* __restrict__ cnt, const float* __restrict__ userF,
                               const float* __restrict__ bundF, const float* __restrict__ itemF,
                               unsigned short* __restrict__ X) {
  long idx = (long)blockIdx.x * 256 + threadIdx.x;
  if (idx >= (long)GBI0 * 64) return;
  int g = (int)(idx >> 6), d = (int)(idx & 63);
  float v = 0.0f;
  if (g < NILc) v = (g < NUc) ? userF[(long)g * 64 + d] : itemF[(long)(g - NUc) * 64 + d];
  else if (g >= GUB0 && g < GUB0 + NBLc) {
    int l = g - GUB0;
    v = (l < NUc) ? userF[(long)l * 64 + d] : bundF[(long)(l - NUc) * 64 + d];
  }
  float dinv = 1.0f / (sqrtf((float)cnt[g]) + 1e-8f);
  X[idx] = f2bf(v * dinv);
}

// ---------------- layer-1 SpMM: unconditional padded loop ----------------
__global__ void k_spmm_l1(const int* __restrict__ rp, const int* __restrict__ cnt,
                          const int* __restrict__ col, const unsigned short* __restrict__ X,
                          unsigned short* __restrict__ M1, float* __restrict__ INV1, int n) {
  int row = blockIdx.x * 4 + (threadIdx.x >> 6);
  if (row >= n) return;
  int lane = threadIdx.x & 63, q = lane >> 4, p = lane & 15;
  int s = rp[row], e = rp[row + 1];
  const uint2* Xp = (const uint2*)X + p;
  float a0 = 0.f, a1 = 0.f, a2 = 0.f, a3 = 0.f;
  for (int eo = s + q; eo < e; eo += 4) {
    int c = col[eo];
    uint2 v = Xp[(size_t)c << 4];
    a0 += __uint_as_float(v.x << 16);
    a1 += __uint_as_float(v.x & 0xFFFF0000u);
    a2 += __uint_as_float(v.y << 16);
    a3 += __uint_as_float(v.y & 0xFFFF0000u);
  }
  a0 += __shfl_xor(a0, 32, 64); a1 += __shfl_xor(a1, 32, 64);
  a2 += __shfl_xor(a2, 32, 64); a3 += __shfl_xor(a3, 32, 64);
  a0 += __shfl_xor(a0, 16, 64); a1 += __shfl_xor(a1, 16, 64);
  a2 += __shfl_xor(a2, 16, 64); a3 += __shfl_xor(a3, 16, 64);
  float dinv = 1.0f / (sqrtf((float)cnt[row]) + 1e-8f);
  float f = dinv * 0.5f;
  float r0 = a0 * f, r1 = a1 * f, r2 = a2 * f, r3 = a3 * f;
  float ss = r0 * r0 + r1 * r1 + r2 * r2 + r3 * r3;
  ss += __shfl_xor(ss, 8, 64); ss += __shfl_xor(ss, 4, 64);
  ss += __shfl_xor(ss, 2, 64); ss += __shfl_xor(ss, 1, 64);
  if (q == 0) {
    uint2 m;
    m.x = (unsigned int)f2bf(r0 * dinv) | ((unsigned int)f2bf(r1 * dinv) << 16);
    m.y = (unsigned int)f2bf(r2 * dinv) | ((unsigned int)f2bf(r3 * dinv) << 16);
    *(uint2*)(M1 + (size_t)row * 64 + p * 4) = m;
    if (p == 0) INV1[row] = 1.0f / fmaxf(sqrtf(ss), 1e-12f);
  }
}

// ---------------- layer-2 SpMM with fused acc: writes ACC (+item mirror) ----
__global__ void k_spmm_l2acc(const int* __restrict__ rp, const int* __restrict__ cnt,
                             const int* __restrict__ col, const unsigned short* __restrict__ M1,
                             const float* __restrict__ INV1,
                             const float* __restrict__ userF, const float* __restrict__ bundF,
                             const float* __restrict__ itemF,
                             float* __restrict__ ACC, unsigned short* __restrict__ MACC, int n) {
  int g = blockIdx.x * 4 + (threadIdx.x >> 6);
  if (g >= n) return;
  int ail, baseRow;
  const float* baseT;
  bool isItem = false;
  if (g < NILc) {
    ail = g;
    if (g < NUc) { baseT = userF; baseRow = g; }
    else { baseT = itemF; baseRow = g - NUc; isItem = true; }
  } else if (g >= GUB0 && g < GUB0 + NBLc) {
    int l = g - GUB0;
    ail = NILc + l;
    if (l < NUc) { baseT = userF; baseRow = l; }
    else { baseT = bundF; baseRow = l - NUc; }
  } else {
    return;  // padding row
  }
  int lane = threadIdx.x & 63, q = lane >> 4, p = lane & 15;
  int s = rp[g], e = rp[g + 1];
  const uint2* Xp = (const uint2*)M1 + p;
  float a0 = 0.f, a1 = 0.f, a2 = 0.f, a3 = 0.f;
  for (int eo = s + q; eo < e; eo += 4) {
    int c = col[eo];
    uint2 v = Xp[(size_t)c << 4];
    a0 += __uint_as_float(v.x << 16);
    a1 += __uint_as_float(v.x & 0xFFFF0000u);
    a2 += __uint_as_float(v.y << 16);
    a3 += __uint_as_float(v.y & 0xFFFF0000u);
  }
  a0 += __shfl_xor(a0, 32, 64); a1 += __shfl_xor(a1, 32, 64);
  a2 += __shfl_xor(a2, 32, 64); a3 += __shfl_xor(a3, 32, 64);
  a0 += __shfl_xor(a0, 16, 64); a1 += __shfl_xor(a1, 16, 64);
  a2 += __shfl_xor(a2, 16, 64); a3 += __shfl_xor(a3, 16, 64);
  float rs = sqrtf((float)cnt[g]) + 1e-8f;   // 1/dinv
  float dinv = 1.0f / rs;
  float f = dinv * (1.0f / 3.0f);
  float r0 = a0 * f, r1 = a1 * f, r2 = a2 * f, r3 = a3 * f;
  float ss = r0 * r0 + r1 * r1 + r2 * r2 + r3 * r3;
  ss += __shfl_xor(ss, 8, 64); ss += __shfl_xor(ss, 4, 64);
  ss += __shfl_xor(ss, 2, 64); ss += __shfl_xor(ss, 1, 64);
  if (q == 0) {
    float inv2 = 1.0f / fmaxf(sqrtf(ss), 1e-12f);
    float s1 = rs * INV1[g];
    uint2 m1v = Xp[(size_t)g << 4];
    float4 b4 = *(const float4*)(baseT + (long)baseRow * 64 + p * 4);
    float o0 = b4.x + __uint_as_float(m1v.x << 16) * s1 + r0 * inv2;
    float o1 = b4.y + __uint_as_float(m1v.x & 0xFFFF0000u) * s1 + r1 * inv2;
    float o2 = b4.z + __uint_as_float(m1v.y << 16) * s1 + r2 * inv2;
    float o3 = b4.w + __uint_as_float(m1v.y & 0xFFFF0000u) * s1 + r3 * inv2;
    *(float4*)(ACC + (size_t)ail * 64 + p * 4) = make_float4(o0, o1, o2, o3);
    if (isItem) {
      uint2 mm;
      mm.x = (unsigned int)f2bf(o0) | ((unsigned int)f2bf(o1) << 16);
      mm.y = (unsigned int)f2bf(o2) | ((unsigned int)f2bf(o3) << 16);
      *(uint2*)(MACC + (size_t)baseRow * 64 + p * 4) = mm;
    }
  }
}

// bundle mean-agg (BI rows; cols index MACC, dummy = zeroed row NIc)
__global__ void k_agg_g(const int* __restrict__ rp, const int* __restrict__ cnt,
                        const int* __restrict__ col, const unsigned short* __restrict__ MACC,
                        float* __restrict__ ILB, int n) {
  int rl = blockIdx.x * 4 + (threadIdx.x >> 6);
  if (rl >= n) return;
  int row = GBI0 + rl;
  int lane = threadIdx.x & 63, q = lane >> 4, p = lane & 15;
  int s = rp[row], e = rp[row + 1];
  const uint2* Xp = (const uint2*)MACC + p;
  float a0 = 0.f, a1 = 0.f, a2 = 0.f, a3 = 0.f;
  for (int eo = s + q; eo < e; eo += 4) {
    int c = col[eo];
    uint2 v = Xp[(size_t)c << 4];
    a0 += __uint_as_float(v.x << 16);
    a1 += __uint_as_float(v.x & 0xFFFF0000u);
    a2 += __uint_as_float(v.y << 16);
    a3 += __uint_as_float(v.y & 0xFFFF0000u);
  }
  a0 += __shfl_xor(a0, 32, 64); a1 += __shfl_xor(a1, 32, 64);
  a2 += __shfl_xor(a2, 32, 64); a3 += __shfl_xor(a3, 32, 64);
  a0 += __shfl_xor(a0, 16, 64); a1 += __shfl_xor(a1, 16, 64);
  a2 += __shfl_xor(a2, 16, 64); a3 += __shfl_xor(a3, 16, 64);
  if (q == 0) {
    float w = 1.0f / ((float)cnt[row] + 1e-8f);
    *(float4*)(ILB + (size_t)rl * 64 + p * 4) = make_float4(a0 * w, a1 * w, a2 * w, a3 * w);
  }
}

__global__ void k_gather_all(const int* __restrict__ users, const int* __restrict__ bundles,
                             const float* __restrict__ ACC, const float* __restrict__ ILB, int B,
                             float* __restrict__ ILu, float* __restrict__ BLu,
                             float* __restrict__ ILb2, float* __restrict__ BLb2) {
  long i = (long)blockIdx.x * 256 + threadIdx.x;
  if (i >= (long)6 * B * 64) return;
  int r = (int)(i >> 6), d = (int)(i & 63);
  if (r < B) ILu[(long)r * 64 + d] = ACC[(long)users[r] * 64 + d];
  else if (r < 2 * B) { int rr = r - B; BLu[(long)rr * 64 + d] = ACC[(long)(NILc + users[rr]) * 64 + d]; }
  else if (r < 4 * B) { int rr = r - 2 * B; ILb2[(long)rr * 64 + d] = ILB[(long)bundles[rr] * 64 + d]; }
  else { int rr = r - 4 * B; BLb2[(long)rr * 64 + d] = ACC[(long)(NILc + NUc + bundles[rr]) * 64 + d]; }
}

__global__ void k_normalize4(const float* __restrict__ s0, const float* __restrict__ s1,
                             const float* __restrict__ s2, const float* __restrict__ s3,
                             float* __restrict__ d0, float* __restrict__ d1,
                             float* __restrict__ d2, float* __restrict__ d3, int B) {
  int row = blockIdx.x * 4 + (threadIdx.x >> 6);
  int lane = threadIdx.x & 63;
  if (row >= 4 * B) return;
  int which = row / B, r = row - which * B;
  const float* src; float* dst; int stride;
  if (which == 0)      { src = s0; dst = d0; stride = 64; }
  else if (which == 1) { src = s1; dst = d1; stride = 64; }
  else if (which == 2) { src = s2; dst = d2; stride = 128; }
  else                 { src = s3; dst = d3; stride = 128; }
  float v = src[(long)r * stride + lane];
  float ss = wredsum(v * v);
  dst[(long)r * 64 + lane] = v * (1.0f / fmaxf(sqrtf(ss), 1e-12f));
}

__global__ void k_bpr(const float* __restrict__ ILu, const float* __restrict__ ILb2,
                      const float* __restrict__ BLu, const float* __restrict__ BLb2,
                      int B, float* __restrict__ out) {
  int row = blockIdx.x * 4 + (threadIdx.x >> 6);
  int lane = threadIdx.x & 63;
  if (row >= B) return;
  float t = ILu[(long)row * 64 + lane] *
              (ILb2[(long)(2 * row) * 64 + lane] - ILb2[(long)(2 * row + 1) * 64 + lane]) +
            BLu[(long)row * 64 + lane] *
              (BLb2[(long)(2 * row) * 64 + lane] - BLb2[(long)(2 * row + 1) * 64 + lane]);
  float x = wredsum(t);
  if (lane == 0) {
    float ls = -(fmaxf(-x, 0.0f) + log1pf(expf(-fabsf(x))));
    unsafeAtomicAdd(&out[0], -ls / (float)B);
  }
}

// ---------------- fused InfoNCE GEMM + per-strip LSE partials ----------------
// grid (N/128, N/128, 2); writes Pm/Ps[z][row][bx] and Diag[z][row].
__global__ void k_gemm_lse(const float* __restrict__ P1, const float* __restrict__ A1,
                           const float* __restrict__ P2, const float* __restrict__ A2,
                           float* __restrict__ Pm, float* __restrict__ Ps,
                           float* __restrict__ Diag, int N, float scale) {
  __shared__ float PsS[64][129];
  __shared__ float AsS[64][129];
  constexpr float L2E = 1.44269504f;
  const float* P = blockIdx.z ? P2 : P1;
  const float* A = blockIdx.z ? A2 : A1;
  int bi0 = blockIdx.y * 128, bj0 = blockIdx.x * 128;
  int t = threadIdx.x;
  #pragma unroll
  for (int sct = 0; sct < 8; sct++) {
    int idx4 = t + sct * 256;
    int r = idx4 >> 4, k = (idx4 & 15) << 2;
    int pr = min(bi0 + r, N - 1);
    int ar = min(bj0 + r, N - 1);
    float4 v = *(const float4*)(P + (long)pr * 64 + k);
    PsS[k][r] = v.x; PsS[k + 1][r] = v.y; PsS[k + 2][r] = v.z; PsS[k + 3][r] = v.w;
    float4 w = *(const float4*)(A + (long)ar * 64 + k);
    AsS[k][r] = w.x; AsS[k + 1][r] = w.y; AsS[k + 2][r] = w.z; AsS[k + 3][r] = w.w;
  }
  __syncthreads();
  int tx = t & 15, ty = t >> 4;
  float acc[8][8];
  #pragma unroll
  for (int i = 0; i < 8; i++)
    #pragma unroll
    for (int j = 0; j < 8; j++) acc[i][j] = 0.0f;
  #pragma unroll 4
  for (int k = 0; k < 64; k++) {
    float a[8], b[8];
    #pragma unroll
    for (int i = 0; i < 8; i++) a[i] = PsS[k][ty * 8 + i];
    #pragma unroll
    for (int j = 0; j < 8; j++) b[j] = AsS[k][tx + 16 * j];
    #pragma unroll
    for (int i = 0; i < 8; i++)
      #pragma unroll
      for (int j = 0; j < 8; j++) acc[i][j] = fmaf(a[i], b[j], acc[i][j]);
  }
  __syncthreads();  // done with tile LDS; reuse for reduction
  float2* red = (float2*)&PsS[0][0];
  for (int i = 0; i < 8; i++) {
    float xs[8], tm = -1e30f;
    #pragma unroll
    for (int j = 0; j < 8; j++) { xs[j] = acc[i][j] * scale; tm = fmaxf(tm, xs[j]); }
    float tsum = 0.f;
    #pragma unroll
    for (int j = 0; j < 8; j++) tsum += exp2f((xs[j] - tm) * L2E);
    red[ty * 16 + tx] = make_float2(tm, tsum);
    // diag element (block on diagonal): col tx+16j == row ty*8+i
    int lc = ty * 8 + i;
    if (blockIdx.x == blockIdx.y && tx == (lc & 15)) {
      int j = lc >> 4;
      Diag[(size_t)blockIdx.z * N + bi0 + lc] = acc[i][j] * scale;
    }
    __syncthreads();
    if (tx == 0) {
      float M = -1e30f;
      for (int k2 = 0; k2 < 16; k2++) M = fmaxf(M, red[ty * 16 + k2].x);
      float S = 0.f;
      for (int k2 = 0; k2 < 16; k2++) {
        float2 pr = red[ty * 16 + k2];
        S += pr.y * exp2f((pr.x - M) * L2E);
      }
      size_t o = ((size_t)blockIdx.z * N + bi0 + ty * 8 + i) * 16 + blockIdx.x;
      Pm[o] = M; Ps[o] = S;
    }
    __syncthreads();
  }
}

// final LSE reduce over 16 strips per (z,row)
__global__ void k_lse_final(const float* __restrict__ Pm, const float* __restrict__ Ps,
                            const float* __restrict__ Diag, int N, float coeff,
                            float* __restrict__ out) {
  constexpr float L2E = 1.44269504f;
  int idx = blockIdx.x * 4 + (threadIdx.x >> 6);
  if (idx >= 2 * N) return;
  int z = idx >= N ? 1 : 0, r = idx - z * N;
  int lane = threadIdx.x & 63;
  float m = -1e30f, s = 0.f;
  if (lane < 16) {
    size_t o = ((size_t)z * N + r) * 16 + lane;
    m = Pm[o]; s = Ps[o];
  }
  #pragma unroll
  for (int o = 8; o >= 1; o >>= 1) {
    float m2 = __shfl_xor(m, o, 64), s2 = __shfl_xor(s, o, 64);
    float M = fmaxf(m, m2);
    s = s * exp2f((m - M) * L2E) + s2 * exp2f((m2 - M) * L2E);
    m = M;
  }
  if (lane == 0) {
    float lse = m + log2f(s) * 0.69314718f;
    unsafeAtomicAdd(&out[1], -(Diag[(size_t)z * N + r] - lse) * coeff);
  }
}

extern "C" void kernel_launch(void* const* d_in, const int* in_sizes, int n_in,
                              void* d_out, int out_size, void* d_ws, size_t ws_size,
                              hipStream_t stream) {
  const int* users   = (const int*)d_in[0];
  const int* bundles = (const int*)d_in[1];
  const int* ui_u    = (const int*)d_in[2];
  const int* ui_i    = (const int*)d_in[3];
  const int* ub_u    = (const int*)d_in[4];
  const int* ub_b    = (const int*)d_in[5];
  const int* bi_b    = (const int*)d_in[6];
  const int* bi_i    = (const int*)d_in[7];
  const float* userF = (const float*)d_in[8];
  const float* bundF = (const float*)d_in[9];
  const float* itemF = (const float*)d_in[10];
  float* out = (float*)d_out;

  const int B    = in_sizes[0];
  const int E_ui = in_sizes[2];
  const int E_ub = in_sizes[4];
  const int E_bi = in_sizes[6];
  const long E_all = 2L * E_ui + 2L * E_ub + E_bi;

  float* ws = (float*)d_ws;
  size_t off = 0;
  auto alloc = [&](size_t nfloat) -> float* {
    float* p = ws + off;
    off += (nfloat + 63) & ~(size_t)63;
    return p;
  };
  float* ACC = alloc((size_t)(NILc + NBLc) * 64);                 // 56.3 MB
  unsigned short* X  = (unsigned short*)alloc((size_t)GBI0 * 32); // 28.2 MB
  unsigned short* M1 = (unsigned short*)alloc((size_t)GBI0 * 32); // 28.2 MB
  int2* binned = (int2*)alloc((size_t)E_all * 2);                 // 48 MB
  int* colv  = (int*)alloc((size_t)E_all + 3 * (size_t)GTOT + 64);
  int* rp    = (int*)alloc(GTOT + 1);
  int* cnt   = (int*)alloc(GTOT + 1);
  float* INV1 = alloc(GTOT);
  float* ILB  = alloc((size_t)NBUc * 64);
  float* ILu  = alloc((size_t)B * 64);
  float* BLu  = alloc((size_t)B * 64);
  float* ILb2 = alloc((size_t)B * 128);
  float* BLb2 = alloc((size_t)B * 128);
  float* PN1  = alloc((size_t)B * 64);
  float* AN1  = alloc((size_t)B * 64);
  float* PN2  = alloc((size_t)B * 64);
  float* AN2  = alloc((size_t)B * 64);
  float* Pm   = alloc((size_t)2 * B * 16);
  float* Ps   = alloc((size_t)2 * B * 16);
  float* Diag = alloc((size_t)2 * B);
  int* bCnt  = (int*)alloc(2049);
  int* bBase = (int*)alloc(2049);
  int* bCur  = (int*)alloc(2049);
  int* bsum  = (int*)alloc(256);
  (void)ws_size; (void)n_in; (void)out_size;

  // MACC (bf16 item mirror, NIc+1 rows incl. zero dummy) overlays binned
  // (dead after csrfill). 12.9 MB < 48 MB.
  unsigned short* MACC = (unsigned short*)binned;

  // ---- unified bucketed binning + padded CSR (all 3 graphs) ----
  hipMemsetAsync(bCnt, 0, sizeof(int) * NBK, stream);
  k_bcount_all<<<1024, 256, 0, stream>>>(ui_u, ui_i, ub_u, ub_b, bi_b, E_ui, E_ub, E_bi, bCnt);
  k_scan2048<<<1, 512, 0, stream>>>(bCnt, NBK, bBase, bCur);
  k_bin_all<<<1024, 256, 0, stream>>>(ui_u, ui_i, ub_u, ub_b, bi_b, bi_i,
                                      E_ui, E_ub, E_bi, bCur, binned);
  hipMemsetAsync(cnt, 0, sizeof(int) * (GTOT + 1), stream);
  k_rowhist_all<<<NBK, 256, 0, stream>>>(binned, bBase, cnt);
  {
    int scan_n = GTOT + 1;
    int nb1 = (scan_n + 1023) / 1024;
    k_scan_block_pad<<<nb1, 256, 0, stream>>>(cnt, scan_n, rp, bsum);
    k_scan_bsum<<<1, 256, 0, stream>>>(bsum, nb1);
    k_scan_add<<<(scan_n + 255) / 256, 256, 0, stream>>>(rp, scan_n, bsum);
  }
  k_csrfill_all<<<NBK, 256, 0, stream>>>(binned, bBase, rp, colv);

  // ---- propagate (UI + UB merged per layer); acc fused into layer 2 ----
  k_prescale_all<<<(int)(((long)GBI0 * 64 + 255) / 256), 256, 0, stream>>>(cnt, userF, bundF,
                                                                           itemF, X);
  k_spmm_l1<<<(GBI0 + 3) / 4, 256, 0, stream>>>(rp, cnt, colv, X, M1, INV1, GBI0);
  // zero MACC dummy row (index NIc) before l2acc writes item mirror
  hipMemsetAsync(MACC + (size_t)NIc * 64, 0, 128, stream);
  k_spmm_l2acc<<<(GBI0 + 3) / 4, 256, 0, stream>>>(rp, cnt, colv, M1, INV1,
                                                   userF, bundF, itemF, ACC, MACC, GBI0);
  k_agg_g<<<(NBUc + 3) / 4, 256, 0, stream>>>(rp, cnt, colv, MACC, ILB, NBUc);
  k_gather_all<<<(int)(((long)6 * B * 64 + 255) / 256), 256, 0, stream>>>(
      users, bundles, ACC, ILB, B, ILu, BLu, ILb2, BLb2);

  // ---- losses ----
  hipMemsetAsync(out, 0, 2 * sizeof(float), stream);
  k_bpr<<<(B + 3) / 4, 256, 0, stream>>>(ILu, ILb2, BLu, BLb2, B, out);
  k_normalize4<<<(4 * B + 3) / 4, 256, 0, stream>>>(ILu, BLu, ILb2, BLb2, PN1, AN1, PN2, AN2, B);
  dim3 gg((B + 127) / 128, (B + 127) / 128, 2);
  k_gemm_lse<<<gg, 256, 0, stream>>>(PN1, AN1, PN2, AN2, Pm, Ps, Diag, B, 4.0f);  // 1/C_TEMP
  k_lse_final<<<(2 * B + 3) / 4, 256, 0, stream>>>(Pm, Ps, Diag, B, 0.5f / (float)B, out);
}

// Round 12
// 575.690 us; speedup vs baseline: 1.1965x; 1.1965x over previous
//
#include <hip/hip_runtime.h>
#include <hip/hip_bf16.h>
#include <math.h>

// CrossCBR R12: R10 structure (separate acc/gemm/lse — R11's fusions regressed)
// + rows padded to multiple of 16 with dummy zero-row cols so the SpMM inner
// loop runs unconditional with 4 independent gathers in flight (MLP fix).
static constexpr int NUc  = 50000;
static constexpr int NBUc = 20000;
static constexpr int NIc  = 100000;
static constexpr int NILc = 150000;           // UI graph nodes
static constexpr int NBLc = 70000;            // UB graph nodes
// global padded rows: UI [0,150016), UB [150016,220032), BI [220032,240128)
static constexpr int GUB0   = 150016;         // 1172*128
static constexpr int GBI0   = 220032;         // 1719*128
static constexpr int BK_UB0 = 1172;
static constexpr int BK_BI0 = 1719;
static constexpr int NBK    = 1876;
static constexpr int GTOT   = NBK * 128;      // 240128

__device__ __forceinline__ float wredsum(float v) {
  #pragma unroll
  for (int m = 32; m >= 1; m >>= 1) v += __shfl_xor(v, m, 64);
  return v;
}
__device__ __forceinline__ float bf2f(unsigned short h) {
  return __uint_as_float(((unsigned int)h) << 16);
}
__device__ __forceinline__ unsigned short f2bf(float f) {  // RNE
  unsigned int u = __float_as_uint(f);
  return (unsigned short)((u + 0x7FFFu + ((u >> 16) & 1u)) >> 16);
}

// ---------------- bucket counts (all 3 graphs, one launch) ----------------
__global__ void k_bcount_all(const int* __restrict__ ui_u, const int* __restrict__ ui_i,
                             const int* __restrict__ ub_u, const int* __restrict__ ub_b,
                             const int* __restrict__ bi_b,
                             int E_ui, int E_ub, int E_bi, int* __restrict__ bCnt) {
  __shared__ int hist[NBK];
  for (int i = threadIdx.x; i < NBK; i += 256) hist[i] = 0;
  __syncthreads();
  int b = blockIdx.x;
  if (b < 512) {
    int chunk = (E_ui + 511) / 512, c0 = b * chunk, c1 = min(E_ui, c0 + chunk);
    for (int e = c0 + (int)threadIdx.x; e < c1; e += 256) {
      atomicAdd(&hist[ui_u[e] >> 7], 1);
      atomicAdd(&hist[(ui_i[e] + NUc) >> 7], 1);
    }
  } else if (b < 768) {
    int lb = b - 512, chunk = (E_ub + 255) / 256, c0 = lb * chunk, c1 = min(E_ub, c0 + chunk);
    for (int e = c0 + (int)threadIdx.x; e < c1; e += 256) {
      atomicAdd(&hist[(GUB0 + ub_u[e]) >> 7], 1);
      atomicAdd(&hist[(GUB0 + NUc + ub_b[e]) >> 7], 1);
    }
  } else {
    int lb = b - 768, chunk = (E_bi + 255) / 256, c0 = lb * chunk, c1 = min(E_bi, c0 + chunk);
    for (int e = c0 + (int)threadIdx.x; e < c1; e += 256)
      atomicAdd(&hist[(GBI0 + bi_b[e]) >> 7], 1);
  }
  __syncthreads();
  for (int i = threadIdx.x; i < NBK; i += 256)
    if (hist[i]) atomicAdd(&bCnt[i], hist[i]);
}

// exclusive scan of n<=2048 elements, 1 block x 512
__global__ void k_scan2048(const int* __restrict__ in, int n,
                           int* __restrict__ outBase, int* __restrict__ outCur) {
  __shared__ int sh[512];
  int t = threadIdx.x, i0 = 4 * t;
  int v0 = (i0 < n) ? in[i0] : 0;
  int v1 = (i0 + 1 < n) ? in[i0 + 1] : 0;
  int v2 = (i0 + 2 < n) ? in[i0 + 2] : 0;
  int v3 = (i0 + 3 < n) ? in[i0 + 3] : 0;
  int ts = v0 + v1 + v2 + v3;
  sh[t] = ts;
  __syncthreads();
  for (int o = 1; o < 512; o <<= 1) {
    int x = (t >= o) ? sh[t - o] : 0;
    __syncthreads();
    sh[t] += x;
    __syncthreads();
  }
  int ex = sh[t] - ts;
  if (i0 < n)     { outBase[i0] = ex;                    outCur[i0] = ex; }
  if (i0 + 1 < n) { outBase[i0 + 1] = ex + v0;           outCur[i0 + 1] = ex + v0; }
  if (i0 + 2 < n) { outBase[i0 + 2] = ex + v0 + v1;      outCur[i0 + 2] = ex + v0 + v1; }
  if (i0 + 3 < n) { outBase[i0 + 3] = ex + v0 + v1 + v2; outCur[i0 + 3] = ex + v0 + v1 + v2; }
  if (t == 511) outBase[n] = sh[511];
}

// ---------------- bin all edges -> bucket-sorted (row,col) pairs ----------------
__global__ void k_bin_all(const int* __restrict__ ui_u, const int* __restrict__ ui_i,
                          const int* __restrict__ ub_u, const int* __restrict__ ub_b,
                          const int* __restrict__ bi_b, const int* __restrict__ bi_i,
                          int E_ui, int E_ub, int E_bi,
                          int* __restrict__ bCur, int2* __restrict__ binned) {
  __shared__ int hist[NBK];
  __shared__ int base[NBK];
  for (int i = threadIdx.x; i < NBK; i += 256) hist[i] = 0;
  __syncthreads();
  int b = blockIdx.x;
  int c0, c1, seg;
  if (b < 512)      { seg = 0; int ch = (E_ui + 511) / 512; c0 = b * ch; c1 = min(E_ui, c0 + ch); }
  else if (b < 768) { seg = 1; int ch = (E_ub + 255) / 256; c0 = (b - 512) * ch; c1 = min(E_ub, c0 + ch); }
  else              { seg = 2; int ch = (E_bi + 255) / 256; c0 = (b - 768) * ch; c1 = min(E_bi, c0 + ch); }
  for (int e = c0 + (int)threadIdx.x; e < c1; e += 256) {
    if (seg == 0) {
      atomicAdd(&hist[ui_u[e] >> 7], 1);
      atomicAdd(&hist[(ui_i[e] + NUc) >> 7], 1);
    } else if (seg == 1) {
      atomicAdd(&hist[(GUB0 + ub_u[e]) >> 7], 1);
      atomicAdd(&hist[(GUB0 + NUc + ub_b[e]) >> 7], 1);
    } else {
      atomicAdd(&hist[(GBI0 + bi_b[e]) >> 7], 1);
    }
  }
  __syncthreads();
  for (int i = threadIdx.x; i < NBK; i += 256) {
    int h = hist[i];
    base[i] = h ? atomicAdd(&bCur[i], h) : 0;
    hist[i] = 0;
  }
  __syncthreads();
  for (int e = c0 + (int)threadIdx.x; e < c1; e += 256) {
    if (seg == 0) {
      int u = ui_u[e], x = ui_i[e] + NUc;
      int b1 = u >> 7; binned[base[b1] + atomicAdd(&hist[b1], 1)] = make_int2(u, x);
      int b2 = x >> 7; binned[base[b2] + atomicAdd(&hist[b2], 1)] = make_int2(x, u);
    } else if (seg == 1) {
      int ul = ub_u[e], bl = NUc + ub_b[e];
      int r1 = GUB0 + ul, r2 = GUB0 + bl;
      int b1 = r1 >> 7; binned[base[b1] + atomicAdd(&hist[b1], 1)] = make_int2(r1, bl);
      int b2 = r2 >> 7; binned[base[b2] + atomicAdd(&hist[b2], 1)] = make_int2(r2, ul);
    } else {
      int r = GBI0 + bi_b[e];
      int b1 = r >> 7; binned[base[b1] + atomicAdd(&hist[b1], 1)] = make_int2(r, bi_i[e]);
    }
  }
}

// per-row degree (covers all padded rows)
__global__ void k_rowhist_all(const int2* __restrict__ binned, const int* __restrict__ bBase,
                              int* __restrict__ cnt) {
  __shared__ int hist[128];
  int bk = blockIdx.x, rowbase = bk << 7;
  int s = bBase[bk], e = bBase[bk + 1];
  if (threadIdx.x < 128) hist[threadIdx.x] = 0;
  __syncthreads();
  for (int i = s + (int)threadIdx.x; i < e; i += 256)
    atomicAdd(&hist[binned[i].x & 127], 1);
  __syncthreads();
  if (threadIdx.x < 128) cnt[rowbase + (int)threadIdx.x] = hist[threadIdx.x];
}

// hierarchical scan of PADDED counts: pcnt = (cnt+15)&~15
__global__ void k_scan_block_pad(const int* __restrict__ in, int n, int* __restrict__ out,
                                 int* __restrict__ bsum) {
  __shared__ int sh[256];
  int t = threadIdx.x;
  long base = (long)blockIdx.x * 1024 + (long)t * 4;
  int v0 = (base     < n) ? ((in[base]     + 15) & ~15) : 0;
  int v1 = (base + 1 < n) ? ((in[base + 1] + 15) & ~15) : 0;
  int v2 = (base + 2 < n) ? ((in[base + 2] + 15) & ~15) : 0;
  int v3 = (base + 3 < n) ? ((in[base + 3] + 15) & ~15) : 0;
  int tsum = v0 + v1 + v2 + v3;
  sh[t] = tsum;
  __syncthreads();
  for (int o = 1; o < 256; o <<= 1) {
    int x = (t >= o) ? sh[t - o] : 0;
    __syncthreads();
    sh[t] += x;
    __syncthreads();
  }
  int excl = sh[t] - tsum;
  if (t == 255) bsum[blockIdx.x] = sh[255];
  if (base     < n) out[base]     = excl;
  if (base + 1 < n) out[base + 1] = excl + v0;
  if (base + 2 < n) out[base + 2] = excl + v0 + v1;
  if (base + 3 < n) out[base + 3] = excl + v0 + v1 + v2;
}

__global__ void k_scan_bsum(int* __restrict__ bsum, int nb) {  // nb <= 256
  __shared__ int sh[256];
  int t = threadIdx.x;
  int v = (t < nb) ? bsum[t] : 0;
  sh[t] = v;
  __syncthreads();
  for (int o = 1; o < 256; o <<= 1) {
    int x = (t >= o) ? sh[t - o] : 0;
    __syncthreads();
    sh[t] += x;
    __syncthreads();
  }
  if (t < nb) bsum[t] = sh[t] - v;
}

__global__ void k_scan_add(int* __restrict__ out, int n, const int* __restrict__ bsum) {
  long i = (long)blockIdx.x * 256 + threadIdx.x;
  if (i < n) out[i] += bsum[i >> 10];
}

// per-bucket CSR fill + tail padding with zero-row dummy cols
__global__ void k_csrfill_all(const int2* __restrict__ binned, const int* __restrict__ bBase,
                              const int* __restrict__ rp, int* __restrict__ colv) {
  __shared__ int cur[128];
  int bk = blockIdx.x, rowbase = bk << 7;
  int xb, zpad;
  if (bk < BK_UB0)      { xb = 0;    zpad = NILc; }          // X zero row
  else if (bk < BK_BI0) { xb = GUB0; zpad = GUB0 + NBLc; }   // X zero row (UB side)
  else                  { xb = 0;    zpad = NIc; }           // MACC zero row
  int s = bBase[bk], e = bBase[bk + 1];
  if (threadIdx.x < 128) cur[threadIdx.x] = rp[rowbase + (int)threadIdx.x];
  __syncthreads();
  for (int i = s + (int)threadIdx.x; i < e; i += 256) {
    int2 rc = binned[i];
    int pos = atomicAdd(&cur[rc.x & 127], 1);
    colv[pos] = xb + rc.y;
  }
  __syncthreads();
  if (threadIdx.x < 128) {
    int r = rowbase + (int)threadIdx.x;
    int end = rp[r + 1];
    for (int k = cur[threadIdx.x]; k < end; k++) colv[k] = zpad;
  }
}

// X[g] = f2bf(feat[g] * dinv[g]) over [0, GBI0); padding rows -> 0
__global__ void k_prescale_all(const int* __restrict__ cnt, const float* __restrict__ userF,
                               const float* __restrict__ bundF, const float* __restrict__ itemF,
                               unsigned short* __restrict__ X) {
  long idx = (long)blockIdx.x * 256 + threadIdx.x;
  if (idx >= (long)GBI0 * 64) return;
  int g = (int)(idx >> 6), d = (int)(idx & 63);
  float v = 0.0f;
  if (g < NILc) v = (g < NUc) ? userF[(long)g * 64 + d] : itemF[(long)(g - NUc) * 64 + d];
  else if (g >= GUB0 && g < GUB0 + NBLc) {
    int l = g - GUB0;
    v = (l < NUc) ? userF[(long)l * 64 + d] : bundF[(long)(l - NUc) * 64 + d];
  }
  float dinv = 1.0f / (sqrtf((float)cnt[g]) + 1e-8f);
  X[idx] = f2bf(v * dinv);
}

// ---------------- SpMM: padded-16, 4 independent gathers in flight ----------
__global__ void k_spmm_g(const int* __restrict__ rp, const int* __restrict__ cnt,
                         const int* __restrict__ col, const unsigned short* __restrict__ X,
                         unsigned short* __restrict__ outB, float* __restrict__ outInv,
                         float scale, int mulDinv, int n) {
  int row = blockIdx.x * 4 + (threadIdx.x >> 6);
  if (row >= n) return;
  int lane = threadIdx.x & 63, q = lane >> 4, p = lane & 15;
  int s = rp[row], e = rp[row + 1];   // e-s multiple of 16
  const uint2* Xp = (const uint2*)X + p;
  float a0 = 0.f, a1 = 0.f, a2 = 0.f, a3 = 0.f;
  for (int eo = s + q; eo < e; eo += 16) {
    int c0 = col[eo], c1 = col[eo + 4], c2 = col[eo + 8], c3 = col[eo + 12];
    uint2 v0 = Xp[(size_t)c0 << 4];
    uint2 v1 = Xp[(size_t)c1 << 4];
    uint2 v2 = Xp[(size_t)c2 << 4];
    uint2 v3 = Xp[(size_t)c3 << 4];
    a0 += (__uint_as_float(v0.x << 16) + __uint_as_float(v1.x << 16)) +
          (__uint_as_float(v2.x << 16) + __uint_as_float(v3.x << 16));
    a1 += (__uint_as_float(v0.x & 0xFFFF0000u) + __uint_as_float(v1.x & 0xFFFF0000u)) +
          (__uint_as_float(v2.x & 0xFFFF0000u) + __uint_as_float(v3.x & 0xFFFF0000u));
    a2 += (__uint_as_float(v0.y << 16) + __uint_as_float(v1.y << 16)) +
          (__uint_as_float(v2.y << 16) + __uint_as_float(v3.y << 16));
    a3 += (__uint_as_float(v0.y & 0xFFFF0000u) + __uint_as_float(v1.y & 0xFFFF0000u)) +
          (__uint_as_float(v2.y & 0xFFFF0000u) + __uint_as_float(v3.y & 0xFFFF0000u));
  }
  a0 += __shfl_xor(a0, 32, 64); a1 += __shfl_xor(a1, 32, 64);
  a2 += __shfl_xor(a2, 32, 64); a3 += __shfl_xor(a3, 32, 64);
  a0 += __shfl_xor(a0, 16, 64); a1 += __shfl_xor(a1, 16, 64);
  a2 += __shfl_xor(a2, 16, 64); a3 += __shfl_xor(a3, 16, 64);
  float dinv = 1.0f / (sqrtf((float)cnt[row]) + 1e-8f);
  float f = dinv * scale;
  float r0 = a0 * f, r1 = a1 * f, r2 = a2 * f, r3 = a3 * f;
  float ss = r0 * r0 + r1 * r1 + r2 * r2 + r3 * r3;
  ss += __shfl_xor(ss, 8, 64); ss += __shfl_xor(ss, 4, 64);
  ss += __shfl_xor(ss, 2, 64); ss += __shfl_xor(ss, 1, 64);
  if (q == 0) {
    float mf = mulDinv ? dinv : 1.0f;
    uint2 m;
    m.x = (unsigned int)f2bf(r0 * mf) | ((unsigned int)f2bf(r1 * mf) << 16);
    m.y = (unsigned int)f2bf(r2 * mf) | ((unsigned int)f2bf(r3 * mf) << 16);
    *(uint2*)(outB + (size_t)row * 64 + p * 4) = m;
    if (p == 0) outInv[row] = 1.0f / fmaxf(sqrtf(ss), 1e-12f);
  }
}

// bundle mean-agg (BI rows; cols index MACC, dummy = zeroed row NIc)
__global__ void k_agg_g(const int* __restrict__ rp, const int* __restrict__ cnt,
                        const int* __restrict__ col, const unsigned short* __restrict__ MACC,
                        float* __restrict__ ILB, int n) {
  int rl = blockIdx.x * 4 + (threadIdx.x >> 6);
  if (rl >= n) return;
  int row = GBI0 + rl;
  int lane = threadIdx.x & 63, q = lane >> 4, p = lane & 15;
  int s = rp[row], e = rp[row + 1];
  const uint2* Xp = (const uint2*)MACC + p;
  float a0 = 0.f, a1 = 0.f, a2 = 0.f, a3 = 0.f;
  for (int eo = s + q; eo < e; eo += 16) {
    int c0 = col[eo], c1 = col[eo + 4], c2 = col[eo + 8], c3 = col[eo + 12];
    uint2 v0 = Xp[(size_t)c0 << 4];
    uint2 v1 = Xp[(size_t)c1 << 4];
    uint2 v2 = Xp[(size_t)c2 << 4];
    uint2 v3 = Xp[(size_t)c3 << 4];
    a0 += (__uint_as_float(v0.x << 16) + __uint_as_float(v1.x << 16)) +
          (__uint_as_float(v2.x << 16) + __uint_as_float(v3.x << 16));
    a1 += (__uint_as_float(v0.x & 0xFFFF0000u) + __uint_as_float(v1.x & 0xFFFF0000u)) +
          (__uint_as_float(v2.x & 0xFFFF0000u) + __uint_as_float(v3.x & 0xFFFF0000u));
    a2 += (__uint_as_float(v0.y << 16) + __uint_as_float(v1.y << 16)) +
          (__uint_as_float(v2.y << 16) + __uint_as_float(v3.y << 16));
    a3 += (__uint_as_float(v0.y & 0xFFFF0000u) + __uint_as_float(v1.y & 0xFFFF0000u)) +
          (__uint_as_float(v2.y & 0xFFFF0000u) + __uint_as_float(v3.y & 0xFFFF0000u));
  }
  a0 += __shfl_xor(a0, 32, 64); a1 += __shfl_xor(a1, 32, 64);
  a2 += __shfl_xor(a2, 32, 64); a3 += __shfl_xor(a3, 32, 64);
  a0 += __shfl_xor(a0, 16, 64); a1 += __shfl_xor(a1, 16, 64);
  a2 += __shfl_xor(a2, 16, 64); a3 += __shfl_xor(a3, 16, 64);
  if (q == 0) {
    float w = 1.0f / ((float)cnt[row] + 1e-8f);
    *(float4*)(ILB + (size_t)rl * 64 + p * 4) = make_float4(a0 * w, a1 * w, a2 * w, a3 * w);
  }
}

// ACC (IL rows then BL rows) + bf16 item mirror; F1 reconstructed from M1
__global__ void k_acc_all(const float* __restrict__ userF, const float* __restrict__ bundF,
                          const float* __restrict__ itemF, const int* __restrict__ cnt,
                          const unsigned short* __restrict__ M1, const unsigned short* __restrict__ F2b,
                          const float* __restrict__ INV1, const float* __restrict__ INV2,
                          float* __restrict__ ACC, unsigned short* __restrict__ MACC) {
  long idx = (long)blockIdx.x * 256 + threadIdx.x;
  if (idx >= (long)(NILc + NBLc) * 64) return;
  int rl = (int)(idx >> 6), d = (int)(idx & 63);
  int g; float base;
  bool il = rl < NILc;
  if (il) {
    g = rl;
    base = (rl < NUc) ? userF[(long)rl * 64 + d] : itemF[(long)(rl - NUc) * 64 + d];
  } else {
    int l = rl - NILc;
    g = GUB0 + l;
    base = (l < NUc) ? userF[(long)l * 64 + d] : bundF[(long)(l - NUc) * 64 + d];
  }
  float rs = sqrtf((float)cnt[g]) + 1e-8f;   // 1/dinv
  float F1 = bf2f(M1[(size_t)g * 64 + d]) * rs;
  float F2 = bf2f(F2b[(size_t)g * 64 + d]);
  float res = base + F1 * INV1[g] + F2 * INV2[g];
  ACC[idx] = res;
  if (il && rl >= NUc) MACC[(size_t)(rl - NUc) * 64 + d] = f2bf(res);
}

__global__ void k_gather_all(const int* __restrict__ users, const int* __restrict__ bundles,
                             const float* __restrict__ ACC, const float* __restrict__ ILB, int B,
                             float* __restrict__ ILu, float* __restrict__ BLu,
                             float* __restrict__ ILb2, float* __restrict__ BLb2) {
  long i = (long)blockIdx.x * 256 + threadIdx.x;
  if (i >= (long)6 * B * 64) return;
  int r = (int)(i >> 6), d = (int)(i & 63);
  if (r < B) ILu[(long)r * 64 + d] = ACC[(long)users[r] * 64 + d];
  else if (r < 2 * B) { int rr = r - B; BLu[(long)rr * 64 + d] = ACC[(long)(NILc + users[rr]) * 64 + d]; }
  else if (r < 4 * B) { int rr = r - 2 * B; ILb2[(long)rr * 64 + d] = ILB[(long)bundles[rr] * 64 + d]; }
  else { int rr = r - 4 * B; BLb2[(long)rr * 64 + d] = ACC[(long)(NILc + NUc + bundles[rr]) * 64 + d]; }
}

__global__ void k_normalize4(const float* __restrict__ s0, const float* __restrict__ s1,
                             const float* __restrict__ s2, const float* __restrict__ s3,
                             float* __restrict__ d0, float* __restrict__ d1,
                             float* __restrict__ d2, float* __restrict__ d3, int B) {
  int row = blockIdx.x * 4 + (threadIdx.x >> 6);
  int lane = threadIdx.x & 63;
  if (row >= 4 * B) return;
  int which = row / B, r = row - which * B;
  const float* src; float* dst; int stride;
  if (which == 0)      { src = s0; dst = d0; stride = 64; }
  else if (which == 1) { src = s1; dst = d1; stride = 64; }
  else if (which == 2) { src = s2; dst = d2; stride = 128; }
  else                 { src = s3; dst = d3; stride = 128; }
  float v = src[(long)r * stride + lane];
  float ss = wredsum(v * v);
  dst[(long)r * 64 + lane] = v * (1.0f / fmaxf(sqrtf(ss), 1e-12f));
}

__global__ void k_bpr(const float* __restrict__ ILu, const float* __restrict__ ILb2,
                      const float* __restrict__ BLu, const float* __restrict__ BLb2,
                      int B, float* __restrict__ out) {
  int row = blockIdx.x * 4 + (threadIdx.x >> 6);
  int lane = threadIdx.x & 63;
  if (row >= B) return;
  float t = ILu[(long)row * 64 + lane] *
              (ILb2[(long)(2 * row) * 64 + lane] - ILb2[(long)(2 * row + 1) * 64 + lane]) +
            BLu[(long)row * 64 + lane] *
              (BLb2[(long)(2 * row) * 64 + lane] - BLb2[(long)(2 * row + 1) * 64 + lane]);
  float x = wredsum(t);
  if (lane == 0) {
    float ls = -(fmaxf(-x, 0.0f) + log1pf(expf(-fabsf(x))));
    unsafeAtomicAdd(&out[0], -ls / (float)B);
  }
}

// InfoNCE GEMM, z selects pair; conflict-free stride-16 columns
__global__ void k_gemm_nt2(const float* __restrict__ P1, const float* __restrict__ A1,
                           const float* __restrict__ P2, const float* __restrict__ A2,
                           float* __restrict__ S1o, float* __restrict__ S2o,
                           int N, float scale) {
  __shared__ float Ps[64][129];
  __shared__ float As[64][129];
  const float* P = blockIdx.z ? P2 : P1;
  const float* A = blockIdx.z ? A2 : A1;
  float* S = blockIdx.z ? S2o : S1o;
  int bi0 = blockIdx.y * 128, bj0 = blockIdx.x * 128;
  int t = threadIdx.x;
  #pragma unroll
  for (int sct = 0; sct < 8; sct++) {
    int idx4 = t + sct * 256;
    int r = idx4 >> 4, k = (idx4 & 15) << 2;
    int pr = min(bi0 + r, N - 1);
    int ar = min(bj0 + r, N - 1);
    float4 v = *(const float4*)(P + (long)pr * 64 + k);
    Ps[k][r] = v.x; Ps[k + 1][r] = v.y; Ps[k + 2][r] = v.z; Ps[k + 3][r] = v.w;
    float4 w = *(const float4*)(A + (long)ar * 64 + k);
    As[k][r] = w.x; As[k + 1][r] = w.y; As[k + 2][r] = w.z; As[k + 3][r] = w.w;
  }
  __syncthreads();
  int tx = t & 15, ty = t >> 4;
  float acc[8][8];
  #pragma unroll
  for (int i = 0; i < 8; i++)
    #pragma unroll
    for (int j = 0; j < 8; j++) acc[i][j] = 0.0f;
  #pragma unroll 4
  for (int k = 0; k < 64; k++) {
    float a[8], b[8];
    #pragma unroll
    for (int i = 0; i < 8; i++) a[i] = Ps[k][ty * 8 + i];
    #pragma unroll
    for (int j = 0; j < 8; j++) b[j] = As[k][tx + 16 * j];
    #pragma unroll
    for (int i = 0; i < 8; i++)
      #pragma unroll
      for (int j = 0; j < 8; j++) acc[i][j] = fmaf(a[i], b[j], acc[i][j]);
  }
  #pragma unroll
  for (int i = 0; i < 8; i++) {
    int row = bi0 + ty * 8 + i;
    if (row >= N) continue;
    #pragma unroll
    for (int j = 0; j < 8; j++) {
      int cc = bj0 + tx + 16 * j;
      if (cc < N) S[(long)row * N + cc] = acc[i][j] * scale;
    }
  }
}

__global__ void k_lse2(const float* __restrict__ S1, const float* __restrict__ S2,
                       int B, float coeff, float* __restrict__ out) {
  constexpr float L2E = 1.44269504f;
  int row = blockIdx.x * 4 + (threadIdx.x >> 6);
  int lane = threadIdx.x & 63;
  const float* Sr; int dg;
  if (row < B) { Sr = S1 + (long)row * B; dg = row; }
  else         { Sr = S2 + (long)(row - B) * B; dg = row - B; }
  float m = -1e30f, s = 0.0f;
  for (int w = 0; w < (B >> 8); w++) {
    float4 v = *(const float4*)(Sr + ((w << 6) + lane) * 4);
    float mx = fmaxf(fmaxf(v.x, v.y), fmaxf(v.z, v.w));
    if (mx > m) { s *= exp2f((m - mx) * L2E); m = mx; }
    s += exp2f((v.x - m) * L2E) + exp2f((v.y - m) * L2E) +
         exp2f((v.z - m) * L2E) + exp2f((v.w - m) * L2E);
  }
  #pragma unroll
  for (int o = 32; o >= 1; o >>= 1) {
    float m2 = __shfl_xor(m, o, 64), s2 = __shfl_xor(s, o, 64);
    float M = fmaxf(m, m2);
    s = s * exp2f((m - M) * L2E) + s2 * exp2f((m2 - M) * L2E);
    m = M;
  }
  if (lane == 0) {
    float lse = m + log2f(s) * 0.69314718f;
    unsafeAtomicAdd(&out[1], -(Sr[dg] - lse) * coeff);
  }
}

extern "C" void kernel_launch(void* const* d_in, const int* in_sizes, int n_in,
                              void* d_out, int out_size, void* d_ws, size_t ws_size,
                              hipStream_t stream) {
  const int* users   = (const int*)d_in[0];
  const int* bundles = (const int*)d_in[1];
  const int* ui_u    = (const int*)d_in[2];
  const int* ui_i    = (const int*)d_in[3];
  const int* ub_u    = (const int*)d_in[4];
  const int* ub_b    = (const int*)d_in[5];
  const int* bi_b    = (const int*)d_in[6];
  const int* bi_i    = (const int*)d_in[7];
  const float* userF = (const float*)d_in[8];
  const float* bundF = (const float*)d_in[9];
  const float* itemF = (const float*)d_in[10];
  float* out = (float*)d_out;

  const int B    = in_sizes[0];
  const int E_ui = in_sizes[2];
  const int E_ub = in_sizes[4];
  const int E_bi = in_sizes[6];
  const long E_all = 2L * E_ui + 2L * E_ub + E_bi;

  float* ws = (float*)d_ws;
  size_t off = 0;
  auto alloc = [&](size_t nfloat) -> float* {
    float* p = ws + off;
    off += (nfloat + 63) & ~(size_t)63;
    return p;
  };
  float* ACC = alloc((size_t)(NILc + NBLc) * 64);                 // 56.3 MB
  unsigned short* X  = (unsigned short*)alloc((size_t)GBI0 * 32); // 28.2 MB
  unsigned short* M1 = (unsigned short*)alloc((size_t)GBI0 * 32); // 28.2 MB
  int2* binned = (int2*)alloc((size_t)E_all * 2);                 // 48 MB
  int* colv  = (int*)alloc((size_t)E_all + 15 * (size_t)GTOT + 128);  // padded cols
  int* rp    = (int*)alloc(GTOT + 1);
  int* cnt   = (int*)alloc(GTOT + 1);
  float* INV1 = alloc(GTOT);
  float* INV2 = alloc(GTOT);
  float* ILB  = alloc((size_t)NBUc * 64);
  float* ILu  = alloc((size_t)B * 64);
  float* BLu  = alloc((size_t)B * 64);
  float* ILb2 = alloc((size_t)B * 128);
  float* BLb2 = alloc((size_t)B * 128);
  float* PN1  = alloc((size_t)B * 64);
  float* AN1  = alloc((size_t)B * 64);
  float* PN2  = alloc((size_t)B * 64);
  float* AN2  = alloc((size_t)B * 64);
  int* bCnt  = (int*)alloc(2049);
  int* bBase = (int*)alloc(2049);
  int* bCur  = (int*)alloc(2049);
  int* bsum  = (int*)alloc(256);
  (void)ws_size; (void)n_in; (void)out_size;

  // overlays into dead phases:
  unsigned short* F2b  = X;                        // layer-2 out overlays X (dead after l1)
  unsigned short* MACC = (unsigned short*)binned;  // 12.9 MB incl. zero row NIc; binned dead after csrfill
  float* S1 = ACC;                                 // ACC dead after gathers
  float* S2 = ACC + (size_t)B * B;

  // ---- unified bucketed binning + padded CSR (all 3 graphs) ----
  hipMemsetAsync(bCnt, 0, sizeof(int) * NBK, stream);
  k_bcount_all<<<1024, 256, 0, stream>>>(ui_u, ui_i, ub_u, ub_b, bi_b, E_ui, E_ub, E_bi, bCnt);
  k_scan2048<<<1, 512, 0, stream>>>(bCnt, NBK, bBase, bCur);
  k_bin_all<<<1024, 256, 0, stream>>>(ui_u, ui_i, ub_u, ub_b, bi_b, bi_i,
                                      E_ui, E_ub, E_bi, bCur, binned);
  hipMemsetAsync(cnt, 0, sizeof(int) * (GTOT + 1), stream);
  k_rowhist_all<<<NBK, 256, 0, stream>>>(binned, bBase, cnt);
  {
    int scan_n = GTOT + 1;
    int nb1 = (scan_n + 1023) / 1024;
    k_scan_block_pad<<<nb1, 256, 0, stream>>>(cnt, scan_n, rp, bsum);
    k_scan_bsum<<<1, 256, 0, stream>>>(bsum, nb1);
    k_scan_add<<<(scan_n + 255) / 256, 256, 0, stream>>>(rp, scan_n, bsum);
  }
  k_csrfill_all<<<NBK, 256, 0, stream>>>(binned, bBase, rp, colv);

  // ---- propagate (UI + UB merged per layer) ----
  k_prescale_all<<<(int)(((long)GBI0 * 64 + 255) / 256), 256, 0, stream>>>(cnt, userF, bundF,
                                                                           itemF, X);
  k_spmm_g<<<(GBI0 + 3) / 4, 256, 0, stream>>>(rp, cnt, colv, X, M1, INV1, 0.5f, 1, GBI0);
  k_spmm_g<<<(GBI0 + 3) / 4, 256, 0, stream>>>(rp, cnt, colv, M1, F2b, INV2, 1.0f / 3.0f, 0, GBI0);
  // zero MACC dummy row (index NIc) before agg reads it via padded cols
  hipMemsetAsync(MACC + (size_t)NIc * 64, 0, 128, stream);
  k_acc_all<<<(int)(((long)(NILc + NBLc) * 64 + 255) / 256), 256, 0, stream>>>(
      userF, bundF, itemF, cnt, M1, F2b, INV1, INV2, ACC, MACC);
  k_agg_g<<<(NBUc + 3) / 4, 256, 0, stream>>>(rp, cnt, colv, MACC, ILB, NBUc);
  k_gather_all<<<(int)(((long)6 * B * 64 + 255) / 256), 256, 0, stream>>>(
      users, bundles, ACC, ILB, B, ILu, BLu, ILb2, BLb2);

  // ---- losses ----
  hipMemsetAsync(out, 0, 2 * sizeof(float), stream);
  k_bpr<<<(B + 3) / 4, 256, 0, stream>>>(ILu, ILb2, BLu, BLb2, B, out);
  k_normalize4<<<(4 * B + 3) / 4, 256, 0, stream>>>(ILu, BLu, ILb2, BLb2, PN1, AN1, PN2, AN2, B);
  dim3 gg((B + 127) / 128, (B + 127) / 128, 2);
  k_gemm_nt2<<<gg, 256, 0, stream>>>(PN1, AN1, PN2, AN2, S1, S2, B, 4.0f);  // 1/C_TEMP
  k_lse2<<<(2 * B + 3) / 4, 256, 0, stream>>>(S1, S2, B, 0.5f / (float)B, out);
}

// Round 14
// 531.686 us; speedup vs baseline: 1.2955x; 1.0828x over previous
//
#include <hip/hip_runtime.h>
#include <hip/hip_bf16.h>
#include <math.h>

// CrossCBR R13 (resubmit after infra failure): R12 SpMM kept byte-identical
// (107us, gather-bound). Tail cuts: binned packed to uint32 (halve build
// traffic); ACC eliminated — item mirror written directly (k_acc_items) and
// batch embeddings computed on-the-fly at gathered indices with fused
// normalize (k_batch). S1/S2 overlay X/M1.
static constexpr int NUc  = 50000;
static constexpr int NBUc = 20000;
static constexpr int NIc  = 100000;
static constexpr int NILc = 150000;           // UI graph nodes
static constexpr int NBLc = 70000;            // UB graph nodes
// global padded rows: UI [0,150016), UB [150016,220032), BI [220032,240128)
static constexpr int GUB0   = 150016;         // 1172*128
static constexpr int GBI0   = 220032;         // 1719*128
static constexpr int BK_UB0 = 1172;
static constexpr int BK_BI0 = 1719;
static constexpr int NBK    = 1876;
static constexpr int GTOT   = NBK * 128;      // 240128

__device__ __forceinline__ float wredsum(float v) {
  #pragma unroll
  for (int m = 32; m >= 1; m >>= 1) v += __shfl_xor(v, m, 64);
  return v;
}
__device__ __forceinline__ float bf2f(unsigned short h) {
  return __uint_as_float(((unsigned int)h) << 16);
}
__device__ __forceinline__ unsigned short f2bf(float f) {  // RNE
  unsigned int u = __float_as_uint(f);
  return (unsigned short)((u + 0x7FFFu + ((u >> 16) & 1u)) >> 16);
}

// ---------------- bucket counts (all 3 graphs, one launch) ----------------
__global__ void k_bcount_all(const int* __restrict__ ui_u, const int* __restrict__ ui_i,
                             const int* __restrict__ ub_u, const int* __restrict__ ub_b,
                             const int* __restrict__ bi_b,
                             int E_ui, int E_ub, int E_bi, int* __restrict__ bCnt) {
  __shared__ int hist[NBK];
  for (int i = threadIdx.x; i < NBK; i += 256) hist[i] = 0;
  __syncthreads();
  int b = blockIdx.x;
  if (b < 512) {
    int chunk = (E_ui + 511) / 512, c0 = b * chunk, c1 = min(E_ui, c0 + chunk);
    for (int e = c0 + (int)threadIdx.x; e < c1; e += 256) {
      atomicAdd(&hist[ui_u[e] >> 7], 1);
      atomicAdd(&hist[(ui_i[e] + NUc) >> 7], 1);
    }
  } else if (b < 768) {
    int lb = b - 512, chunk = (E_ub + 255) / 256, c0 = lb * chunk, c1 = min(E_ub, c0 + chunk);
    for (int e = c0 + (int)threadIdx.x; e < c1; e += 256) {
      atomicAdd(&hist[(GUB0 + ub_u[e]) >> 7], 1);
      atomicAdd(&hist[(GUB0 + NUc + ub_b[e]) >> 7], 1);
    }
  } else {
    int lb = b - 768, chunk = (E_bi + 255) / 256, c0 = lb * chunk, c1 = min(E_bi, c0 + chunk);
    for (int e = c0 + (int)threadIdx.x; e < c1; e += 256)
      atomicAdd(&hist[(GBI0 + bi_b[e]) >> 7], 1);
  }
  __syncthreads();
  for (int i = threadIdx.x; i < NBK; i += 256)
    if (hist[i]) atomicAdd(&bCnt[i], hist[i]);
}

// exclusive scan of n<=2048 elements, 1 block x 512
__global__ void k_scan2048(const int* __restrict__ in, int n,
                           int* __restrict__ outBase, int* __restrict__ outCur) {
  __shared__ int sh[512];
  int t = threadIdx.x, i0 = 4 * t;
  int v0 = (i0 < n) ? in[i0] : 0;
  int v1 = (i0 + 1 < n) ? in[i0 + 1] : 0;
  int v2 = (i0 + 2 < n) ? in[i0 + 2] : 0;
  int v3 = (i0 + 3 < n) ? in[i0 + 3] : 0;
  int ts = v0 + v1 + v2 + v3;
  sh[t] = ts;
  __syncthreads();
  for (int o = 1; o < 512; o <<= 1) {
    int x = (t >= o) ? sh[t - o] : 0;
    __syncthreads();
    sh[t] += x;
    __syncthreads();
  }
  int ex = sh[t] - ts;
  if (i0 < n)     { outBase[i0] = ex;                    outCur[i0] = ex; }
  if (i0 + 1 < n) { outBase[i0 + 1] = ex + v0;           outCur[i0 + 1] = ex + v0; }
  if (i0 + 2 < n) { outBase[i0 + 2] = ex + v0 + v1;      outCur[i0 + 2] = ex + v0 + v1; }
  if (i0 + 3 < n) { outBase[i0 + 3] = ex + v0 + v1 + v2; outCur[i0 + 3] = ex + v0 + v1 + v2; }
  if (t == 511) outBase[n] = sh[511];
}

// ---------------- bin all edges -> bucket-sorted packed (row7|col18) --------
__global__ void k_bin_all(const int* __restrict__ ui_u, const int* __restrict__ ui_i,
                          const int* __restrict__ ub_u, const int* __restrict__ ub_b,
                          const int* __restrict__ bi_b, const int* __restrict__ bi_i,
                          int E_ui, int E_ub, int E_bi,
                          int* __restrict__ bCur, unsigned int* __restrict__ binned) {
  __shared__ int hist[NBK];
  __shared__ int base[NBK];
  for (int i = threadIdx.x; i < NBK; i += 256) hist[i] = 0;
  __syncthreads();
  int b = blockIdx.x;
  int c0, c1, seg;
  if (b < 512)      { seg = 0; int ch = (E_ui + 511) / 512; c0 = b * ch; c1 = min(E_ui, c0 + ch); }
  else if (b < 768) { seg = 1; int ch = (E_ub + 255) / 256; c0 = (b - 512) * ch; c1 = min(E_ub, c0 + ch); }
  else              { seg = 2; int ch = (E_bi + 255) / 256; c0 = (b - 768) * ch; c1 = min(E_bi, c0 + ch); }
  for (int e = c0 + (int)threadIdx.x; e < c1; e += 256) {
    if (seg == 0) {
      atomicAdd(&hist[ui_u[e] >> 7], 1);
      atomicAdd(&hist[(ui_i[e] + NUc) >> 7], 1);
    } else if (seg == 1) {
      atomicAdd(&hist[(GUB0 + ub_u[e]) >> 7], 1);
      atomicAdd(&hist[(GUB0 + NUc + ub_b[e]) >> 7], 1);
    } else {
      atomicAdd(&hist[(GBI0 + bi_b[e]) >> 7], 1);
    }
  }
  __syncthreads();
  for (int i = threadIdx.x; i < NBK; i += 256) {
    int h = hist[i];
    base[i] = h ? atomicAdd(&bCur[i], h) : 0;
    hist[i] = 0;
  }
  __syncthreads();
  for (int e = c0 + (int)threadIdx.x; e < c1; e += 256) {
    if (seg == 0) {
      int u = ui_u[e], x = ui_i[e] + NUc;   // both < 2^18
      int b1 = u >> 7;
      binned[base[b1] + atomicAdd(&hist[b1], 1)] = ((unsigned)(u & 127) << 18) | (unsigned)x;
      int b2 = x >> 7;
      binned[base[b2] + atomicAdd(&hist[b2], 1)] = ((unsigned)(x & 127) << 18) | (unsigned)u;
    } else if (seg == 1) {
      int ul = ub_u[e], bl = NUc + ub_b[e];
      int r1 = GUB0 + ul, r2 = GUB0 + bl;
      int b1 = r1 >> 7;
      binned[base[b1] + atomicAdd(&hist[b1], 1)] = ((unsigned)(r1 & 127) << 18) | (unsigned)bl;
      int b2 = r2 >> 7;
      binned[base[b2] + atomicAdd(&hist[b2], 1)] = ((unsigned)(r2 & 127) << 18) | (unsigned)ul;
    } else {
      int r = GBI0 + bi_b[e];
      int b1 = r >> 7;
      binned[base[b1] + atomicAdd(&hist[b1], 1)] = ((unsigned)(r & 127) << 18) | (unsigned)bi_i[e];
    }
  }
}

// per-row degree (covers all padded rows)
__global__ void k_rowhist_all(const unsigned int* __restrict__ binned, const int* __restrict__ bBase,
                              int* __restrict__ cnt) {
  __shared__ int hist[128];
  int bk = blockIdx.x, rowbase = bk << 7;
  int s = bBase[bk], e = bBase[bk + 1];
  if (threadIdx.x < 128) hist[threadIdx.x] = 0;
  __syncthreads();
  for (int i = s + (int)threadIdx.x; i < e; i += 256)
    atomicAdd(&hist[binned[i] >> 18], 1);
  __syncthreads();
  if (threadIdx.x < 128) cnt[rowbase + (int)threadIdx.x] = hist[threadIdx.x];
}

// hierarchical scan of PADDED counts: pcnt = (cnt+15)&~15
__global__ void k_scan_block_pad(const int* __restrict__ in, int n, int* __restrict__ out,
                                 int* __restrict__ bsum) {
  __shared__ int sh[256];
  int t = threadIdx.x;
  long base = (long)blockIdx.x * 1024 + (long)t * 4;
  int v0 = (base     < n) ? ((in[base]     + 15) & ~15) : 0;
  int v1 = (base + 1 < n) ? ((in[base + 1] + 15) & ~15) : 0;
  int v2 = (base + 2 < n) ? ((in[base + 2] + 15) & ~15) : 0;
  int v3 = (base + 3 < n) ? ((in[base + 3] + 15) & ~15) : 0;
  int tsum = v0 + v1 + v2 + v3;
  sh[t] = tsum;
  __syncthreads();
  for (int o = 1; o < 256; o <<= 1) {
    int x = (t >= o) ? sh[t - o] : 0;
    __syncthreads();
    sh[t] += x;
    __syncthreads();
  }
  int excl = sh[t] - tsum;
  if (t == 255) bsum[blockIdx.x] = sh[255];
  if (base     < n) out[base]     = excl;
  if (base + 1 < n) out[base + 1] = excl + v0;
  if (base + 2 < n) out[base + 2] = excl + v0 + v1;
  if (base + 3 < n) out[base + 3] = excl + v0 + v1 + v2;
}

__global__ void k_scan_bsum(int* __restrict__ bsum, int nb) {  // nb <= 256
  __shared__ int sh[256];
  int t = threadIdx.x;
  int v = (t < nb) ? bsum[t] : 0;
  sh[t] = v;
  __syncthreads();
  for (int o = 1; o < 256; o <<= 1) {
    int x = (t >= o) ? sh[t - o] : 0;
    __syncthreads();
    sh[t] += x;
    __syncthreads();
  }
  if (t < nb) bsum[t] = sh[t] - v;
}

__global__ void k_scan_add(int* __restrict__ out, int n, const int* __restrict__ bsum) {
  long i = (long)blockIdx.x * 256 + threadIdx.x;
  if (i < n) out[i] += bsum[i >> 10];
}

// per-bucket CSR fill + tail padding with zero-row dummy cols
__global__ void k_csrfill_all(const unsigned int* __restrict__ binned, const int* __restrict__ bBase,
                              const int* __restrict__ rp, int* __restrict__ colv) {
  __shared__ int cur[128];
  int bk = blockIdx.x, rowbase = bk << 7;
  int xb, zpad;
  if (bk < BK_UB0)      { xb = 0;    zpad = NILc; }          // X zero row
  else if (bk < BK_BI0) { xb = GUB0; zpad = GUB0 + NBLc; }   // X zero row (UB side)
  else                  { xb = 0;    zpad = NIc; }           // MACC zero row
  int s = bBase[bk], e = bBase[bk + 1];
  if (threadIdx.x < 128) cur[threadIdx.x] = rp[rowbase + (int)threadIdx.x];
  __syncthreads();
  for (int i = s + (int)threadIdx.x; i < e; i += 256) {
    unsigned int pk = binned[i];
    int pos = atomicAdd(&cur[pk >> 18], 1);
    colv[pos] = xb + (int)(pk & 0x3FFFFu);
  }
  __syncthreads();
  if (threadIdx.x < 128) {
    int r = rowbase + (int)threadIdx.x;
    int end = rp[r + 1];
    for (int k = cur[threadIdx.x]; k < end; k++) colv[k] = zpad;
  }
}

// X[g] = f2bf(feat[g] * dinv[g]) over [0, GBI0); padding rows -> 0
__global__ void k_prescale_all(const int* __restrict__ cnt, const float* __restrict__ userF,
                               const float* __restrict__ bundF, const float* __restrict__ itemF,
                               unsigned short* __restrict__ X) {
  long idx = (long)blockIdx.x * 256 + threadIdx.x;
  if (idx >= (long)GBI0 * 64) return;
  int g = (int)(idx >> 6), d = (int)(idx & 63);
  float v = 0.0f;
  if (g < NILc) v = (g < NUc) ? userF[(long)g * 64 + d] : itemF[(long)(g - NUc) * 64 + d];
  else if (g >= GUB0 && g < GUB0 + NBLc) {
    int l = g - GUB0;
    v = (l < NUc) ? userF[(long)l * 64 + d] : bundF[(long)(l - NUc) * 64 + d];
  }
  float dinv = 1.0f / (sqrtf((float)cnt[g]) + 1e-8f);
  X[idx] = f2bf(v * dinv);
}

// ---------------- SpMM: padded-16, 4 independent gathers in flight ----------
__global__ void k_spmm_g(const int* __restrict__ rp, const int* __restrict__ cnt,
                         const int* __restrict__ col, const unsigned short* __restrict__ X,
                         unsigned short* __restrict__ outB, float* __restrict__ outInv,
                         float scale, int mulDinv, int n) {
  int row = blockIdx.x * 4 + (threadIdx.x >> 6);
  if (row >= n) return;
  int lane = threadIdx.x & 63, q = lane >> 4, p = lane & 15;
  int s = rp[row], e = rp[row + 1];   // e-s multiple of 16
  const uint2* Xp = (const uint2*)X + p;
  float a0 = 0.f, a1 = 0.f, a2 = 0.f, a3 = 0.f;
  for (int eo = s + q; eo < e; eo += 16) {
    int c0 = col[eo], c1 = col[eo + 4], c2 = col[eo + 8], c3 = col[eo + 12];
    uint2 v0 = Xp[(size_t)c0 << 4];
    uint2 v1 = Xp[(size_t)c1 << 4];
    uint2 v2 = Xp[(size_t)c2 << 4];
    uint2 v3 = Xp[(size_t)c3 << 4];
    a0 += (__uint_as_float(v0.x << 16) + __uint_as_float(v1.x << 16)) +
          (__uint_as_float(v2.x << 16) + __uint_as_float(v3.x << 16));
    a1 += (__uint_as_float(v0.x & 0xFFFF0000u) + __uint_as_float(v1.x & 0xFFFF0000u)) +
          (__uint_as_float(v2.x & 0xFFFF0000u) + __uint_as_float(v3.x & 0xFFFF0000u));
    a2 += (__uint_as_float(v0.y << 16) + __uint_as_float(v1.y << 16)) +
          (__uint_as_float(v2.y << 16) + __uint_as_float(v3.y << 16));
    a3 += (__uint_as_float(v0.y & 0xFFFF0000u) + __uint_as_float(v1.y & 0xFFFF0000u)) +
          (__uint_as_float(v2.y & 0xFFFF0000u) + __uint_as_float(v3.y & 0xFFFF0000u));
  }
  a0 += __shfl_xor(a0, 32, 64); a1 += __shfl_xor(a1, 32, 64);
  a2 += __shfl_xor(a2, 32, 64); a3 += __shfl_xor(a3, 32, 64);
  a0 += __shfl_xor(a0, 16, 64); a1 += __shfl_xor(a1, 16, 64);
  a2 += __shfl_xor(a2, 16, 64); a3 += __shfl_xor(a3, 16, 64);
  float dinv = 1.0f / (sqrtf((float)cnt[row]) + 1e-8f);
  float f = dinv * scale;
  float r0 = a0 * f, r1 = a1 * f, r2 = a2 * f, r3 = a3 * f;
  float ss = r0 * r0 + r1 * r1 + r2 * r2 + r3 * r3;
  ss += __shfl_xor(ss, 8, 64); ss += __shfl_xor(ss, 4, 64);
  ss += __shfl_xor(ss, 2, 64); ss += __shfl_xor(ss, 1, 64);
  if (q == 0) {
    float mf = mulDinv ? dinv : 1.0f;
    uint2 m;
    m.x = (unsigned int)f2bf(r0 * mf) | ((unsigned int)f2bf(r1 * mf) << 16);
    m.y = (unsigned int)f2bf(r2 * mf) | ((unsigned int)f2bf(r3 * mf) << 16);
    *(uint2*)(outB + (size_t)row * 64 + p * 4) = m;
    if (p == 0) outInv[row] = 1.0f / fmaxf(sqrtf(ss), 1e-12f);
  }
}

// bundle mean-agg (BI rows; cols index MACC, dummy = zeroed row NIc)
__global__ void k_agg_g(const int* __restrict__ rp, const int* __restrict__ cnt,
                        const int* __restrict__ col, const unsigned short* __restrict__ MACC,
                        float* __restrict__ ILB, int n) {
  int rl = blockIdx.x * 4 + (threadIdx.x >> 6);
  if (rl >= n) return;
  int row = GBI0 + rl;
  int lane = threadIdx.x & 63, q = lane >> 4, p = lane & 15;
  int s = rp[row], e = rp[row + 1];
  const uint2* Xp = (const uint2*)MACC + p;
  float a0 = 0.f, a1 = 0.f, a2 = 0.f, a3 = 0.f;
  for (int eo = s + q; eo < e; eo += 16) {
    int c0 = col[eo], c1 = col[eo + 4], c2 = col[eo + 8], c3 = col[eo + 12];
    uint2 v0 = Xp[(size_t)c0 << 4];
    uint2 v1 = Xp[(size_t)c1 << 4];
    uint2 v2 = Xp[(size_t)c2 << 4];
    uint2 v3 = Xp[(size_t)c3 << 4];
    a0 += (__uint_as_float(v0.x << 16) + __uint_as_float(v1.x << 16)) +
          (__uint_as_float(v2.x << 16) + __uint_as_float(v3.x << 16));
    a1 += (__uint_as_float(v0.x & 0xFFFF0000u) + __uint_as_float(v1.x & 0xFFFF0000u)) +
          (__uint_as_float(v2.x & 0xFFFF0000u) + __uint_as_float(v3.x & 0xFFFF0000u));
    a2 += (__uint_as_float(v0.y << 16) + __uint_as_float(v1.y << 16)) +
          (__uint_as_float(v2.y << 16) + __uint_as_float(v3.y << 16));
    a3 += (__uint_as_float(v0.y & 0xFFFF0000u) + __uint_as_float(v1.y & 0xFFFF0000u)) +
          (__uint_as_float(v2.y & 0xFFFF0000u) + __uint_as_float(v3.y & 0xFFFF0000u));
  }
  a0 += __shfl_xor(a0, 32, 64); a1 += __shfl_xor(a1, 32, 64);
  a2 += __shfl_xor(a2, 32, 64); a3 += __shfl_xor(a3, 32, 64);
  a0 += __shfl_xor(a0, 16, 64); a1 += __shfl_xor(a1, 16, 64);
  a2 += __shfl_xor(a2, 16, 64); a3 += __shfl_xor(a3, 16, 64);
  if (q == 0) {
    float w = 1.0f / ((float)cnt[row] + 1e-8f);
    *(float4*)(ILB + (size_t)rl * 64 + p * 4) = make_float4(a0 * w, a1 * w, a2 * w, a3 * w);
  }
}

// item rows only: MACC[item] = f2bf(itemF + F1*inv1 + F2*inv2)
__global__ void k_acc_items(const float* __restrict__ itemF, const int* __restrict__ cnt,
                            const unsigned short* __restrict__ M1, const unsigned short* __restrict__ F2b,
                            const float* __restrict__ INV1, const float* __restrict__ INV2,
                            unsigned short* __restrict__ MACC) {
  long idx = (long)blockIdx.x * 256 + threadIdx.x;
  if (idx >= (long)NIc * 64) return;
  int rl = (int)(idx >> 6);
  int g = NUc + rl;
  long gi = (long)g * 64 + (idx & 63);
  float rs = sqrtf((float)cnt[g]) + 1e-8f;
  float res = itemF[idx] + bf2f(M1[gi]) * rs * INV1[g] + bf2f(F2b[gi]) * INV2[g];
  MACC[idx] = f2bf(res);
}

// batch rows on-the-fly: wave per row; writes raw + normalized
__global__ void k_batch(const int* __restrict__ users, const int* __restrict__ bundles,
                        const float* __restrict__ userF, const float* __restrict__ bundF,
                        const int* __restrict__ cnt,
                        const unsigned short* __restrict__ M1, const unsigned short* __restrict__ F2b,
                        const float* __restrict__ INV1, const float* __restrict__ INV2,
                        const float* __restrict__ ILB, int B,
                        float* __restrict__ ILu, float* __restrict__ BLu,
                        float* __restrict__ ILb2, float* __restrict__ BLb2,
                        float* __restrict__ PN1, float* __restrict__ AN1,
                        float* __restrict__ PN2, float* __restrict__ AN2) {
  int w = blockIdx.x * 4 + (threadIdx.x >> 6);
  int lane = threadIdx.x & 63;
  if (w >= 6 * B) return;
  float val;
  float* rawDst; float* nrmDst = nullptr; int nrmRow = 0;
  if (w < 2 * B) {
    bool il = w < B;
    int j = il ? w : w - B;
    int u = users[j];
    int g = il ? u : GUB0 + u;
    long gi = (long)g * 64 + lane;
    float rs = sqrtf((float)cnt[g]) + 1e-8f;
    val = userF[(long)u * 64 + lane] + bf2f(M1[gi]) * rs * INV1[g] + bf2f(F2b[gi]) * INV2[g];
    rawDst = (il ? ILu : BLu) + (long)j * 64;
    nrmDst = il ? PN1 : AN1; nrmRow = j;
  } else if (w < 4 * B) {
    int j = w - 2 * B;
    int b = bundles[j];
    val = ILB[(long)b * 64 + lane];
    rawDst = ILb2 + (long)j * 64;
    if ((j & 1) == 0) { nrmDst = PN2; nrmRow = j >> 1; }
  } else {
    int j = w - 4 * B;
    int b = bundles[j];
    int g = GUB0 + NUc + b;
    long gi = (long)g * 64 + lane;
    float rs = sqrtf((float)cnt[g]) + 1e-8f;
    val = bundF[(long)b * 64 + lane] + bf2f(M1[gi]) * rs * INV1[g] + bf2f(F2b[gi]) * INV2[g];
    rawDst = BLb2 + (long)j * 64;
    if ((j & 1) == 0) { nrmDst = AN2; nrmRow = j >> 1; }
  }
  rawDst[lane] = val;
  float ss = wredsum(val * val);
  if (nrmDst) nrmDst[(long)nrmRow * 64 + lane] = val * (1.0f / fmaxf(sqrtf(ss), 1e-12f));
}

__global__ void k_bpr(const float* __restrict__ ILu, const float* __restrict__ ILb2,
                      const float* __restrict__ BLu, const float* __restrict__ BLb2,
                      int B, float* __restrict__ out) {
  int row = blockIdx.x * 4 + (threadIdx.x >> 6);
  int lane = threadIdx.x & 63;
  if (row >= B) return;
  float t = ILu[(long)row * 64 + lane] *
              (ILb2[(long)(2 * row) * 64 + lane] - ILb2[(long)(2 * row + 1) * 64 + lane]) +
            BLu[(long)row * 64 + lane] *
              (BLb2[(long)(2 * row) * 64 + lane] - BLb2[(long)(2 * row + 1) * 64 + lane]);
  float x = wredsum(t);
  if (lane == 0) {
    float ls = -(fmaxf(-x, 0.0f) + log1pf(expf(-fabsf(x))));
    unsafeAtomicAdd(&out[0], -ls / (float)B);
  }
}

// InfoNCE GEMM, z selects pair; conflict-free stride-16 columns
__global__ void k_gemm_nt2(const float* __restrict__ P1, const float* __restrict__ A1,
                           const float* __restrict__ P2, const float* __restrict__ A2,
                           float* __restrict__ S1o, float* __restrict__ S2o,
                           int N, float scale) {
  __shared__ float Ps[64][129];
  __shared__ float As[64][129];
  const float* P = blockIdx.z ? P2 : P1;
  const float* A = blockIdx.z ? A2 : A1;
  float* S = blockIdx.z ? S2o : S1o;
  int bi0 = blockIdx.y * 128, bj0 = blockIdx.x * 128;
  int t = threadIdx.x;
  #pragma unroll
  for (int sct = 0; sct < 8; sct++) {
    int idx4 = t + sct * 256;
    int r = idx4 >> 4, k = (idx4 & 15) << 2;
    int pr = min(bi0 + r, N - 1);
    int ar = min(bj0 + r, N - 1);
    float4 v = *(const float4*)(P + (long)pr * 64 + k);
    Ps[k][r] = v.x; Ps[k + 1][r] = v.y; Ps[k + 2][r] = v.z; Ps[k + 3][r] = v.w;
    float4 w = *(const float4*)(A + (long)ar * 64 + k);
    As[k][r] = w.x; As[k + 1][r] = w.y; As[k + 2][r] = w.z; As[k + 3][r] = w.w;
  }
  __syncthreads();
  int tx = t & 15, ty = t >> 4;
  float acc[8][8];
  #pragma unroll
  for (int i = 0; i < 8; i++)
    #pragma unroll
    for (int j = 0; j < 8; j++) acc[i][j] = 0.0f;
  #pragma unroll 4
  for (int k = 0; k < 64; k++) {
    float a[8], b[8];
    #pragma unroll
    for (int i = 0; i < 8; i++) a[i] = Ps[k][ty * 8 + i];
    #pragma unroll
    for (int j = 0; j < 8; j++) b[j] = As[k][tx + 16 * j];
    #pragma unroll
    for (int i = 0; i < 8; i++)
      #pragma unroll
      for (int j = 0; j < 8; j++) acc[i][j] = fmaf(a[i], b[j], acc[i][j]);
  }
  #pragma unroll
  for (int i = 0; i < 8; i++) {
    int row = bi0 + ty * 8 + i;
    if (row >= N) continue;
    #pragma unroll
    for (int j = 0; j < 8; j++) {
      int cc = bj0 + tx + 16 * j;
      if (cc < N) S[(long)row * N + cc] = acc[i][j] * scale;
    }
  }
}

__global__ void k_lse2(const float* __restrict__ S1, const float* __restrict__ S2,
                       int B, float coeff, float* __restrict__ out) {
  constexpr float L2E = 1.44269504f;
  int row = blockIdx.x * 4 + (threadIdx.x >> 6);
  int lane = threadIdx.x & 63;
  const float* Sr; int dg;
  if (row < B) { Sr = S1 + (long)row * B; dg = row; }
  else         { Sr = S2 + (long)(row - B) * B; dg = row - B; }
  float m = -1e30f, s = 0.0f;
  for (int w = 0; w < (B >> 8); w++) {
    float4 v = *(const float4*)(Sr + ((w << 6) + lane) * 4);
    float mx = fmaxf(fmaxf(v.x, v.y), fmaxf(v.z, v.w));
    if (mx > m) { s *= exp2f((m - mx) * L2E); m = mx; }
    s += exp2f((v.x - m) * L2E) + exp2f((v.y - m) * L2E) +
         exp2f((v.z - m) * L2E) + exp2f((v.w - m) * L2E);
  }
  #pragma unroll
  for (int o = 32; o >= 1; o >>= 1) {
    float m2 = __shfl_xor(m, o, 64), s2 = __shfl_xor(s, o, 64);
    float M = fmaxf(m, m2);
    s = s * exp2f((m - M) * L2E) + s2 * exp2f((m2 - M) * L2E);
    m = M;
  }
  if (lane == 0) {
    float lse = m + log2f(s) * 0.69314718f;
    unsafeAtomicAdd(&out[1], -(Sr[dg] - lse) * coeff);
  }
}

extern "C" void kernel_launch(void* const* d_in, const int* in_sizes, int n_in,
                              void* d_out, int out_size, void* d_ws, size_t ws_size,
                              hipStream_t stream) {
  const int* users   = (const int*)d_in[0];
  const int* bundles = (const int*)d_in[1];
  const int* ui_u    = (const int*)d_in[2];
  const int* ui_i    = (const int*)d_in[3];
  const int* ub_u    = (const int*)d_in[4];
  const int* ub_b    = (const int*)d_in[5];
  const int* bi_b    = (const int*)d_in[6];
  const int* bi_i    = (const int*)d_in[7];
  const float* userF = (const float*)d_in[8];
  const float* bundF = (const float*)d_in[9];
  const float* itemF = (const float*)d_in[10];
  float* out = (float*)d_out;

  const int B    = in_sizes[0];
  const int E_ui = in_sizes[2];
  const int E_ub = in_sizes[4];
  const int E_bi = in_sizes[6];
  const long E_all = 2L * E_ui + 2L * E_ub + E_bi;

  float* ws = (float*)d_ws;
  size_t off = 0;
  auto alloc = [&](size_t nfloat) -> float* {
    float* p = ws + off;
    off += (nfloat + 63) & ~(size_t)63;
    return p;
  };
  unsigned short* X  = (unsigned short*)alloc((size_t)GBI0 * 32); // 28.2 MB
  unsigned short* M1 = (unsigned short*)alloc((size_t)GBI0 * 32); // 28.2 MB
  unsigned int* binned = (unsigned int*)alloc((size_t)E_all);     // 24 MB packed
  int* colv  = (int*)alloc((size_t)E_all + 15 * (size_t)GTOT + 128);  // padded cols
  int* rp    = (int*)alloc(GTOT + 1);
  int* cnt   = (int*)alloc(GTOT + 1);
  float* INV1 = alloc(GTOT);
  float* INV2 = alloc(GTOT);
  float* ILB  = alloc((size_t)NBUc * 64);
  float* ILu  = alloc((size_t)B * 64);
  float* BLu  = alloc((size_t)B * 64);
  float* ILb2 = alloc((size_t)B * 128);
  float* BLb2 = alloc((size_t)B * 128);
  float* PN1  = alloc((size_t)B * 64);
  float* AN1  = alloc((size_t)B * 64);
  float* PN2  = alloc((size_t)B * 64);
  float* AN2  = alloc((size_t)B * 64);
  int* bCnt  = (int*)alloc(2049);
  int* bBase = (int*)alloc(2049);
  int* bCur  = (int*)alloc(2049);
  int* bsum  = (int*)alloc(256);
  (void)ws_size; (void)n_in; (void)out_size;

  // overlays into dead phases:
  unsigned short* F2b  = X;                        // layer-2 out overlays X (dead after l1)
  unsigned short* MACC = (unsigned short*)binned;  // 12.9 MB incl. zero row NIc; binned dead after csrfill
  float* S1 = (float*)X;                           // X/F2b dead after k_batch; B*B*4=16.8MB <= 28.2MB
  float* S2 = (float*)M1;                          // M1 dead after k_batch

  // ---- unified bucketed binning + padded CSR (all 3 graphs) ----
  hipMemsetAsync(bCnt, 0, sizeof(int) * NBK, stream);
  k_bcount_all<<<1024, 256, 0, stream>>>(ui_u, ui_i, ub_u, ub_b, bi_b, E_ui, E_ub, E_bi, bCnt);
  k_scan2048<<<1, 512, 0, stream>>>(bCnt, NBK, bBase, bCur);
  k_bin_all<<<1024, 256, 0, stream>>>(ui_u, ui_i, ub_u, ub_b, bi_b, bi_i,
                                      E_ui, E_ub, E_bi, bCur, binned);
  hipMemsetAsync(cnt, 0, sizeof(int) * (GTOT + 1), stream);
  k_rowhist_all<<<NBK, 256, 0, stream>>>(binned, bBase, cnt);
  {
    int scan_n = GTOT + 1;
    int nb1 = (scan_n + 1023) / 1024;
    k_scan_block_pad<<<nb1, 256, 0, stream>>>(cnt, scan_n, rp, bsum);
    k_scan_bsum<<<1, 256, 0, stream>>>(bsum, nb1);
    k_scan_add<<<(scan_n + 255) / 256, 256, 0, stream>>>(rp, scan_n, bsum);
  }
  k_csrfill_all<<<NBK, 256, 0, stream>>>(binned, bBase, rp, colv);

  // ---- propagate (UI + UB merged per layer) ----
  k_prescale_all<<<(int)(((long)GBI0 * 64 + 255) / 256), 256, 0, stream>>>(cnt, userF, bundF,
                                                                           itemF, X);
  k_spmm_g<<<(GBI0 + 3) / 4, 256, 0, stream>>>(rp, cnt, colv, X, M1, INV1, 0.5f, 1, GBI0);
  k_spmm_g<<<(GBI0 + 3) / 4, 256, 0, stream>>>(rp, cnt, colv, M1, F2b, INV2, 1.0f / 3.0f, 0, GBI0);
  // items -> bf16 mirror (MACC overlays binned; zero dummy row NIc first)
  hipMemsetAsync(MACC + (size_t)NIc * 64, 0, 128, stream);
  k_acc_items<<<(int)(((long)NIc * 64 + 255) / 256), 256, 0, stream>>>(
      itemF, cnt, M1, F2b, INV1, INV2, MACC);
  k_agg_g<<<(NBUc + 3) / 4, 256, 0, stream>>>(rp, cnt, colv, MACC, ILB, NBUc);
  k_batch<<<(6 * B + 3) / 4, 256, 0, stream>>>(users, bundles, userF, bundF, cnt, M1, F2b,
                                               INV1, INV2, ILB, B,
                                               ILu, BLu, ILb2, BLb2, PN1, AN1, PN2, AN2);

  // ---- losses ----
  hipMemsetAsync(out, 0, 2 * sizeof(float), stream);
  k_bpr<<<(B + 3) / 4, 256, 0, stream>>>(ILu, ILb2, BLu, BLb2, B, out);
  dim3 gg((B + 127) / 128, (B + 127) / 128, 2);
  k_gemm_nt2<<<gg, 256, 0, stream>>>(PN1, AN1, PN2, AN2, S1, S2, B, 4.0f);  // 1/C_TEMP
  k_lse2<<<(2 * B + 3) / 4, 256, 0, stream>>>(S1, S2, B, 0.5f / (float)B, out);
}

// Round 16
// 526.049 us; speedup vs baseline: 1.3094x; 1.0107x over previous
//
#include <hip/hip_runtime.h>
#include <hip/hip_bf16.h>
#include <math.h>

// CrossCBR R15 (resubmit after infra failure): (1) SpMM/agg unpack drops
// hi-word AND masks (raw dword as f32, <=2^-7 low-mantissa contamination —
// inside bf16 noise); (2) GEMM+LSE fused barrier-free via 16-lane shfl strip
// reduction (no S matrix) + tiny final.
static constexpr int NUc  = 50000;
static constexpr int NBUc = 20000;
static constexpr int NIc  = 100000;
static constexpr int NILc = 150000;           // UI graph nodes
static constexpr int NBLc = 70000;            // UB graph nodes
// global padded rows: UI [0,150016), UB [150016,220032), BI [220032,240128)
static constexpr int GUB0   = 150016;         // 1172*128
static constexpr int GBI0   = 220032;         // 1719*128
static constexpr int BK_UB0 = 1172;
static constexpr int BK_BI0 = 1719;
static constexpr int NBK    = 1876;
static constexpr int GTOT   = NBK * 128;      // 240128

__device__ __forceinline__ float wredsum(float v) {
  #pragma unroll
  for (int m = 32; m >= 1; m >>= 1) v += __shfl_xor(v, m, 64);
  return v;
}
__device__ __forceinline__ float bf2f(unsigned short h) {
  return __uint_as_float(((unsigned int)h) << 16);
}
__device__ __forceinline__ unsigned short f2bf(float f) {  // RNE
  unsigned int u = __float_as_uint(f);
  return (unsigned short)((u + 0x7FFFu + ((u >> 16) & 1u)) >> 16);
}

// ---------------- bucket counts (all 3 graphs, one launch) ----------------
__global__ void k_bcount_all(const int* __restrict__ ui_u, const int* __restrict__ ui_i,
                             const int* __restrict__ ub_u, const int* __restrict__ ub_b,
                             const int* __restrict__ bi_b,
                             int E_ui, int E_ub, int E_bi, int* __restrict__ bCnt) {
  __shared__ int hist[NBK];
  for (int i = threadIdx.x; i < NBK; i += 256) hist[i] = 0;
  __syncthreads();
  int b = blockIdx.x;
  if (b < 512) {
    int chunk = (E_ui + 511) / 512, c0 = b * chunk, c1 = min(E_ui, c0 + chunk);
    for (int e = c0 + (int)threadIdx.x; e < c1; e += 256) {
      atomicAdd(&hist[ui_u[e] >> 7], 1);
      atomicAdd(&hist[(ui_i[e] + NUc) >> 7], 1);
    }
  } else if (b < 768) {
    int lb = b - 512, chunk = (E_ub + 255) / 256, c0 = lb * chunk, c1 = min(E_ub, c0 + chunk);
    for (int e = c0 + (int)threadIdx.x; e < c1; e += 256) {
      atomicAdd(&hist[(GUB0 + ub_u[e]) >> 7], 1);
      atomicAdd(&hist[(GUB0 + NUc + ub_b[e]) >> 7], 1);
    }
  } else {
    int lb = b - 768, chunk = (E_bi + 255) / 256, c0 = lb * chunk, c1 = min(E_bi, c0 + chunk);
    for (int e = c0 + (int)threadIdx.x; e < c1; e += 256)
      atomicAdd(&hist[(GBI0 + bi_b[e]) >> 7], 1);
  }
  __syncthreads();
  for (int i = threadIdx.x; i < NBK; i += 256)
    if (hist[i]) atomicAdd(&bCnt[i], hist[i]);
}

// exclusive scan of n<=2048 elements, 1 block x 512
__global__ void k_scan2048(const int* __restrict__ in, int n,
                           int* __restrict__ outBase, int* __restrict__ outCur) {
  __shared__ int sh[512];
  int t = threadIdx.x, i0 = 4 * t;
  int v0 = (i0 < n) ? in[i0] : 0;
  int v1 = (i0 + 1 < n) ? in[i0 + 1] : 0;
  int v2 = (i0 + 2 < n) ? in[i0 + 2] : 0;
  int v3 = (i0 + 3 < n) ? in[i0 + 3] : 0;
  int ts = v0 + v1 + v2 + v3;
  sh[t] = ts;
  __syncthreads();
  for (int o = 1; o < 512; o <<= 1) {
    int x = (t >= o) ? sh[t - o] : 0;
    __syncthreads();
    sh[t] += x;
    __syncthreads();
  }
  int ex = sh[t] - ts;
  if (i0 < n)     { outBase[i0] = ex;                    outCur[i0] = ex; }
  if (i0 + 1 < n) { outBase[i0 + 1] = ex + v0;           outCur[i0 + 1] = ex + v0; }
  if (i0 + 2 < n) { outBase[i0 + 2] = ex + v0 + v1;      outCur[i0 + 2] = ex + v0 + v1; }
  if (i0 + 3 < n) { outBase[i0 + 3] = ex + v0 + v1 + v2; outCur[i0 + 3] = ex + v0 + v1 + v2; }
  if (t == 511) outBase[n] = sh[511];
}

// ---------------- bin all edges -> bucket-sorted packed (row7|col18) --------
__global__ void k_bin_all(const int* __restrict__ ui_u, const int* __restrict__ ui_i,
                          const int* __restrict__ ub_u, const int* __restrict__ ub_b,
                          const int* __restrict__ bi_b, const int* __restrict__ bi_i,
                          int E_ui, int E_ub, int E_bi,
                          int* __restrict__ bCur, unsigned int* __restrict__ binned) {
  __shared__ int hist[NBK];
  __shared__ int base[NBK];
  for (int i = threadIdx.x; i < NBK; i += 256) hist[i] = 0;
  __syncthreads();
  int b = blockIdx.x;
  int c0, c1, seg;
  if (b < 512)      { seg = 0; int ch = (E_ui + 511) / 512; c0 = b * ch; c1 = min(E_ui, c0 + ch); }
  else if (b < 768) { seg = 1; int ch = (E_ub + 255) / 256; c0 = (b - 512) * ch; c1 = min(E_ub, c0 + ch); }
  else              { seg = 2; int ch = (E_bi + 255) / 256; c0 = (b - 768) * ch; c1 = min(E_bi, c0 + ch); }
  for (int e = c0 + (int)threadIdx.x; e < c1; e += 256) {
    if (seg == 0) {
      atomicAdd(&hist[ui_u[e] >> 7], 1);
      atomicAdd(&hist[(ui_i[e] + NUc) >> 7], 1);
    } else if (seg == 1) {
      atomicAdd(&hist[(GUB0 + ub_u[e]) >> 7], 1);
      atomicAdd(&hist[(GUB0 + NUc + ub_b[e]) >> 7], 1);
    } else {
      atomicAdd(&hist[(GBI0 + bi_b[e]) >> 7], 1);
    }
  }
  __syncthreads();
  for (int i = threadIdx.x; i < NBK; i += 256) {
    int h = hist[i];
    base[i] = h ? atomicAdd(&bCur[i], h) : 0;
    hist[i] = 0;
  }
  __syncthreads();
  for (int e = c0 + (int)threadIdx.x; e < c1; e += 256) {
    if (seg == 0) {
      int u = ui_u[e], x = ui_i[e] + NUc;   // both < 2^18
      int b1 = u >> 7;
      binned[base[b1] + atomicAdd(&hist[b1], 1)] = ((unsigned)(u & 127) << 18) | (unsigned)x;
      int b2 = x >> 7;
      binned[base[b2] + atomicAdd(&hist[b2], 1)] = ((unsigned)(x & 127) << 18) | (unsigned)u;
    } else if (seg == 1) {
      int ul = ub_u[e], bl = NUc + ub_b[e];
      int r1 = GUB0 + ul, r2 = GUB0 + bl;
      int b1 = r1 >> 7;
      binned[base[b1] + atomicAdd(&hist[b1], 1)] = ((unsigned)(r1 & 127) << 18) | (unsigned)bl;
      int b2 = r2 >> 7;
      binned[base[b2] + atomicAdd(&hist[b2], 1)] = ((unsigned)(r2 & 127) << 18) | (unsigned)ul;
    } else {
      int r = GBI0 + bi_b[e];
      int b1 = r >> 7;
      binned[base[b1] + atomicAdd(&hist[b1], 1)] = ((unsigned)(r & 127) << 18) | (unsigned)bi_i[e];
    }
  }
}

// per-row degree (covers all padded rows)
__global__ void k_rowhist_all(const unsigned int* __restrict__ binned, const int* __restrict__ bBase,
                              int* __restrict__ cnt) {
  __shared__ int hist[128];
  int bk = blockIdx.x, rowbase = bk << 7;
  int s = bBase[bk], e = bBase[bk + 1];
  if (threadIdx.x < 128) hist[threadIdx.x] = 0;
  __syncthreads();
  for (int i = s + (int)threadIdx.x; i < e; i += 256)
    atomicAdd(&hist[binned[i] >> 18], 1);
  __syncthreads();
  if (threadIdx.x < 128) cnt[rowbase + (int)threadIdx.x] = hist[threadIdx.x];
}

// hierarchical scan of PADDED counts: pcnt = (cnt+15)&~15
__global__ void k_scan_block_pad(const int* __restrict__ in, int n, int* __restrict__ out,
                                 int* __restrict__ bsum) {
  __shared__ int sh[256];
  int t = threadIdx.x;
  long base = (long)blockIdx.x * 1024 + (long)t * 4;
  int v0 = (base     < n) ? ((in[base]     + 15) & ~15) : 0;
  int v1 = (base + 1 < n) ? ((in[base + 1] + 15) & ~15) : 0;
  int v2 = (base + 2 < n) ? ((in[base + 2] + 15) & ~15) : 0;
  int v3 = (base + 3 < n) ? ((in[base + 3] + 15) & ~15) : 0;
  int tsum = v0 + v1 + v2 + v3;
  sh[t] = tsum;
  __syncthreads();
  for (int o = 1; o < 256; o <<= 1) {
    int x = (t >= o) ? sh[t - o] : 0;
    __syncthreads();
    sh[t] += x;
    __syncthreads();
  }
  int excl = sh[t] - tsum;
  if (t == 255) bsum[blockIdx.x] = sh[255];
  if (base     < n) out[base]     = excl;
  if (base + 1 < n) out[base + 1] = excl + v0;
  if (base + 2 < n) out[base + 2] = excl + v0 + v1;
  if (base + 3 < n) out[base + 3] = excl + v0 + v1 + v2;
}

__global__ void k_scan_bsum(int* __restrict__ bsum, int nb) {  // nb <= 256
  __shared__ int sh[256];
  int t = threadIdx.x;
  int v = (t < nb) ? bsum[t] : 0;
  sh[t] = v;
  __syncthreads();
  for (int o = 1; o < 256; o <<= 1) {
    int x = (t >= o) ? sh[t - o] : 0;
    __syncthreads();
    sh[t] += x;
    __syncthreads();
  }
  if (t < nb) bsum[t] = sh[t] - v;
}

__global__ void k_scan_add(int* __restrict__ out, int n, const int* __restrict__ bsum) {
  long i = (long)blockIdx.x * 256 + threadIdx.x;
  if (i < n) out[i] += bsum[i >> 10];
}

// per-bucket CSR fill + tail padding with zero-row dummy cols
__global__ void k_csrfill_all(const unsigned int* __restrict__ binned, const int* __restrict__ bBase,
                              const int* __restrict__ rp, int* __restrict__ colv) {
  __shared__ int cur[128];
  int bk = blockIdx.x, rowbase = bk << 7;
  int xb, zpad;
  if (bk < BK_UB0)      { xb = 0;    zpad = NILc; }          // X zero row
  else if (bk < BK_BI0) { xb = GUB0; zpad = GUB0 + NBLc; }   // X zero row (UB side)
  else                  { xb = 0;    zpad = NIc; }           // MACC zero row
  int s = bBase[bk], e = bBase[bk + 1];
  if (threadIdx.x < 128) cur[threadIdx.x] = rp[rowbase + (int)threadIdx.x];
  __syncthreads();
  for (int i = s + (int)threadIdx.x; i < e; i += 256) {
    unsigned int pk = binned[i];
    int pos = atomicAdd(&cur[pk >> 18], 1);
    colv[pos] = xb + (int)(pk & 0x3FFFFu);
  }
  __syncthreads();
  if (threadIdx.x < 128) {
    int r = rowbase + (int)threadIdx.x;
    int end = rp[r + 1];
    for (int k = cur[threadIdx.x]; k < end; k++) colv[k] = zpad;
  }
}

// X[g] = f2bf(feat[g] * dinv[g]) over [0, GBI0); padding rows -> 0
__global__ void k_prescale_all(const int* __restrict__ cnt, const float* __restrict__ userF,
                               const float* __restrict__ bundF, const float* __restrict__ itemF,
                               unsigned short* __restrict__ X) {
  long idx = (long)blockIdx.x * 256 + threadIdx.x;
  if (idx >= (long)GBI0 * 64) return;
  int g = (int)(idx >> 6), d = (int)(idx & 63);
  float v = 0.0f;
  if (g < NILc) v = (g < NUc) ? userF[(long)g * 64 + d] : itemF[(long)(g - NUc) * 64 + d];
  else if (g >= GUB0 && g < GUB0 + NBLc) {
    int l = g - GUB0;
    v = (l < NUc) ? userF[(long)l * 64 + d] : bundF[(long)(l - NUc) * 64 + d];
  }
  float dinv = 1.0f / (sqrtf((float)cnt[g]) + 1e-8f);
  X[idx] = f2bf(v * dinv);
}

// ---------------- SpMM: padded-16, 4 independent gathers; no hi-masks -------
// hi-bf16 read as raw f32 (low-mantissa contamination <= 2^-7 rel, inside
// bf16 rounding noise) — saves 8 VALU insts per 16-edge iteration.
__global__ void k_spmm_g(const int* __restrict__ rp, const int* __restrict__ cnt,
                         const int* __restrict__ col, const unsigned short* __restrict__ X,
                         unsigned short* __restrict__ outB, float* __restrict__ outInv,
                         float scale, int mulDinv, int n) {
  int row = blockIdx.x * 4 + (threadIdx.x >> 6);
  if (row >= n) return;
  int lane = threadIdx.x & 63, q = lane >> 4, p = lane & 15;
  int s = rp[row], e = rp[row + 1];   // e-s multiple of 16
  const uint2* Xp = (const uint2*)X + p;
  float a0 = 0.f, a1 = 0.f, a2 = 0.f, a3 = 0.f;
  for (int eo = s + q; eo < e; eo += 16) {
    int c0 = col[eo], c1 = col[eo + 4], c2 = col[eo + 8], c3 = col[eo + 12];
    uint2 v0 = Xp[(size_t)c0 << 4];
    uint2 v1 = Xp[(size_t)c1 << 4];
    uint2 v2 = Xp[(size_t)c2 << 4];
    uint2 v3 = Xp[(size_t)c3 << 4];
    a0 += (__uint_as_float(v0.x << 16) + __uint_as_float(v1.x << 16)) +
          (__uint_as_float(v2.x << 16) + __uint_as_float(v3.x << 16));
    a1 += (__uint_as_float(v0.x) + __uint_as_float(v1.x)) +
          (__uint_as_float(v2.x) + __uint_as_float(v3.x));
    a2 += (__uint_as_float(v0.y << 16) + __uint_as_float(v1.y << 16)) +
          (__uint_as_float(v2.y << 16) + __uint_as_float(v3.y << 16));
    a3 += (__uint_as_float(v0.y) + __uint_as_float(v1.y)) +
          (__uint_as_float(v2.y) + __uint_as_float(v3.y));
  }
  a0 += __shfl_xor(a0, 32, 64); a1 += __shfl_xor(a1, 32, 64);
  a2 += __shfl_xor(a2, 32, 64); a3 += __shfl_xor(a3, 32, 64);
  a0 += __shfl_xor(a0, 16, 64); a1 += __shfl_xor(a1, 16, 64);
  a2 += __shfl_xor(a2, 16, 64); a3 += __shfl_xor(a3, 16, 64);
  float dinv = 1.0f / (sqrtf((float)cnt[row]) + 1e-8f);
  float f = dinv * scale;
  float r0 = a0 * f, r1 = a1 * f, r2 = a2 * f, r3 = a3 * f;
  float ss = r0 * r0 + r1 * r1 + r2 * r2 + r3 * r3;
  ss += __shfl_xor(ss, 8, 64); ss += __shfl_xor(ss, 4, 64);
  ss += __shfl_xor(ss, 2, 64); ss += __shfl_xor(ss, 1, 64);
  if (q == 0) {
    float mf = mulDinv ? dinv : 1.0f;
    uint2 m;
    m.x = (unsigned int)f2bf(r0 * mf) | ((unsigned int)f2bf(r1 * mf) << 16);
    m.y = (unsigned int)f2bf(r2 * mf) | ((unsigned int)f2bf(r3 * mf) << 16);
    *(uint2*)(outB + (size_t)row * 64 + p * 4) = m;
    if (p == 0) outInv[row] = 1.0f / fmaxf(sqrtf(ss), 1e-12f);
  }
}

// bundle mean-agg (BI rows; cols index MACC, dummy = zeroed row NIc)
__global__ void k_agg_g(const int* __restrict__ rp, const int* __restrict__ cnt,
                        const int* __restrict__ col, const unsigned short* __restrict__ MACC,
                        float* __restrict__ ILB, int n) {
  int rl = blockIdx.x * 4 + (threadIdx.x >> 6);
  if (rl >= n) return;
  int row = GBI0 + rl;
  int lane = threadIdx.x & 63, q = lane >> 4, p = lane & 15;
  int s = rp[row], e = rp[row + 1];
  const uint2* Xp = (const uint2*)MACC + p;
  float a0 = 0.f, a1 = 0.f, a2 = 0.f, a3 = 0.f;
  for (int eo = s + q; eo < e; eo += 16) {
    int c0 = col[eo], c1 = col[eo + 4], c2 = col[eo + 8], c3 = col[eo + 12];
    uint2 v0 = Xp[(size_t)c0 << 4];
    uint2 v1 = Xp[(size_t)c1 << 4];
    uint2 v2 = Xp[(size_t)c2 << 4];
    uint2 v3 = Xp[(size_t)c3 << 4];
    a0 += (__uint_as_float(v0.x << 16) + __uint_as_float(v1.x << 16)) +
          (__uint_as_float(v2.x << 16) + __uint_as_float(v3.x << 16));
    a1 += (__uint_as_float(v0.x) + __uint_as_float(v1.x)) +
          (__uint_as_float(v2.x) + __uint_as_float(v3.x));
    a2 += (__uint_as_float(v0.y << 16) + __uint_as_float(v1.y << 16)) +
          (__uint_as_float(v2.y << 16) + __uint_as_float(v3.y << 16));
    a3 += (__uint_as_float(v0.y) + __uint_as_float(v1.y)) +
          (__uint_as_float(v2.y) + __uint_as_float(v3.y));
  }
  a0 += __shfl_xor(a0, 32, 64); a1 += __shfl_xor(a1, 32, 64);
  a2 += __shfl_xor(a2, 32, 64); a3 += __shfl_xor(a3, 32, 64);
  a0 += __shfl_xor(a0, 16, 64); a1 += __shfl_xor(a1, 16, 64);
  a2 += __shfl_xor(a2, 16, 64); a3 += __shfl_xor(a3, 16, 64);
  if (q == 0) {
    float w = 1.0f / ((float)cnt[row] + 1e-8f);
    *(float4*)(ILB + (size_t)rl * 64 + p * 4) = make_float4(a0 * w, a1 * w, a2 * w, a3 * w);
  }
}

// item rows only: MACC[item] = f2bf(itemF + F1*inv1 + F2*inv2)
__global__ void k_acc_items(const float* __restrict__ itemF, const int* __restrict__ cnt,
                            const unsigned short* __restrict__ M1, const unsigned short* __restrict__ F2b,
                            const float* __restrict__ INV1, const float* __restrict__ INV2,
                            unsigned short* __restrict__ MACC) {
  long idx = (long)blockIdx.x * 256 + threadIdx.x;
  if (idx >= (long)NIc * 64) return;
  int rl = (int)(idx >> 6);
  int g = NUc + rl;
  long gi = (long)g * 64 + (idx & 63);
  float rs = sqrtf((float)cnt[g]) + 1e-8f;
  float res = itemF[idx] + bf2f(M1[gi]) * rs * INV1[g] + bf2f(F2b[gi]) * INV2[g];
  MACC[idx] = f2bf(res);
}

// batch rows on-the-fly: wave per row; writes raw + normalized
__global__ void k_batch(const int* __restrict__ users, const int* __restrict__ bundles,
                        const float* __restrict__ userF, const float* __restrict__ bundF,
                        const int* __restrict__ cnt,
                        const unsigned short* __restrict__ M1, const unsigned short* __restrict__ F2b,
                        const float* __restrict__ INV1, const float* __restrict__ INV2,
                        const float* __restrict__ ILB, int B,
                        float* __restrict__ ILu, float* __restrict__ BLu,
                        float* __restrict__ ILb2, float* __restrict__ BLb2,
                        float* __restrict__ PN1, float* __restrict__ AN1,
                        float* __restrict__ PN2, float* __restrict__ AN2) {
  int w = blockIdx.x * 4 + (threadIdx.x >> 6);
  int lane = threadIdx.x & 63;
  if (w >= 6 * B) return;
  float val;
  float* rawDst; float* nrmDst = nullptr; int nrmRow = 0;
  if (w < 2 * B) {
    bool il = w < B;
    int j = il ? w : w - B;
    int u = users[j];
    int g = il ? u : GUB0 + u;
    long gi = (long)g * 64 + lane;
    float rs = sqrtf((float)cnt[g]) + 1e-8f;
    val = userF[(long)u * 64 + lane] + bf2f(M1[gi]) * rs * INV1[g] + bf2f(F2b[gi]) * INV2[g];
    rawDst = (il ? ILu : BLu) + (long)j * 64;
    nrmDst = il ? PN1 : AN1; nrmRow = j;
  } else if (w < 4 * B) {
    int j = w - 2 * B;
    int b = bundles[j];
    val = ILB[(long)b * 64 + lane];
    rawDst = ILb2 + (long)j * 64;
    if ((j & 1) == 0) { nrmDst = PN2; nrmRow = j >> 1; }
  } else {
    int j = w - 4 * B;
    int b = bundles[j];
    int g = GUB0 + NUc + b;
    long gi = (long)g * 64 + lane;
    float rs = sqrtf((float)cnt[g]) + 1e-8f;
    val = bundF[(long)b * 64 + lane] + bf2f(M1[gi]) * rs * INV1[g] + bf2f(F2b[gi]) * INV2[g];
    rawDst = BLb2 + (long)j * 64;
    if ((j & 1) == 0) { nrmDst = AN2; nrmRow = j >> 1; }
  }
  rawDst[lane] = val;
  float ss = wredsum(val * val);
  if (nrmDst) nrmDst[(long)nrmRow * 64 + lane] = val * (1.0f / fmaxf(sqrtf(ss), 1e-12f));
}

__global__ void k_bpr(const float* __restrict__ ILu, const float* __restrict__ ILb2,
                      const float* __restrict__ BLu, const float* __restrict__ BLb2,
                      int B, float* __restrict__ out) {
  int row = blockIdx.x * 4 + (threadIdx.x >> 6);
  int lane = threadIdx.x & 63;
  if (row >= B) return;
  float t = ILu[(long)row * 64 + lane] *
              (ILb2[(long)(2 * row) * 64 + lane] - ILb2[(long)(2 * row + 1) * 64 + lane]) +
            BLu[(long)row * 64 + lane] *
              (BLb2[(long)(2 * row) * 64 + lane] - BLb2[(long)(2 * row + 1) * 64 + lane]);
  float x = wredsum(t);
  if (lane == 0) {
    float ls = -(fmaxf(-x, 0.0f) + log1pf(expf(-fabsf(x))));
    unsafeAtomicAdd(&out[0], -ls / (float)B);
  }
}

// ---------------- fused InfoNCE GEMM + barrier-free strip LSE ----------------
// grid (N/128, N/128, 2); per row-strip partial (max,sum) via 16-lane shfl
// reduction (tx groups are 16-lane aligned inside a wave) — no S matrix.
__global__ void k_gemm_lse(const float* __restrict__ P1, const float* __restrict__ A1,
                           const float* __restrict__ P2, const float* __restrict__ A2,
                           float* __restrict__ Pm, float* __restrict__ Ps,
                           float* __restrict__ Diag, int N, float scale) {
  __shared__ float PsS[64][129];
  __shared__ float AsS[64][129];
  constexpr float L2E = 1.44269504f;
  const float* P = blockIdx.z ? P2 : P1;
  const float* A = blockIdx.z ? A2 : A1;
  int bi0 = blockIdx.y * 128, bj0 = blockIdx.x * 128;
  int t = threadIdx.x;
  #pragma unroll
  for (int sct = 0; sct < 8; sct++) {
    int idx4 = t + sct * 256;
    int r = idx4 >> 4, k = (idx4 & 15) << 2;
    int pr = min(bi0 + r, N - 1);
    int ar = min(bj0 + r, N - 1);
    float4 v = *(const float4*)(P + (long)pr * 64 + k);
    PsS[k][r] = v.x; PsS[k + 1][r] = v.y; PsS[k + 2][r] = v.z; PsS[k + 3][r] = v.w;
    float4 w = *(const float4*)(A + (long)ar * 64 + k);
    AsS[k][r] = w.x; AsS[k + 1][r] = w.y; AsS[k + 2][r] = w.z; AsS[k + 3][r] = w.w;
  }
  __syncthreads();
  int tx = t & 15, ty = t >> 4;
  float acc[8][8];
  #pragma unroll
  for (int i = 0; i < 8; i++)
    #pragma unroll
    for (int j = 0; j < 8; j++) acc[i][j] = 0.0f;
  #pragma unroll 4
  for (int k = 0; k < 64; k++) {
    float a[8], b[8];
    #pragma unroll
    for (int i = 0; i < 8; i++) a[i] = PsS[k][ty * 8 + i];
    #pragma unroll
    for (int j = 0; j < 8; j++) b[j] = AsS[k][tx + 16 * j];
    #pragma unroll
    for (int i = 0; i < 8; i++)
      #pragma unroll
      for (int j = 0; j < 8; j++) acc[i][j] = fmaf(a[i], b[j], acc[i][j]);
  }
  bool diagBlk = (blockIdx.x == blockIdx.y);
  #pragma unroll
  for (int i = 0; i < 8; i++) {
    int lrow = ty * 8 + i;
    float xs[8], tm = -1e30f;
    #pragma unroll
    for (int j = 0; j < 8; j++) { xs[j] = acc[i][j] * scale; tm = fmaxf(tm, xs[j]); }
    float tsum = 0.f;
    #pragma unroll
    for (int j = 0; j < 8; j++) tsum += exp2f((xs[j] - tm) * L2E);
    #pragma unroll
    for (int o = 1; o <= 8; o <<= 1) {
      float m2 = __shfl_xor(tm, o, 64), s2 = __shfl_xor(tsum, o, 64);
      float M = fmaxf(tm, m2);
      tsum = tsum * exp2f((tm - M) * L2E) + s2 * exp2f((m2 - M) * L2E);
      tm = M;
    }
    if (tx == 0) {
      size_t o = ((size_t)blockIdx.z * N + bi0 + lrow) * 16 + blockIdx.x;
      Pm[o] = tm; Ps[o] = tsum;
    }
    if (diagBlk && tx == (lrow & 15))
      Diag[(size_t)blockIdx.z * N + bi0 + lrow] = xs[lrow >> 4];
  }
}

// final LSE reduce over 16 strips per (z,row)
__global__ void k_lse_final(const float* __restrict__ Pm, const float* __restrict__ Ps,
                            const float* __restrict__ Diag, int N, float coeff,
                            float* __restrict__ out) {
  constexpr float L2E = 1.44269504f;
  int idx = blockIdx.x * 4 + (threadIdx.x >> 6);
  if (idx >= 2 * N) return;
  int z = idx >= N ? 1 : 0, r = idx - z * N;
  int lane = threadIdx.x & 63;
  float m = -1e30f, s = 0.f;
  if (lane < 16) {
    size_t o = ((size_t)z * N + r) * 16 + lane;
    m = Pm[o]; s = Ps[o];
  }
  #pragma unroll
  for (int o = 8; o >= 1; o >>= 1) {
    float m2 = __shfl_xor(m, o, 64), s2 = __shfl_xor(s, o, 64);
    float M = fmaxf(m, m2);
    s = s * exp2f((m - M) * L2E) + s2 * exp2f((m2 - M) * L2E);
    m = M;
  }
  if (lane == 0) {
    float lse = m + log2f(s) * 0.69314718f;
    unsafeAtomicAdd(&out[1], -(Diag[(size_t)z * N + r] - lse) * coeff);
  }
}

extern "C" void kernel_launch(void* const* d_in, const int* in_sizes, int n_in,
                              void* d_out, int out_size, void* d_ws, size_t ws_size,
                              hipStream_t stream) {
  const int* users   = (const int*)d_in[0];
  const int* bundles = (const int*)d_in[1];
  const int* ui_u    = (const int*)d_in[2];
  const int* ui_i    = (const int*)d_in[3];
  const int* ub_u    = (const int*)d_in[4];
  const int* ub_b    = (const int*)d_in[5];
  const int* bi_b    = (const int*)d_in[6];
  const int* bi_i    = (const int*)d_in[7];
  const float* userF = (const float*)d_in[8];
  const float* bundF = (const float*)d_in[9];
  const float* itemF = (const float*)d_in[10];
  float* out = (float*)d_out;

  const int B    = in_sizes[0];
  const int E_ui = in_sizes[2];
  const int E_ub = in_sizes[4];
  const int E_bi = in_sizes[6];
  const long E_all = 2L * E_ui + 2L * E_ub + E_bi;

  float* ws = (float*)d_ws;
  size_t off = 0;
  auto alloc = [&](size_t nfloat) -> float* {
    float* p = ws + off;
    off += (nfloat + 63) & ~(size_t)63;
    return p;
  };
  unsigned short* X  = (unsigned short*)alloc((size_t)GBI0 * 32); // 28.2 MB
  unsigned short* M1 = (unsigned short*)alloc((size_t)GBI0 * 32); // 28.2 MB
  unsigned int* binned = (unsigned int*)alloc((size_t)E_all);     // 24 MB packed
  int* colv  = (int*)alloc((size_t)E_all + 15 * (size_t)GTOT + 128);  // padded cols
  int* rp    = (int*)alloc(GTOT + 1);
  int* cnt   = (int*)alloc(GTOT + 1);
  float* INV1 = alloc(GTOT);
  float* INV2 = alloc(GTOT);
  float* ILB  = alloc((size_t)NBUc * 64);
  float* ILu  = alloc((size_t)B * 64);
  float* BLu  = alloc((size_t)B * 64);
  float* ILb2 = alloc((size_t)B * 128);
  float* BLb2 = alloc((size_t)B * 128);
  float* PN1  = alloc((size_t)B * 64);
  float* AN1  = alloc((size_t)B * 64);
  float* PN2  = alloc((size_t)B * 64);
  float* AN2  = alloc((size_t)B * 64);
  float* Pm   = alloc((size_t)2 * B * 16);
  float* Ps   = alloc((size_t)2 * B * 16);
  float* Diag = alloc((size_t)2 * B);
  int* bCnt  = (int*)alloc(2049);
  int* bBase = (int*)alloc(2049);
  int* bCur  = (int*)alloc(2049);
  int* bsum  = (int*)alloc(256);
  (void)ws_size; (void)n_in; (void)out_size;

  // overlays into dead phases:
  unsigned short* F2b  = X;                        // layer-2 out overlays X (dead after l1)
  unsigned short* MACC = (unsigned short*)binned;  // 12.9 MB incl. zero row NIc; binned dead after csrfill

  // ---- unified bucketed binning + padded CSR (all 3 graphs) ----
  hipMemsetAsync(bCnt, 0, sizeof(int) * NBK, stream);
  k_bcount_all<<<1024, 256, 0, stream>>>(ui_u, ui_i, ub_u, ub_b, bi_b, E_ui, E_ub, E_bi, bCnt);
  k_scan2048<<<1, 512, 0, stream>>>(bCnt, NBK, bBase, bCur);
  k_bin_all<<<1024, 256, 0, stream>>>(ui_u, ui_i, ub_u, ub_b, bi_b, bi_i,
                                      E_ui, E_ub, E_bi, bCur, binned);
  hipMemsetAsync(cnt, 0, sizeof(int) * (GTOT + 1), stream);
  k_rowhist_all<<<NBK, 256, 0, stream>>>(binned, bBase, cnt);
  {
    int scan_n = GTOT + 1;
    int nb1 = (scan_n + 1023) / 1024;
    k_scan_block_pad<<<nb1, 256, 0, stream>>>(cnt, scan_n, rp, bsum);
    k_scan_bsum<<<1, 256, 0, stream>>>(bsum, nb1);
    k_scan_add<<<(scan_n + 255) / 256, 256, 0, stream>>>(rp, scan_n, bsum);
  }
  k_csrfill_all<<<NBK, 256, 0, stream>>>(binned, bBase, rp, colv);

  // ---- propagate (UI + UB merged per layer) ----
  k_prescale_all<<<(int)(((long)GBI0 * 64 + 255) / 256), 256, 0, stream>>>(cnt, userF, bundF,
                                                                           itemF, X);
  k_spmm_g<<<(GBI0 + 3) / 4, 256, 0, stream>>>(rp, cnt, colv, X, M1, INV1, 0.5f, 1, GBI0);
  k_spmm_g<<<(GBI0 + 3) / 4, 256, 0, stream>>>(rp, cnt, colv, M1, F2b, INV2, 1.0f / 3.0f, 0, GBI0);
  // items -> bf16 mirror (MACC overlays binned; zero dummy row NIc first)
  hipMemsetAsync(MACC + (size_t)NIc * 64, 0, 128, stream);
  k_acc_items<<<(int)(((long)NIc * 64 + 255) / 256), 256, 0, stream>>>(
      itemF, cnt, M1, F2b, INV1, INV2, MACC);
  k_agg_g<<<(NBUc + 3) / 4, 256, 0, stream>>>(rp, cnt, colv, MACC, ILB, NBUc);
  k_batch<<<(6 * B + 3) / 4, 256, 0, stream>>>(users, bundles, userF, bundF, cnt, M1, F2b,
                                               INV1, INV2, ILB, B,
                                               ILu, BLu, ILb2, BLb2, PN1, AN1, PN2, AN2);

  // ---- losses ----
  hipMemsetAsync(out, 0, 2 * sizeof(float), stream);
  k_bpr<<<(B + 3) / 4, 256, 0, stream>>>(ILu, ILb2, BLu, BLb2, B, out);
  dim3 gg((B + 127) / 128, (B + 127) / 128, 2);
  k_gemm_lse<<<gg, 256, 0, stream>>>(PN1, AN1, PN2, AN2, Pm, Ps, Diag, B, 4.0f);  // 1/C_TEMP
  k_lse_final<<<(2 * B + 3) / 4, 256, 0, stream>>>(Pm, Ps, Diag, B, 0.5f / (float)B, out);
}

// Round 19
// 492.437 us; speedup vs baseline: 1.3987x; 1.0683x over previous
//
#include <hip/hip_runtime.h>
#include <hip/hip_bf16.h>
#include <math.h>

// CrossCBR R17 (2nd resubmit after infra failures): fp8(e4m3,SCL=64) operands
// for both SpMM layers — gather rows 128B->64B (R16 proved SpMM is byte/
// gather-bound, not issue-bound: -20% VALU gave -1%). HW cvt_pk builtins for
// decode/encode. F2 output stays bf16.
static constexpr int NUc  = 50000;
static constexpr int NBUc = 20000;
static constexpr int NIc  = 100000;
static constexpr int NILc = 150000;
static constexpr int NBLc = 70000;
static constexpr int GUB0   = 150016;         // 1172*128
static constexpr int GBI0   = 220032;         // 1719*128
static constexpr int BK_UB0 = 1172;
static constexpr int BK_BI0 = 1719;
static constexpr int NBK    = 1876;
static constexpr int GTOT   = NBK * 128;      // 240128
static constexpr float SCL  = 64.0f;          // fp8 pre-scale (avoid denormal floor)
typedef float floatx2 __attribute__((ext_vector_type(2)));

__device__ __forceinline__ float wredsum(float v) {
  #pragma unroll
  for (int m = 32; m >= 1; m >>= 1) v += __shfl_xor(v, m, 64);
  return v;
}
__device__ __forceinline__ float bf2f(unsigned short h) {
  return __uint_as_float(((unsigned int)h) << 16);
}
__device__ __forceinline__ unsigned short f2bf(float f) {  // RNE
  unsigned int u = __float_as_uint(f);
  return (unsigned short)((u + 0x7FFFu + ((u >> 16) & 1u)) >> 16);
}
// decode one fp8 byte (shift into byte 0, constant sel)
__device__ __forceinline__ float fp8_1(unsigned int w, int byteIdx) {
  return __builtin_amdgcn_cvt_f32_fp8((w >> (8 * byteIdx)) & 0xFFu, 0);
}

// ---------------- bucket counts (all 3 graphs, one launch) ----------------
__global__ void k_bcount_all(const int* __restrict__ ui_u, const int* __restrict__ ui_i,
                             const int* __restrict__ ub_u, const int* __restrict__ ub_b,
                             const int* __restrict__ bi_b,
                             int E_ui, int E_ub, int E_bi, int* __restrict__ bCnt) {
  __shared__ int hist[NBK];
  for (int i = threadIdx.x; i < NBK; i += 256) hist[i] = 0;
  __syncthreads();
  int b = blockIdx.x;
  if (b < 512) {
    int chunk = (E_ui + 511) / 512, c0 = b * chunk, c1 = min(E_ui, c0 + chunk);
    for (int e = c0 + (int)threadIdx.x; e < c1; e += 256) {
      atomicAdd(&hist[ui_u[e] >> 7], 1);
      atomicAdd(&hist[(ui_i[e] + NUc) >> 7], 1);
    }
  } else if (b < 768) {
    int lb = b - 512, chunk = (E_ub + 255) / 256, c0 = lb * chunk, c1 = min(E_ub, c0 + chunk);
    for (int e = c0 + (int)threadIdx.x; e < c1; e += 256) {
      atomicAdd(&hist[(GUB0 + ub_u[e]) >> 7], 1);
      atomicAdd(&hist[(GUB0 + NUc + ub_b[e]) >> 7], 1);
    }
  } else {
    int lb = b - 768, chunk = (E_bi + 255) / 256, c0 = lb * chunk, c1 = min(E_bi, c0 + chunk);
    for (int e = c0 + (int)threadIdx.x; e < c1; e += 256)
      atomicAdd(&hist[(GBI0 + bi_b[e]) >> 7], 1);
  }
  __syncthreads();
  for (int i = threadIdx.x; i < NBK; i += 256)
    if (hist[i]) atomicAdd(&bCnt[i], hist[i]);
}

__global__ void k_scan2048(const int* __restrict__ in, int n,
                           int* __restrict__ outBase, int* __restrict__ outCur) {
  __shared__ int sh[512];
  int t = threadIdx.x, i0 = 4 * t;
  int v0 = (i0 < n) ? in[i0] : 0;
  int v1 = (i0 + 1 < n) ? in[i0 + 1] : 0;
  int v2 = (i0 + 2 < n) ? in[i0 + 2] : 0;
  int v3 = (i0 + 3 < n) ? in[i0 + 3] : 0;
  int ts = v0 + v1 + v2 + v3;
  sh[t] = ts;
  __syncthreads();
  for (int o = 1; o < 512; o <<= 1) {
    int x = (t >= o) ? sh[t - o] : 0;
    __syncthreads();
    sh[t] += x;
    __syncthreads();
  }
  int ex = sh[t] - ts;
  if (i0 < n)     { outBase[i0] = ex;                    outCur[i0] = ex; }
  if (i0 + 1 < n) { outBase[i0 + 1] = ex + v0;           outCur[i0 + 1] = ex + v0; }
  if (i0 + 2 < n) { outBase[i0 + 2] = ex + v0 + v1;      outCur[i0 + 2] = ex + v0 + v1; }
  if (i0 + 3 < n) { outBase[i0 + 3] = ex + v0 + v1 + v2; outCur[i0 + 3] = ex + v0 + v1 + v2; }
  if (t == 511) outBase[n] = sh[511];
}

__global__ void k_bin_all(const int* __restrict__ ui_u, const int* __restrict__ ui_i,
                          const int* __restrict__ ub_u, const int* __restrict__ ub_b,
                          const int* __restrict__ bi_b, const int* __restrict__ bi_i,
                          int E_ui, int E_ub, int E_bi,
                          int* __restrict__ bCur, unsigned int* __restrict__ binned) {
  __shared__ int hist[NBK];
  __shared__ int base[NBK];
  for (int i = threadIdx.x; i < NBK; i += 256) hist[i] = 0;
  __syncthreads();
  int b = blockIdx.x;
  int c0, c1, seg;
  if (b < 512)      { seg = 0; int ch = (E_ui + 511) / 512; c0 = b * ch; c1 = min(E_ui, c0 + ch); }
  else if (b < 768) { seg = 1; int ch = (E_ub + 255) / 256; c0 = (b - 512) * ch; c1 = min(E_ub, c0 + ch); }
  else              { seg = 2; int ch = (E_bi + 255) / 256; c0 = (b - 768) * ch; c1 = min(E_bi, c0 + ch); }
  for (int e = c0 + (int)threadIdx.x; e < c1; e += 256) {
    if (seg == 0) {
      atomicAdd(&hist[ui_u[e] >> 7], 1);
      atomicAdd(&hist[(ui_i[e] + NUc) >> 7], 1);
    } else if (seg == 1) {
      atomicAdd(&hist[(GUB0 + ub_u[e]) >> 7], 1);
      atomicAdd(&hist[(GUB0 + NUc + ub_b[e]) >> 7], 1);
    } else {
      atomicAdd(&hist[(GBI0 + bi_b[e]) >> 7], 1);
    }
  }
  __syncthreads();
  for (int i = threadIdx.x; i < NBK; i += 256) {
    int h = hist[i];
    base[i] = h ? atomicAdd(&bCur[i], h) : 0;
    hist[i] = 0;
  }
  __syncthreads();
  for (int e = c0 + (int)threadIdx.x; e < c1; e += 256) {
    if (seg == 0) {
      int u = ui_u[e], x = ui_i[e] + NUc;
      int b1 = u >> 7;
      binned[base[b1] + atomicAdd(&hist[b1], 1)] = ((unsigned)(u & 127) << 18) | (unsigned)x;
      int b2 = x >> 7;
      binned[base[b2] + atomicAdd(&hist[b2], 1)] = ((unsigned)(x & 127) << 18) | (unsigned)u;
    } else if (seg == 1) {
      int ul = ub_u[e], bl = NUc + ub_b[e];
      int r1 = GUB0 + ul, r2 = GUB0 + bl;
      int b1 = r1 >> 7;
      binned[base[b1] + atomicAdd(&hist[b1], 1)] = ((unsigned)(r1 & 127) << 18) | (unsigned)bl;
      int b2 = r2 >> 7;
      binned[base[b2] + atomicAdd(&hist[b2], 1)] = ((unsigned)(r2 & 127) << 18) | (unsigned)ul;
    } else {
      int r = GBI0 + bi_b[e];
      int b1 = r >> 7;
      binned[base[b1] + atomicAdd(&hist[b1], 1)] = ((unsigned)(r & 127) << 18) | (unsigned)bi_i[e];
    }
  }
}

__global__ void k_rowhist_all(const unsigned int* __restrict__ binned, const int* __restrict__ bBase,
                              int* __restrict__ cnt) {
  __shared__ int hist[128];
  int bk = blockIdx.x, rowbase = bk << 7;
  int s = bBase[bk], e = bBase[bk + 1];
  if (threadIdx.x < 128) hist[threadIdx.x] = 0;
  __syncthreads();
  for (int i = s + (int)threadIdx.x; i < e; i += 256)
    atomicAdd(&hist[binned[i] >> 18], 1);
  __syncthreads();
  if (threadIdx.x < 128) cnt[rowbase + (int)threadIdx.x] = hist[threadIdx.x];
}

__global__ void k_scan_block_pad(const int* __restrict__ in, int n, int* __restrict__ out,
                                 int* __restrict__ bsum) {
  __shared__ int sh[256];
  int t = threadIdx.x;
  long base = (long)blockIdx.x * 1024 + (long)t * 4;
  int v0 = (base     < n) ? ((in[base]     + 15) & ~15) : 0;
  int v1 = (base + 1 < n) ? ((in[base + 1] + 15) & ~15) : 0;
  int v2 = (base + 2 < n) ? ((in[base + 2] + 15) & ~15) : 0;
  int v3 = (base + 3 < n) ? ((in[base + 3] + 15) & ~15) : 0;
  int tsum = v0 + v1 + v2 + v3;
  sh[t] = tsum;
  __syncthreads();
  for (int o = 1; o < 256; o <<= 1) {
    int x = (t >= o) ? sh[t - o] : 0;
    __syncthreads();
    sh[t] += x;
    __syncthreads();
  }
  int excl = sh[t] - tsum;
  if (t == 255) bsum[blockIdx.x] = sh[255];
  if (base     < n) out[base]     = excl;
  if (base + 1 < n) out[base + 1] = excl + v0;
  if (base + 2 < n) out[base + 2] = excl + v0 + v1;
  if (base + 3 < n) out[base + 3] = excl + v0 + v1 + v2;
}

__global__ void k_scan_bsum(int* __restrict__ bsum, int nb) {
  __shared__ int sh[256];
  int t = threadIdx.x;
  int v = (t < nb) ? bsum[t] : 0;
  sh[t] = v;
  __syncthreads();
  for (int o = 1; o < 256; o <<= 1) {
    int x = (t >= o) ? sh[t - o] : 0;
    __syncthreads();
    sh[t] += x;
    __syncthreads();
  }
  if (t < nb) bsum[t] = sh[t] - v;
}

__global__ void k_scan_add(int* __restrict__ out, int n, const int* __restrict__ bsum) {
  long i = (long)blockIdx.x * 256 + threadIdx.x;
  if (i < n) out[i] += bsum[i >> 10];
}

__global__ void k_csrfill_all(const unsigned int* __restrict__ binned, const int* __restrict__ bBase,
                              const int* __restrict__ rp, int* __restrict__ colv) {
  __shared__ int cur[128];
  int bk = blockIdx.x, rowbase = bk << 7;
  int xb, zpad;
  if (bk < BK_UB0)      { xb = 0;    zpad = NILc; }
  else if (bk < BK_BI0) { xb = GUB0; zpad = GUB0 + NBLc; }
  else                  { xb = 0;    zpad = NIc; }
  int s = bBase[bk], e = bBase[bk + 1];
  if (threadIdx.x < 128) cur[threadIdx.x] = rp[rowbase + (int)threadIdx.x];
  __syncthreads();
  for (int i = s + (int)threadIdx.x; i < e; i += 256) {
    unsigned int pk = binned[i];
    int pos = atomicAdd(&cur[pk >> 18], 1);
    colv[pos] = xb + (int)(pk & 0x3FFFFu);
  }
  __syncthreads();
  if (threadIdx.x < 128) {
    int r = rowbase + (int)threadIdx.x;
    int end = rp[r + 1];
    for (int k = cur[threadIdx.x]; k < end; k++) colv[k] = zpad;
  }
}

// X[g] (fp8) = e4m3(SCL * feat[g] * dinv[g]); thread per uint (4 dims)
__global__ void k_prescale_all(const int* __restrict__ cnt, const float* __restrict__ userF,
                               const float* __restrict__ bundF, const float* __restrict__ itemF,
                               unsigned int* __restrict__ X) {
  long idx = (long)blockIdx.x * 256 + threadIdx.x;   // uint index
  if (idx >= (long)GBI0 * 16) return;
  int g = (int)(idx >> 4), k4 = ((int)idx & 15) << 2;
  float4 v = make_float4(0.f, 0.f, 0.f, 0.f);
  if (g < NILc) {
    const float* src = (g < NUc) ? userF + (long)g * 64 : itemF + (long)(g - NUc) * 64;
    v = *(const float4*)(src + k4);
  } else if (g >= GUB0 && g < GUB0 + NBLc) {
    int l = g - GUB0;
    const float* src = (l < NUc) ? userF + (long)l * 64 : bundF + (long)(l - NUc) * 64;
    v = *(const float4*)(src + k4);
  }
  float f = SCL / (sqrtf((float)cnt[g]) + 1e-8f);
  unsigned int w = 0;
  w = __builtin_amdgcn_cvt_pk_fp8_f32(v.x * f, v.y * f, w, false);
  w = __builtin_amdgcn_cvt_pk_fp8_f32(v.z * f, v.w * f, w, true);
  X[idx] = w;
}

// ---------------- SpMM: fp8 gathers (64B/row), padded-16, 4 in flight -------
// layer1: outF8 = fp8(SCL*res*dinv), layer2: outB16 = bf16(res)
__global__ void k_spmm_g(const int* __restrict__ rp, const int* __restrict__ cnt,
                         const int* __restrict__ col, const unsigned int* __restrict__ X,
                         unsigned int* __restrict__ outF8, unsigned short* __restrict__ outB16,
                         float* __restrict__ outInv, float scale, int n) {
  int row = blockIdx.x * 4 + (threadIdx.x >> 6);
  if (row >= n) return;
  int lane = threadIdx.x & 63, q = lane >> 4, p = lane & 15;
  int s = rp[row], e = rp[row + 1];   // multiple of 16
  const unsigned int* Xp = X + p;
  float a0 = 0.f, a1 = 0.f, a2 = 0.f, a3 = 0.f;
  for (int eo = s + q; eo < e; eo += 16) {
    int c0 = col[eo], c1 = col[eo + 4], c2 = col[eo + 8], c3 = col[eo + 12];
    unsigned int w0 = Xp[(size_t)c0 << 4];
    unsigned int w1 = Xp[(size_t)c1 << 4];
    unsigned int w2 = Xp[(size_t)c2 << 4];
    unsigned int w3 = Xp[(size_t)c3 << 4];
    floatx2 l0 = __builtin_amdgcn_cvt_pk_f32_fp8(w0, false);
    floatx2 h0 = __builtin_amdgcn_cvt_pk_f32_fp8(w0, true);
    floatx2 l1 = __builtin_amdgcn_cvt_pk_f32_fp8(w1, false);
    floatx2 h1 = __builtin_amdgcn_cvt_pk_f32_fp8(w1, true);
    floatx2 l2 = __builtin_amdgcn_cvt_pk_f32_fp8(w2, false);
    floatx2 h2 = __builtin_amdgcn_cvt_pk_f32_fp8(w2, true);
    floatx2 l3 = __builtin_amdgcn_cvt_pk_f32_fp8(w3, false);
    floatx2 h3 = __builtin_amdgcn_cvt_pk_f32_fp8(w3, true);
    a0 += (l0.x + l1.x) + (l2.x + l3.x);
    a1 += (l0.y + l1.y) + (l2.y + l3.y);
    a2 += (h0.x + h1.x) + (h2.x + h3.x);
    a3 += (h0.y + h1.y) + (h2.y + h3.y);
  }
  a0 += __shfl_xor(a0, 32, 64); a1 += __shfl_xor(a1, 32, 64);
  a2 += __shfl_xor(a2, 32, 64); a3 += __shfl_xor(a3, 32, 64);
  a0 += __shfl_xor(a0, 16, 64); a1 += __shfl_xor(a1, 16, 64);
  a2 += __shfl_xor(a2, 16, 64); a3 += __shfl_xor(a3, 16, 64);
  float dinv = 1.0f / (sqrtf((float)cnt[row]) + 1e-8f);
  float f = dinv * scale * (1.0f / SCL);   // un-scale the fp8 pre-scale
  float r0 = a0 * f, r1 = a1 * f, r2 = a2 * f, r3 = a3 * f;
  float ss = r0 * r0 + r1 * r1 + r2 * r2 + r3 * r3;
  ss += __shfl_xor(ss, 8, 64); ss += __shfl_xor(ss, 4, 64);
  ss += __shfl_xor(ss, 2, 64); ss += __shfl_xor(ss, 1, 64);
  if (q == 0) {
    if (outF8) {
      float mf = dinv * SCL;
      unsigned int w = 0;
      w = __builtin_amdgcn_cvt_pk_fp8_f32(r0 * mf, r1 * mf, w, false);
      w = __builtin_amdgcn_cvt_pk_fp8_f32(r2 * mf, r3 * mf, w, true);
      outF8[(size_t)row * 16 + p] = w;
    } else {
      uint2 m;
      m.x = (unsigned int)f2bf(r0) | ((unsigned int)f2bf(r1) << 16);
      m.y = (unsigned int)f2bf(r2) | ((unsigned int)f2bf(r3) << 16);
      *(uint2*)(outB16 + (size_t)row * 64 + p * 4) = m;
    }
    if (p == 0) outInv[row] = 1.0f / fmaxf(sqrtf(ss), 1e-12f);
  }
}

// bundle mean-agg (bf16 MACC, unchanged; dummy = zeroed row NIc)
__global__ void k_agg_g(const int* __restrict__ rp, const int* __restrict__ cnt,
                        const int* __restrict__ col, const unsigned short* __restrict__ MACC,
                        float* __restrict__ ILB, int n) {
  int rl = blockIdx.x * 4 + (threadIdx.x >> 6);
  if (rl >= n) return;
  int row = GBI0 + rl;
  int lane = threadIdx.x & 63, q = lane >> 4, p = lane & 15;
  int s = rp[row], e = rp[row + 1];
  const uint2* Xp = (const uint2*)MACC + p;
  float a0 = 0.f, a1 = 0.f, a2 = 0.f, a3 = 0.f;
  for (int eo = s + q; eo < e; eo += 16) {
    int c0 = col[eo], c1 = col[eo + 4], c2 = col[eo + 8], c3 = col[eo + 12];
    uint2 v0 = Xp[(size_t)c0 << 4];
    uint2 v1 = Xp[(size_t)c1 << 4];
    uint2 v2 = Xp[(size_t)c2 << 4];
    uint2 v3 = Xp[(size_t)c3 << 4];
    a0 += (__uint_as_float(v0.x << 16) + __uint_as_float(v1.x << 16)) +
          (__uint_as_float(v2.x << 16) + __uint_as_float(v3.x << 16));
    a1 += (__uint_as_float(v0.x) + __uint_as_float(v1.x)) +
          (__uint_as_float(v2.x) + __uint_as_float(v3.x));
    a2 += (__uint_as_float(v0.y << 16) + __uint_as_float(v1.y << 16)) +
          (__uint_as_float(v2.y << 16) + __uint_as_float(v3.y << 16));
    a3 += (__uint_as_float(v0.y) + __uint_as_float(v1.y)) +
          (__uint_as_float(v2.y) + __uint_as_float(v3.y));
  }
  a0 += __shfl_xor(a0, 32, 64); a1 += __shfl_xor(a1, 32, 64);
  a2 += __shfl_xor(a2, 32, 64); a3 += __shfl_xor(a3, 32, 64);
  a0 += __shfl_xor(a0, 16, 64); a1 += __shfl_xor(a1, 16, 64);
  a2 += __shfl_xor(a2, 16, 64); a3 += __shfl_xor(a3, 16, 64);
  if (q == 0) {
    float w = 1.0f / ((float)cnt[row] + 1e-8f);
    *(float4*)(ILB + (size_t)rl * 64 + p * 4) = make_float4(a0 * w, a1 * w, a2 * w, a3 * w);
  }
}

// item rows: MACC[item] = f2bf(itemF + F1*inv1 + F2*inv2); M1 is fp8
__global__ void k_acc_items(const float* __restrict__ itemF, const int* __restrict__ cnt,
                            const unsigned int* __restrict__ M1, const unsigned short* __restrict__ F2b,
                            const float* __restrict__ INV1, const float* __restrict__ INV2,
                            unsigned short* __restrict__ MACC) {
  long idx = (long)blockIdx.x * 256 + threadIdx.x;
  if (idx >= (long)NIc * 64) return;
  int rl = (int)(idx >> 6), d = (int)(idx & 63);
  int g = NUc + rl;
  long gi = (long)g * 64 + d;
  float rs = sqrtf((float)cnt[g]) + 1e-8f;
  float m1v = fp8_1(M1[gi >> 2], d & 3) * (1.0f / SCL);
  float res = itemF[idx] + m1v * rs * INV1[g] + bf2f(F2b[gi]) * INV2[g];
  MACC[idx] = f2bf(res);
}

// batch rows on-the-fly; M1 fp8, F2b bf16
__global__ void k_batch(const int* __restrict__ users, const int* __restrict__ bundles,
                        const float* __restrict__ userF, const float* __restrict__ bundF,
                        const int* __restrict__ cnt,
                        const unsigned int* __restrict__ M1, const unsigned short* __restrict__ F2b,
                        const float* __restrict__ INV1, const float* __restrict__ INV2,
                        const float* __restrict__ ILB, int B,
                        float* __restrict__ ILu, float* __restrict__ BLu,
                        float* __restrict__ ILb2, float* __restrict__ BLb2,
                        float* __restrict__ PN1, float* __restrict__ AN1,
                        float* __restrict__ PN2, float* __restrict__ AN2) {
  int w = blockIdx.x * 4 + (threadIdx.x >> 6);
  int lane = threadIdx.x & 63;
  if (w >= 6 * B) return;
  float val;
  float* rawDst; float* nrmDst = nullptr; int nrmRow = 0;
  if (w < 2 * B) {
    bool il = w < B;
    int j = il ? w : w - B;
    int u = users[j];
    int g = il ? u : GUB0 + u;
    long gi = (long)g * 64 + lane;
    float rs = sqrtf((float)cnt[g]) + 1e-8f;
    float m1v = fp8_1(M1[gi >> 2], lane & 3) * (1.0f / SCL);
    val = userF[(long)u * 64 + lane] + m1v * rs * INV1[g] + bf2f(F2b[gi]) * INV2[g];
    rawDst = (il ? ILu : BLu) + (long)j * 64;
    nrmDst = il ? PN1 : AN1; nrmRow = j;
  } else if (w < 4 * B) {
    int j = w - 2 * B;
    int b = bundles[j];
    val = ILB[(long)b * 64 + lane];
    rawDst = ILb2 + (long)j * 64;
    if ((j & 1) == 0) { nrmDst = PN2; nrmRow = j >> 1; }
  } else {
    int j = w - 4 * B;
    int b = bundles[j];
    int g = GUB0 + NUc + b;
    long gi = (long)g * 64 + lane;
    float rs = sqrtf((float)cnt[g]) + 1e-8f;
    float m1v = fp8_1(M1[gi >> 2], lane & 3) * (1.0f / SCL);
    val = bundF[(long)b * 64 + lane] + m1v * rs * INV1[g] + bf2f(F2b[gi]) * INV2[g];
    rawDst = BLb2 + (long)j * 64;
    if ((j & 1) == 0) { nrmDst = AN2; nrmRow = j >> 1; }
  }
  rawDst[lane] = val;
  float ss = wredsum(val * val);
  if (nrmDst) nrmDst[(long)nrmRow * 64 + lane] = val * (1.0f / fmaxf(sqrtf(ss), 1e-12f));
}

__global__ void k_bpr(const float* __restrict__ ILu, const float* __restrict__ ILb2,
                      const float* __restrict__ BLu, const float* __restrict__ BLb2,
                      int B, float* __restrict__ out) {
  int row = blockIdx.x * 4 + (threadIdx.x >> 6);
  int lane = threadIdx.x & 63;
  if (row >= B) return;
  float t = ILu[(long)row * 64 + lane] *
              (ILb2[(long)(2 * row) * 64 + lane] - ILb2[(long)(2 * row + 1) * 64 + lane]) +
            BLu[(long)row * 64 + lane] *
              (BLb2[(long)(2 * row) * 64 + lane] - BLb2[(long)(2 * row + 1) * 64 + lane]);
  float x = wredsum(t);
  if (lane == 0) {
    float ls = -(fmaxf(-x, 0.0f) + log1pf(expf(-fabsf(x))));
    unsafeAtomicAdd(&out[0], -ls / (float)B);
  }
}

// ---------------- fused InfoNCE GEMM + barrier-free strip LSE ----------------
__global__ void k_gemm_lse(const float* __restrict__ P1, const float* __restrict__ A1,
                           const float* __restrict__ P2, const float* __restrict__ A2,
                           float* __restrict__ Pm, float* __restrict__ Ps,
                           float* __restrict__ Diag, int N, float scale) {
  __shared__ float PsS[64][129];
  __shared__ float AsS[64][129];
  constexpr float L2E = 1.44269504f;
  const float* P = blockIdx.z ? P2 : P1;
  const float* A = blockIdx.z ? A2 : A1;
  int bi0 = blockIdx.y * 128, bj0 = blockIdx.x * 128;
  int t = threadIdx.x;
  #pragma unroll
  for (int sct = 0; sct < 8; sct++) {
    int idx4 = t + sct * 256;
    int r = idx4 >> 4, k = (idx4 & 15) << 2;
    int pr = min(bi0 + r, N - 1);
    int ar = min(bj0 + r, N - 1);
    float4 v = *(const float4*)(P + (long)pr * 64 + k);
    PsS[k][r] = v.x; PsS[k + 1][r] = v.y; PsS[k + 2][r] = v.z; PsS[k + 3][r] = v.w;
    float4 w = *(const float4*)(A + (long)ar * 64 + k);
    AsS[k][r] = w.x; AsS[k + 1][r] = w.y; AsS[k + 2][r] = w.z; AsS[k + 3][r] = w.w;
  }
  __syncthreads();
  int tx = t & 15, ty = t >> 4;
  float acc[8][8];
  #pragma unroll
  for (int i = 0; i < 8; i++)
    #pragma unroll
    for (int j = 0; j < 8; j++) acc[i][j] = 0.0f;
  #pragma unroll 4
  for (int k = 0; k < 64; k++) {
    float a[8], b[8];
    #pragma unroll
    for (int i = 0; i < 8; i++) a[i] = PsS[k][ty * 8 + i];
    #pragma unroll
    for (int j = 0; j < 8; j++) b[j] = AsS[k][tx + 16 * j];
    #pragma unroll
    for (int i = 0; i < 8; i++)
      #pragma unroll
      for (int j = 0; j < 8; j++) acc[i][j] = fmaf(a[i], b[j], acc[i][j]);
  }
  bool diagBlk = (blockIdx.x == blockIdx.y);
  #pragma unroll
  for (int i = 0; i < 8; i++) {
    int lrow = ty * 8 + i;
    float xs[8], tm = -1e30f;
    #pragma unroll
    for (int j = 0; j < 8; j++) { xs[j] = acc[i][j] * scale; tm = fmaxf(tm, xs[j]); }
    float tsum = 0.f;
    #pragma unroll
    for (int j = 0; j < 8; j++) tsum += exp2f((xs[j] - tm) * L2E);
    #pragma unroll
    for (int o = 1; o <= 8; o <<= 1) {
      float m2 = __shfl_xor(tm, o, 64), s2 = __shfl_xor(tsum, o, 64);
      float M = fmaxf(tm, m2);
      tsum = tsum * exp2f((tm - M) * L2E) + s2 * exp2f((m2 - M) * L2E);
      tm = M;
    }
    if (tx == 0) {
      size_t o = ((size_t)blockIdx.z * N + bi0 + lrow) * 16 + blockIdx.x;
      Pm[o] = tm; Ps[o] = tsum;
    }
    if (diagBlk && tx == (lrow & 15))
      Diag[(size_t)blockIdx.z * N + bi0 + lrow] = xs[lrow >> 4];
  }
}

__global__ void k_lse_final(const float* __restrict__ Pm, const float* __restrict__ Ps,
                            const float* __restrict__ Diag, int N, float coeff,
                            float* __restrict__ out) {
  constexpr float L2E = 1.44269504f;
  int idx = blockIdx.x * 4 + (threadIdx.x >> 6);
  if (idx >= 2 * N) return;
  int z = idx >= N ? 1 : 0, r = idx - z * N;
  int lane = threadIdx.x & 63;
  float m = -1e30f, s = 0.f;
  if (lane < 16) {
    size_t o = ((size_t)z * N + r) * 16 + lane;
    m = Pm[o]; s = Ps[o];
  }
  #pragma unroll
  for (int o = 8; o >= 1; o >>= 1) {
    float m2 = __shfl_xor(m, o, 64), s2 = __shfl_xor(s, o, 64);
    float M = fmaxf(m, m2);
    s = s * exp2f((m - M) * L2E) + s2 * exp2f((m2 - M) * L2E);
    m = M;
  }
  if (lane == 0) {
    float lse = m + log2f(s) * 0.69314718f;
    unsafeAtomicAdd(&out[1], -(Diag[(size_t)z * N + r] - lse) * coeff);
  }
}

extern "C" void kernel_launch(void* const* d_in, const int* in_sizes, int n_in,
                              void* d_out, int out_size, void* d_ws, size_t ws_size,
                              hipStream_t stream) {
  const int* users   = (const int*)d_in[0];
  const int* bundles = (const int*)d_in[1];
  const int* ui_u    = (const int*)d_in[2];
  const int* ui_i    = (const int*)d_in[3];
  const int* ub_u    = (const int*)d_in[4];
  const int* ub_b    = (const int*)d_in[5];
  const int* bi_b    = (const int*)d_in[6];
  const int* bi_i    = (const int*)d_in[7];
  const float* userF = (const float*)d_in[8];
  const float* bundF = (const float*)d_in[9];
  const float* itemF = (const float*)d_in[10];
  float* out = (float*)d_out;

  const int B    = in_sizes[0];
  const int E_ui = in_sizes[2];
  const int E_ub = in_sizes[4];
  const int E_bi = in_sizes[6];
  const long E_all = 2L * E_ui + 2L * E_ub + E_bi;

  float* ws = (float*)d_ws;
  size_t off = 0;
  auto alloc = [&](size_t nfloat) -> float* {
    float* p = ws + off;
    off += (nfloat + 63) & ~(size_t)63;
    return p;
  };
  unsigned int* X  = (unsigned int*)alloc((size_t)GBI0 * 16);     // fp8, 14.1 MB
  unsigned int* M1 = (unsigned int*)alloc((size_t)GBI0 * 16);     // fp8, 14.1 MB
  unsigned short* F2b = (unsigned short*)alloc((size_t)GBI0 * 32);// bf16, 28.2 MB
  unsigned int* binned = (unsigned int*)alloc((size_t)E_all);     // 24 MB packed
  int* colv  = (int*)alloc((size_t)E_all + 15 * (size_t)GTOT + 128);
  int* rp    = (int*)alloc(GTOT + 1);
  int* cnt   = (int*)alloc(GTOT + 1);
  float* INV1 = alloc(GTOT);
  float* INV2 = alloc(GTOT);
  float* ILB  = alloc((size_t)NBUc * 64);
  float* ILu  = alloc((size_t)B * 64);
  float* BLu  = alloc((size_t)B * 64);
  float* ILb2 = alloc((size_t)B * 128);
  float* BLb2 = alloc((size_t)B * 128);
  float* PN1  = alloc((size_t)B * 64);
  float* AN1  = alloc((size_t)B * 64);
  float* PN2  = alloc((size_t)B * 64);
  float* AN2  = alloc((size_t)B * 64);
  float* Pm   = alloc((size_t)2 * B * 16);
  float* Ps   = alloc((size_t)2 * B * 16);
  float* Diag = alloc((size_t)2 * B);
  int* bCnt  = (int*)alloc(2049);
  int* bBase = (int*)alloc(2049);
  int* bCur  = (int*)alloc(2049);
  int* bsum  = (int*)alloc(256);
  (void)ws_size; (void)n_in; (void)out_size;

  // MACC (bf16 item mirror + zero row NIc) overlays binned (dead after csrfill)
  unsigned short* MACC = (unsigned short*)binned;

  // ---- unified bucketed binning + padded CSR ----
  hipMemsetAsync(bCnt, 0, sizeof(int) * NBK, stream);
  k_bcount_all<<<1024, 256, 0, stream>>>(ui_u, ui_i, ub_u, ub_b, bi_b, E_ui, E_ub, E_bi, bCnt);
  k_scan2048<<<1, 512, 0, stream>>>(bCnt, NBK, bBase, bCur);
  k_bin_all<<<1024, 256, 0, stream>>>(ui_u, ui_i, ub_u, ub_b, bi_b, bi_i,
                                      E_ui, E_ub, E_bi, bCur, binned);
  hipMemsetAsync(cnt, 0, sizeof(int) * (GTOT + 1), stream);
  k_rowhist_all<<<NBK, 256, 0, stream>>>(binned, bBase, cnt);
  {
    int scan_n = GTOT + 1;
    int nb1 = (scan_n + 1023) / 1024;
    k_scan_block_pad<<<nb1, 256, 0, stream>>>(cnt, scan_n, rp, bsum);
    k_scan_bsum<<<1, 256, 0, stream>>>(bsum, nb1);
    k_scan_add<<<(scan_n + 255) / 256, 256, 0, stream>>>(rp, scan_n, bsum);
  }
  k_csrfill_all<<<NBK, 256, 0, stream>>>(binned, bBase, rp, colv);

  // ---- propagate (UI + UB merged per layer; fp8 operands) ----
  k_prescale_all<<<(int)(((long)GBI0 * 16 + 255) / 256), 256, 0, stream>>>(cnt, userF, bundF,
                                                                           itemF, X);
  k_spmm_g<<<(GBI0 + 3) / 4, 256, 0, stream>>>(rp, cnt, colv, X, M1, nullptr, INV1, 0.5f, GBI0);
  k_spmm_g<<<(GBI0 + 3) / 4, 256, 0, stream>>>(rp, cnt, colv, M1, nullptr, F2b, INV2,
                                               1.0f / 3.0f, GBI0);
  hipMemsetAsync(MACC + (size_t)NIc * 64, 0, 128, stream);
  k_acc_items<<<(int)(((long)NIc * 64 + 255) / 256), 256, 0, stream>>>(
      itemF, cnt, M1, F2b, INV1, INV2, MACC);
  k_agg_g<<<(NBUc + 3) / 4, 256, 0, stream>>>(rp, cnt, colv, MACC, ILB, NBUc);
  k_batch<<<(6 * B + 3) / 4, 256, 0, stream>>>(users, bundles, userF, bundF, cnt, M1, F2b,
                                               INV1, INV2, ILB, B,
                                               ILu, BLu, ILb2, BLb2, PN1, AN1, PN2, AN2);

  // ---- losses ----
  hipMemsetAsync(out, 0, 2 * sizeof(float), stream);
  k_bpr<<<(B + 3) / 4, 256, 0, stream>>>(ILu, ILb2, BLu, BLb2, B, out);
  dim3 gg((B + 127) / 128, (B + 127) / 128, 2);
  k_gemm_lse<<<gg, 256, 0, stream>>>(PN1, AN1, PN2, AN2, Pm, Ps, Diag, B, 4.0f);  // 1/C_TEMP
  k_lse_final<<<(2 * B + 3) / 4, 256, 0, stream>>>(Pm, Ps, Diag, B, 0.5f / (float)B, out);
}

// Round 20
// 472.254 us; speedup vs baseline: 1.4585x; 1.0427x over previous
//
#include <hip/hip_runtime.h>
#include <hip/hip_bf16.h>
#include <math.h>

// CrossCBR R20: tail cuts on R19 (SpMM untouched at 96.5us, gather-bound):
// (1) acc_items fused into layer-2 SpMM epilogue (item rows emit fp8 mirror
// directly, skip F2b/INV2); (2) item mirror fp8 (agg gathers 128B->64B);
// (3) bundle-agg computed only at referenced bundles[j] (4096 waves, ILB gone).
static constexpr int NUc  = 50000;
static constexpr int NBUc = 20000;
static constexpr int NIc  = 100000;
static constexpr int NILc = 150000;
static constexpr int NBLc = 70000;
static constexpr int GUB0   = 150016;         // 1172*128
static constexpr int GBI0   = 220032;         // 1719*128
static constexpr int BK_UB0 = 1172;
static constexpr int BK_BI0 = 1719;
static constexpr int NBK    = 1876;
static constexpr int GTOT   = NBK * 128;      // 240128
static constexpr float SCL  = 64.0f;          // fp8 pre-scale
typedef float floatx2 __attribute__((ext_vector_type(2)));

__device__ __forceinline__ float wredsum(float v) {
  #pragma unroll
  for (int m = 32; m >= 1; m >>= 1) v += __shfl_xor(v, m, 64);
  return v;
}
__device__ __forceinline__ float bf2f(unsigned short h) {
  return __uint_as_float(((unsigned int)h) << 16);
}
__device__ __forceinline__ unsigned short f2bf(float f) {  // RNE
  unsigned int u = __float_as_uint(f);
  return (unsigned short)((u + 0x7FFFu + ((u >> 16) & 1u)) >> 16);
}
__device__ __forceinline__ float fp8_1(unsigned int w, int byteIdx) {
  return __builtin_amdgcn_cvt_f32_fp8((w >> (8 * byteIdx)) & 0xFFu, 0);
}

// ---------------- bucket counts (all 3 graphs, one launch) ----------------
__global__ void k_bcount_all(const int* __restrict__ ui_u, const int* __restrict__ ui_i,
                             const int* __restrict__ ub_u, const int* __restrict__ ub_b,
                             const int* __restrict__ bi_b,
                             int E_ui, int E_ub, int E_bi, int* __restrict__ bCnt) {
  __shared__ int hist[NBK];
  for (int i = threadIdx.x; i < NBK; i += 256) hist[i] = 0;
  __syncthreads();
  int b = blockIdx.x;
  if (b < 512) {
    int chunk = (E_ui + 511) / 512, c0 = b * chunk, c1 = min(E_ui, c0 + chunk);
    for (int e = c0 + (int)threadIdx.x; e < c1; e += 256) {
      atomicAdd(&hist[ui_u[e] >> 7], 1);
      atomicAdd(&hist[(ui_i[e] + NUc) >> 7], 1);
    }
  } else if (b < 768) {
    int lb = b - 512, chunk = (E_ub + 255) / 256, c0 = lb * chunk, c1 = min(E_ub, c0 + chunk);
    for (int e = c0 + (int)threadIdx.x; e < c1; e += 256) {
      atomicAdd(&hist[(GUB0 + ub_u[e]) >> 7], 1);
      atomicAdd(&hist[(GUB0 + NUc + ub_b[e]) >> 7], 1);
    }
  } else {
    int lb = b - 768, chunk = (E_bi + 255) / 256, c0 = lb * chunk, c1 = min(E_bi, c0 + chunk);
    for (int e = c0 + (int)threadIdx.x; e < c1; e += 256)
      atomicAdd(&hist[(GBI0 + bi_b[e]) >> 7], 1);
  }
  __syncthreads();
  for (int i = threadIdx.x; i < NBK; i += 256)
    if (hist[i]) atomicAdd(&bCnt[i], hist[i]);
}

__global__ void k_scan2048(const int* __restrict__ in, int n,
                           int* __restrict__ outBase, int* __restrict__ outCur) {
  __shared__ int sh[512];
  int t = threadIdx.x, i0 = 4 * t;
  int v0 = (i0 < n) ? in[i0] : 0;
  int v1 = (i0 + 1 < n) ? in[i0 + 1] : 0;
  int v2 = (i0 + 2 < n) ? in[i0 + 2] : 0;
  int v3 = (i0 + 3 < n) ? in[i0 + 3] : 0;
  int ts = v0 + v1 + v2 + v3;
  sh[t] = ts;
  __syncthreads();
  for (int o = 1; o < 512; o <<= 1) {
    int x = (t >= o) ? sh[t - o] : 0;
    __syncthreads();
    sh[t] += x;
    __syncthreads();
  }
  int ex = sh[t] - ts;
  if (i0 < n)     { outBase[i0] = ex;                    outCur[i0] = ex; }
  if (i0 + 1 < n) { outBase[i0 + 1] = ex + v0;           outCur[i0 + 1] = ex + v0; }
  if (i0 + 2 < n) { outBase[i0 + 2] = ex + v0 + v1;      outCur[i0 + 2] = ex + v0 + v1; }
  if (i0 + 3 < n) { outBase[i0 + 3] = ex + v0 + v1 + v2; outCur[i0 + 3] = ex + v0 + v1 + v2; }
  if (t == 511) outBase[n] = sh[511];
}

__global__ void k_bin_all(const int* __restrict__ ui_u, const int* __restrict__ ui_i,
                          const int* __restrict__ ub_u, const int* __restrict__ ub_b,
                          const int* __restrict__ bi_b, const int* __restrict__ bi_i,
                          int E_ui, int E_ub, int E_bi,
                          int* __restrict__ bCur, unsigned int* __restrict__ binned) {
  __shared__ int hist[NBK];
  __shared__ int base[NBK];
  for (int i = threadIdx.x; i < NBK; i += 256) hist[i] = 0;
  __syncthreads();
  int b = blockIdx.x;
  int c0, c1, seg;
  if (b < 512)      { seg = 0; int ch = (E_ui + 511) / 512; c0 = b * ch; c1 = min(E_ui, c0 + ch); }
  else if (b < 768) { seg = 1; int ch = (E_ub + 255) / 256; c0 = (b - 512) * ch; c1 = min(E_ub, c0 + ch); }
  else              { seg = 2; int ch = (E_bi + 255) / 256; c0 = (b - 768) * ch; c1 = min(E_bi, c0 + ch); }
  for (int e = c0 + (int)threadIdx.x; e < c1; e += 256) {
    if (seg == 0) {
      atomicAdd(&hist[ui_u[e] >> 7], 1);
      atomicAdd(&hist[(ui_i[e] + NUc) >> 7], 1);
    } else if (seg == 1) {
      atomicAdd(&hist[(GUB0 + ub_u[e]) >> 7], 1);
      atomicAdd(&hist[(GUB0 + NUc + ub_b[e]) >> 7], 1);
    } else {
      atomicAdd(&hist[(GBI0 + bi_b[e]) >> 7], 1);
    }
  }
  __syncthreads();
  for (int i = threadIdx.x; i < NBK; i += 256) {
    int h = hist[i];
    base[i] = h ? atomicAdd(&bCur[i], h) : 0;
    hist[i] = 0;
  }
  __syncthreads();
  for (int e = c0 + (int)threadIdx.x; e < c1; e += 256) {
    if (seg == 0) {
      int u = ui_u[e], x = ui_i[e] + NUc;
      int b1 = u >> 7;
      binned[base[b1] + atomicAdd(&hist[b1], 1)] = ((unsigned)(u & 127) << 18) | (unsigned)x;
      int b2 = x >> 7;
      binned[base[b2] + atomicAdd(&hist[b2], 1)] = ((unsigned)(x & 127) << 18) | (unsigned)u;
    } else if (seg == 1) {
      int ul = ub_u[e], bl = NUc + ub_b[e];
      int r1 = GUB0 + ul, r2 = GUB0 + bl;
      int b1 = r1 >> 7;
      binned[base[b1] + atomicAdd(&hist[b1], 1)] = ((unsigned)(r1 & 127) << 18) | (unsigned)bl;
      int b2 = r2 >> 7;
      binned[base[b2] + atomicAdd(&hist[b2], 1)] = ((unsigned)(r2 & 127) << 18) | (unsigned)ul;
    } else {
      int r = GBI0 + bi_b[e];
      int b1 = r >> 7;
      binned[base[b1] + atomicAdd(&hist[b1], 1)] = ((unsigned)(r & 127) << 18) | (unsigned)bi_i[e];
    }
  }
}

__global__ void k_rowhist_all(const unsigned int* __restrict__ binned, const int* __restrict__ bBase,
                              int* __restrict__ cnt) {
  __shared__ int hist[128];
  int bk = blockIdx.x, rowbase = bk << 7;
  int s = bBase[bk], e = bBase[bk + 1];
  if (threadIdx.x < 128) hist[threadIdx.x] = 0;
  __syncthreads();
  for (int i = s + (int)threadIdx.x; i < e; i += 256)
    atomicAdd(&hist[binned[i] >> 18], 1);
  __syncthreads();
  if (threadIdx.x < 128) cnt[rowbase + (int)threadIdx.x] = hist[threadIdx.x];
}

__global__ void k_scan_block_pad(const int* __restrict__ in, int n, int* __restrict__ out,
                                 int* __restrict__ bsum) {
  __shared__ int sh[256];
  int t = threadIdx.x;
  long base = (long)blockIdx.x * 1024 + (long)t * 4;
  int v0 = (base     < n) ? ((in[base]     + 15) & ~15) : 0;
  int v1 = (base + 1 < n) ? ((in[base + 1] + 15) & ~15) : 0;
  int v2 = (base + 2 < n) ? ((in[base + 2] + 15) & ~15) : 0;
  int v3 = (base + 3 < n) ? ((in[base + 3] + 15) & ~15) : 0;
  int tsum = v0 + v1 + v2 + v3;
  sh[t] = tsum;
  __syncthreads();
  for (int o = 1; o < 256; o <<= 1) {
    int x = (t >= o) ? sh[t - o] : 0;
    __syncthreads();
    sh[t] += x;
    __syncthreads();
  }
  int excl = sh[t] - tsum;
  if (t == 255) bsum[blockIdx.x] = sh[255];
  if (base     < n) out[base]     = excl;
  if (base + 1 < n) out[base + 1] = excl + v0;
  if (base + 2 < n) out[base + 2] = excl + v0 + v1;
  if (base + 3 < n) out[base + 3] = excl + v0 + v1 + v2;
}

__global__ void k_scan_bsum(int* __restrict__ bsum, int nb) {
  __shared__ int sh[256];
  int t = threadIdx.x;
  int v = (t < nb) ? bsum[t] : 0;
  sh[t] = v;
  __syncthreads();
  for (int o = 1; o < 256; o <<= 1) {
    int x = (t >= o) ? sh[t - o] : 0;
    __syncthreads();
    sh[t] += x;
    __syncthreads();
  }
  if (t < nb) bsum[t] = sh[t] - v;
}

__global__ void k_scan_add(int* __restrict__ out, int n, const int* __restrict__ bsum) {
  long i = (long)blockIdx.x * 256 + threadIdx.x;
  if (i < n) out[i] += bsum[i >> 10];
}

__global__ void k_csrfill_all(const unsigned int* __restrict__ binned, const int* __restrict__ bBase,
                              const int* __restrict__ rp, int* __restrict__ colv) {
  __shared__ int cur[128];
  int bk = blockIdx.x, rowbase = bk << 7;
  int xb, zpad;
  if (bk < BK_UB0)      { xb = 0;    zpad = NILc; }
  else if (bk < BK_BI0) { xb = GUB0; zpad = GUB0 + NBLc; }
  else                  { xb = 0;    zpad = NIc; }
  int s = bBase[bk], e = bBase[bk + 1];
  if (threadIdx.x < 128) cur[threadIdx.x] = rp[rowbase + (int)threadIdx.x];
  __syncthreads();
  for (int i = s + (int)threadIdx.x; i < e; i += 256) {
    unsigned int pk = binned[i];
    int pos = atomicAdd(&cur[pk >> 18], 1);
    colv[pos] = xb + (int)(pk & 0x3FFFFu);
  }
  __syncthreads();
  if (threadIdx.x < 128) {
    int r = rowbase + (int)threadIdx.x;
    int end = rp[r + 1];
    for (int k = cur[threadIdx.x]; k < end; k++) colv[k] = zpad;
  }
}

// X[g] (fp8) = e4m3(SCL * feat[g] * dinv[g]); thread per uint (4 dims)
__global__ void k_prescale_all(const int* __restrict__ cnt, const float* __restrict__ userF,
                               const float* __restrict__ bundF, const float* __restrict__ itemF,
                               unsigned int* __restrict__ X) {
  long idx = (long)blockIdx.x * 256 + threadIdx.x;
  if (idx >= (long)GBI0 * 16) return;
  int g = (int)(idx >> 4), k4 = ((int)idx & 15) << 2;
  float4 v = make_float4(0.f, 0.f, 0.f, 0.f);
  if (g < NILc) {
    const float* src = (g < NUc) ? userF + (long)g * 64 : itemF + (long)(g - NUc) * 64;
    v = *(const float4*)(src + k4);
  } else if (g >= GUB0 && g < GUB0 + NBLc) {
    int l = g - GUB0;
    const float* src = (l < NUc) ? userF + (long)l * 64 : bundF + (long)(l - NUc) * 64;
    v = *(const float4*)(src + k4);
  }
  float f = SCL / (sqrtf((float)cnt[g]) + 1e-8f);
  unsigned int w = 0;
  w = __builtin_amdgcn_cvt_pk_fp8_f32(v.x * f, v.y * f, w, false);
  w = __builtin_amdgcn_cvt_pk_fp8_f32(v.z * f, v.w * f, w, true);
  X[idx] = w;
}

// ---------------- SpMM: fp8 gathers, padded-16, 4 in flight -----------------
// layer1 (outF8!=0): M1 = fp8(SCL*res*dinv), INV1 written.
// layer2 (outF8==0): user/bundle rows -> F2b bf16 + INV2; ITEM rows -> fused
// acc: MACC8 = fp8(SCL*(itemF + F1*inv1 + F2*inv2)) directly (no F2b/INV2).
__global__ void k_spmm_g(const int* __restrict__ rp, const int* __restrict__ cnt,
                         const int* __restrict__ col, const unsigned int* __restrict__ X,
                         unsigned int* __restrict__ outF8, unsigned short* __restrict__ outB16,
                         float* __restrict__ outInv,
                         const float* __restrict__ itemF, const float* __restrict__ INV1in,
                         unsigned int* __restrict__ MACC8,
                         float scale, int n) {
  int row = blockIdx.x * 4 + (threadIdx.x >> 6);
  if (row >= n) return;
  int lane = threadIdx.x & 63, q = lane >> 4, p = lane & 15;
  int s = rp[row], e = rp[row + 1];   // multiple of 16
  const unsigned int* Xp = X + p;
  float a0 = 0.f, a1 = 0.f, a2 = 0.f, a3 = 0.f;
  for (int eo = s + q; eo < e; eo += 16) {
    int c0 = col[eo], c1 = col[eo + 4], c2 = col[eo + 8], c3 = col[eo + 12];
    unsigned int w0 = Xp[(size_t)c0 << 4];
    unsigned int w1 = Xp[(size_t)c1 << 4];
    unsigned int w2 = Xp[(size_t)c2 << 4];
    unsigned int w3 = Xp[(size_t)c3 << 4];
    floatx2 l0 = __builtin_amdgcn_cvt_pk_f32_fp8(w0, false);
    floatx2 h0 = __builtin_amdgcn_cvt_pk_f32_fp8(w0, true);
    floatx2 l1 = __builtin_amdgcn_cvt_pk_f32_fp8(w1, false);
    floatx2 h1 = __builtin_amdgcn_cvt_pk_f32_fp8(w1, true);
    floatx2 l2 = __builtin_amdgcn_cvt_pk_f32_fp8(w2, false);
    floatx2 h2 = __builtin_amdgcn_cvt_pk_f32_fp8(w2, true);
    floatx2 l3 = __builtin_amdgcn_cvt_pk_f32_fp8(w3, false);
    floatx2 h3 = __builtin_amdgcn_cvt_pk_f32_fp8(w3, true);
    a0 += (l0.x + l1.x) + (l2.x + l3.x);
    a1 += (l0.y + l1.y) + (l2.y + l3.y);
    a2 += (h0.x + h1.x) + (h2.x + h3.x);
    a3 += (h0.y + h1.y) + (h2.y + h3.y);
  }
  a0 += __shfl_xor(a0, 32, 64); a1 += __shfl_xor(a1, 32, 64);
  a2 += __shfl_xor(a2, 32, 64); a3 += __shfl_xor(a3, 32, 64);
  a0 += __shfl_xor(a0, 16, 64); a1 += __shfl_xor(a1, 16, 64);
  a2 += __shfl_xor(a2, 16, 64); a3 += __shfl_xor(a3, 16, 64);
  float rs = sqrtf((float)cnt[row]) + 1e-8f;
  float dinv = 1.0f / rs;
  float f = dinv * scale * (1.0f / SCL);
  float r0 = a0 * f, r1 = a1 * f, r2 = a2 * f, r3 = a3 * f;
  float ss = r0 * r0 + r1 * r1 + r2 * r2 + r3 * r3;
  ss += __shfl_xor(ss, 8, 64); ss += __shfl_xor(ss, 4, 64);
  ss += __shfl_xor(ss, 2, 64); ss += __shfl_xor(ss, 1, 64);
  if (q != 0) return;
  if (outF8) {  // layer 1
    float mf = dinv * SCL;
    unsigned int w = 0;
    w = __builtin_amdgcn_cvt_pk_fp8_f32(r0 * mf, r1 * mf, w, false);
    w = __builtin_amdgcn_cvt_pk_fp8_f32(r2 * mf, r3 * mf, w, true);
    outF8[(size_t)row * 16 + p] = w;
    if (p == 0) outInv[row] = 1.0f / fmaxf(sqrtf(ss), 1e-12f);
    return;
  }
  // layer 2
  if (row >= NUc && row < NILc) {  // item row: fused acc -> fp8 mirror
    float inv2 = 1.0f / fmaxf(sqrtf(ss), 1e-12f);
    unsigned int m1w = Xp[(size_t)row << 4];         // X here IS M1
    floatx2 mlo = __builtin_amdgcn_cvt_pk_f32_fp8(m1w, false);
    floatx2 mhi = __builtin_amdgcn_cvt_pk_f32_fp8(m1w, true);
    float s1 = rs * INV1in[row] * (1.0f / SCL);
    float4 bf = *(const float4*)(itemF + (long)(row - NUc) * 64 + p * 4);
    float o0 = bf.x + mlo.x * s1 + r0 * inv2;
    float o1 = bf.y + mlo.y * s1 + r1 * inv2;
    float o2 = bf.z + mhi.x * s1 + r2 * inv2;
    float o3 = bf.w + mhi.y * s1 + r3 * inv2;
    unsigned int w = 0;
    w = __builtin_amdgcn_cvt_pk_fp8_f32(o0 * SCL, o1 * SCL, w, false);
    w = __builtin_amdgcn_cvt_pk_fp8_f32(o2 * SCL, o3 * SCL, w, true);
    MACC8[(size_t)(row - NUc) * 16 + p] = w;
  } else {
    uint2 m;
    m.x = (unsigned int)f2bf(r0) | ((unsigned int)f2bf(r1) << 16);
    m.y = (unsigned int)f2bf(r2) | ((unsigned int)f2bf(r3) << 16);
    *(uint2*)(outB16 + (size_t)row * 64 + p * 4) = m;
    if (p == 0) outInv[row] = 1.0f / fmaxf(sqrtf(ss), 1e-12f);
  }
}

// bundle mean-agg at referenced bundles only: j in [0, 2B); fp8 MACC gathers
__global__ void k_agg_batch(const int* __restrict__ rp, const int* __restrict__ cnt,
                            const int* __restrict__ col, const unsigned int* __restrict__ MACC8,
                            const int* __restrict__ bundles, int nb2,
                            float* __restrict__ ILb2, float* __restrict__ PN2) {
  int j = blockIdx.x * 4 + (threadIdx.x >> 6);
  if (j >= nb2) return;
  int row = GBI0 + bundles[j];
  int lane = threadIdx.x & 63, q = lane >> 4, p = lane & 15;
  int s = rp[row], e = rp[row + 1];
  const unsigned int* Xp = MACC8 + p;
  float a0 = 0.f, a1 = 0.f, a2 = 0.f, a3 = 0.f;
  for (int eo = s + q; eo < e; eo += 16) {
    int c0 = col[eo], c1 = col[eo + 4], c2 = col[eo + 8], c3 = col[eo + 12];
    unsigned int w0 = Xp[(size_t)c0 << 4];
    unsigned int w1 = Xp[(size_t)c1 << 4];
    unsigned int w2 = Xp[(size_t)c2 << 4];
    unsigned int w3 = Xp[(size_t)c3 << 4];
    floatx2 l0 = __builtin_amdgcn_cvt_pk_f32_fp8(w0, false);
    floatx2 h0 = __builtin_amdgcn_cvt_pk_f32_fp8(w0, true);
    floatx2 l1 = __builtin_amdgcn_cvt_pk_f32_fp8(w1, false);
    floatx2 h1 = __builtin_amdgcn_cvt_pk_f32_fp8(w1, true);
    floatx2 l2 = __builtin_amdgcn_cvt_pk_f32_fp8(w2, false);
    floatx2 h2 = __builtin_amdgcn_cvt_pk_f32_fp8(w2, true);
    floatx2 l3 = __builtin_amdgcn_cvt_pk_f32_fp8(w3, false);
    floatx2 h3 = __builtin_amdgcn_cvt_pk_f32_fp8(w3, true);
    a0 += (l0.x + l1.x) + (l2.x + l3.x);
    a1 += (l0.y + l1.y) + (l2.y + l3.y);
    a2 += (h0.x + h1.x) + (h2.x + h3.x);
    a3 += (h0.y + h1.y) + (h2.y + h3.y);
  }
  a0 += __shfl_xor(a0, 32, 64); a1 += __shfl_xor(a1, 32, 64);
  a2 += __shfl_xor(a2, 32, 64); a3 += __shfl_xor(a3, 32, 64);
  a0 += __shfl_xor(a0, 16, 64); a1 += __shfl_xor(a1, 16, 64);
  a2 += __shfl_xor(a2, 16, 64); a3 += __shfl_xor(a3, 16, 64);
  float w = (1.0f / SCL) / ((float)cnt[row] + 1e-8f);
  float r0 = a0 * w, r1 = a1 * w, r2 = a2 * w, r3 = a3 * w;
  float ss = r0 * r0 + r1 * r1 + r2 * r2 + r3 * r3;
  ss += __shfl_xor(ss, 8, 64); ss += __shfl_xor(ss, 4, 64);
  ss += __shfl_xor(ss, 2, 64); ss += __shfl_xor(ss, 1, 64);
  if (q == 0) {
    *(float4*)(ILb2 + (size_t)j * 64 + p * 4) = make_float4(r0, r1, r2, r3);
    if ((j & 1) == 0) {
      float inv = 1.0f / fmaxf(sqrtf(ss), 1e-12f);
      *(float4*)(PN2 + (size_t)(j >> 1) * 64 + p * 4) =
          make_float4(r0 * inv, r1 * inv, r2 * inv, r3 * inv);
    }
  }
}

// batch rows on-the-fly: [0,B) ILu, [B,2B) BLu, [2B,4B) BLb2
__global__ void k_batch(const int* __restrict__ users, const int* __restrict__ bundles,
                        const float* __restrict__ userF, const float* __restrict__ bundF,
                        const int* __restrict__ cnt,
                        const unsigned int* __restrict__ M1, const unsigned short* __restrict__ F2b,
                        const float* __restrict__ INV1, const float* __restrict__ INV2,
                        int B,
                        float* __restrict__ ILu, float* __restrict__ BLu,
                        float* __restrict__ BLb2,
                        float* __restrict__ PN1, float* __restrict__ AN1,
                        float* __restrict__ AN2) {
  int w = blockIdx.x * 4 + (threadIdx.x >> 6);
  int lane = threadIdx.x & 63;
  if (w >= 4 * B) return;
  float val;
  float* rawDst; float* nrmDst = nullptr; int nrmRow = 0;
  if (w < 2 * B) {
    bool il = w < B;
    int j = il ? w : w - B;
    int u = users[j];
    int g = il ? u : GUB0 + u;
    long gi = (long)g * 64 + lane;
    float rs = sqrtf((float)cnt[g]) + 1e-8f;
    float m1v = fp8_1(M1[gi >> 2], lane & 3) * (1.0f / SCL);
    val = userF[(long)u * 64 + lane] + m1v * rs * INV1[g] + bf2f(F2b[gi]) * INV2[g];
    rawDst = (il ? ILu : BLu) + (long)j * 64;
    nrmDst = il ? PN1 : AN1; nrmRow = j;
  } else {
    int j = w - 2 * B;
    int b = bundles[j];
    int g = GUB0 + NUc + b;
    long gi = (long)g * 64 + lane;
    float rs = sqrtf((float)cnt[g]) + 1e-8f;
    float m1v = fp8_1(M1[gi >> 2], lane & 3) * (1.0f / SCL);
    val = bundF[(long)b * 64 + lane] + m1v * rs * INV1[g] + bf2f(F2b[gi]) * INV2[g];
    rawDst = BLb2 + (long)j * 64;
    if ((j & 1) == 0) { nrmDst = AN2; nrmRow = j >> 1; }
  }
  rawDst[lane] = val;
  float ss = wredsum(val * val);
  if (nrmDst) nrmDst[(long)nrmRow * 64 + lane] = val * (1.0f / fmaxf(sqrtf(ss), 1e-12f));
}

__global__ void k_bpr(const float* __restrict__ ILu, const float* __restrict__ ILb2,
                      const float* __restrict__ BLu, const float* __restrict__ BLb2,
                      int B, float* __restrict__ out) {
  int row = blockIdx.x * 4 + (threadIdx.x >> 6);
  int lane = threadIdx.x & 63;
  if (row >= B) return;
  float t = ILu[(long)row * 64 + lane] *
              (ILb2[(long)(2 * row) * 64 + lane] - ILb2[(long)(2 * row + 1) * 64 + lane]) +
            BLu[(long)row * 64 + lane] *
              (BLb2[(long)(2 * row) * 64 + lane] - BLb2[(long)(2 * row + 1) * 64 + lane]);
  float x = wredsum(t);
  if (lane == 0) {
    float ls = -(fmaxf(-x, 0.0f) + log1pf(expf(-fabsf(x))));
    unsafeAtomicAdd(&out[0], -ls / (float)B);
  }
}

// ---------------- fused InfoNCE GEMM + barrier-free strip LSE ----------------
__global__ void k_gemm_lse(const float* __restrict__ P1, const float* __restrict__ A1,
                           const float* __restrict__ P2, const float* __restrict__ A2,
                           float* __restrict__ Pm, float* __restrict__ Ps,
                           float* __restrict__ Diag, int N, float scale) {
  __shared__ float PsS[64][129];
  __shared__ float AsS[64][129];
  constexpr float L2E = 1.44269504f;
  const float* P = blockIdx.z ? P2 : P1;
  const float* A = blockIdx.z ? A2 : A1;
  int bi0 = blockIdx.y * 128, bj0 = blockIdx.x * 128;
  int t = threadIdx.x;
  #pragma unroll
  for (int sct = 0; sct < 8; sct++) {
    int idx4 = t + sct * 256;
    int r = idx4 >> 4, k = (idx4 & 15) << 2;
    int pr = min(bi0 + r, N - 1);
    int ar = min(bj0 + r, N - 1);
    float4 v = *(const float4*)(P + (long)pr * 64 + k);
    PsS[k][r] = v.x; PsS[k + 1][r] = v.y; PsS[k + 2][r] = v.z; PsS[k + 3][r] = v.w;
    float4 w = *(const float4*)(A + (long)ar * 64 + k);
    AsS[k][r] = w.x; AsS[k + 1][r] = w.y; AsS[k + 2][r] = w.z; AsS[k + 3][r] = w.w;
  }
  __syncthreads();
  int tx = t & 15, ty = t >> 4;
  float acc[8][8];
  #pragma unroll
  for (int i = 0; i < 8; i++)
    #pragma unroll
    for (int j = 0; j < 8; j++) acc[i][j] = 0.0f;
  #pragma unroll 4
  for (int k = 0; k < 64; k++) {
    float a[8], b[8];
    #pragma unroll
    for (int i = 0; i < 8; i++) a[i] = PsS[k][ty * 8 + i];
    #pragma unroll
    for (int j = 0; j < 8; j++) b[j] = AsS[k][tx + 16 * j];
    #pragma unroll
    for (int i = 0; i < 8; i++)
      #pragma unroll
      for (int j = 0; j < 8; j++) acc[i][j] = fmaf(a[i], b[j], acc[i][j]);
  }
  bool diagBlk = (blockIdx.x == blockIdx.y);
  #pragma unroll
  for (int i = 0; i < 8; i++) {
    int lrow = ty * 8 + i;
    float xs[8], tm = -1e30f;
    #pragma unroll
    for (int j = 0; j < 8; j++) { xs[j] = acc[i][j] * scale; tm = fmaxf(tm, xs[j]); }
    float tsum = 0.f;
    #pragma unroll
    for (int j = 0; j < 8; j++) tsum += exp2f((xs[j] - tm) * L2E);
    #pragma unroll
    for (int o = 1; o <= 8; o <<= 1) {
      float m2 = __shfl_xor(tm, o, 64), s2 = __shfl_xor(tsum, o, 64);
      float M = fmaxf(tm, m2);
      tsum = tsum * exp2f((tm - M) * L2E) + s2 * exp2f((m2 - M) * L2E);
      tm = M;
    }
    if (tx == 0) {
      size_t o = ((size_t)blockIdx.z * N + bi0 + lrow) * 16 + blockIdx.x;
      Pm[o] = tm; Ps[o] = tsum;
    }
    if (diagBlk && tx == (lrow & 15))
      Diag[(size_t)blockIdx.z * N + bi0 + lrow] = xs[lrow >> 4];
  }
}

__global__ void k_lse_final(const float* __restrict__ Pm, const float* __restrict__ Ps,
                            const float* __restrict__ Diag, int N, float coeff,
                            float* __restrict__ out) {
  constexpr float L2E = 1.44269504f;
  int idx = blockIdx.x * 4 + (threadIdx.x >> 6);
  if (idx >= 2 * N) return;
  int z = idx >= N ? 1 : 0, r = idx - z * N;
  int lane = threadIdx.x & 63;
  float m = -1e30f, s = 0.f;
  if (lane < 16) {
    size_t o = ((size_t)z * N + r) * 16 + lane;
    m = Pm[o]; s = Ps[o];
  }
  #pragma unroll
  for (int o = 8; o >= 1; o >>= 1) {
    float m2 = __shfl_xor(m, o, 64), s2 = __shfl_xor(s, o, 64);
    float M = fmaxf(m, m2);
    s = s * exp2f((m - M) * L2E) + s2 * exp2f((m2 - M) * L2E);
    m = M;
  }
  if (lane == 0) {
    float lse = m + log2f(s) * 0.69314718f;
    unsafeAtomicAdd(&out[1], -(Diag[(size_t)z * N + r] - lse) * coeff);
  }
}

extern "C" void kernel_launch(void* const* d_in, const int* in_sizes, int n_in,
                              void* d_out, int out_size, void* d_ws, size_t ws_size,
                              hipStream_t stream) {
  const int* users   = (const int*)d_in[0];
  const int* bundles = (const int*)d_in[1];
  const int* ui_u    = (const int*)d_in[2];
  const int* ui_i    = (const int*)d_in[3];
  const int* ub_u    = (const int*)d_in[4];
  const int* ub_b    = (const int*)d_in[5];
  const int* bi_b    = (const int*)d_in[6];
  const int* bi_i    = (const int*)d_in[7];
  const float* userF = (const float*)d_in[8];
  const float* bundF = (const float*)d_in[9];
  const float* itemF = (const float*)d_in[10];
  float* out = (float*)d_out;

  const int B    = in_sizes[0];
  const int E_ui = in_sizes[2];
  const int E_ub = in_sizes[4];
  const int E_bi = in_sizes[6];
  const long E_all = 2L * E_ui + 2L * E_ub + E_bi;

  float* ws = (float*)d_ws;
  size_t off = 0;
  auto alloc = [&](size_t nfloat) -> float* {
    float* p = ws + off;
    off += (nfloat + 63) & ~(size_t)63;
    return p;
  };
  unsigned int* X  = (unsigned int*)alloc((size_t)GBI0 * 16);     // fp8
  unsigned int* M1 = (unsigned int*)alloc((size_t)GBI0 * 16);     // fp8
  unsigned short* F2b = (unsigned short*)alloc((size_t)GBI0 * 32);// bf16
  unsigned int* binned = (unsigned int*)alloc((size_t)E_all);     // packed
  int* colv  = (int*)alloc((size_t)E_all + 15 * (size_t)GTOT + 128);
  int* rp    = (int*)alloc(GTOT + 1);
  int* cnt   = (int*)alloc(GTOT + 1);
  float* INV1 = alloc(GTOT);
  float* INV2 = alloc(GTOT);
  float* ILu  = alloc((size_t)B * 64);
  float* BLu  = alloc((size_t)B * 64);
  float* ILb2 = alloc((size_t)B * 128);
  float* BLb2 = alloc((size_t)B * 128);
  float* PN1  = alloc((size_t)B * 64);
  float* AN1  = alloc((size_t)B * 64);
  float* PN2  = alloc((size_t)B * 64);
  float* AN2  = alloc((size_t)B * 64);
  float* Pm   = alloc((size_t)2 * B * 16);
  float* Ps   = alloc((size_t)2 * B * 16);
  float* Diag = alloc((size_t)2 * B);
  int* bCnt  = (int*)alloc(2049);
  int* bBase = (int*)alloc(2049);
  int* bCur  = (int*)alloc(2049);
  int* bsum  = (int*)alloc(256);
  (void)ws_size; (void)n_in; (void)out_size;

  // MACC8 (fp8 item mirror, NIc+1 rows incl. zero dummy) overlays binned
  unsigned int* MACC8 = (unsigned int*)binned;

  // ---- unified bucketed binning + padded CSR ----
  hipMemsetAsync(bCnt, 0, sizeof(int) * NBK, stream);
  k_bcount_all<<<1024, 256, 0, stream>>>(ui_u, ui_i, ub_u, ub_b, bi_b, E_ui, E_ub, E_bi, bCnt);
  k_scan2048<<<1, 512, 0, stream>>>(bCnt, NBK, bBase, bCur);
  k_bin_all<<<1024, 256, 0, stream>>>(ui_u, ui_i, ub_u, ub_b, bi_b, bi_i,
                                      E_ui, E_ub, E_bi, bCur, binned);
  hipMemsetAsync(cnt, 0, sizeof(int) * (GTOT + 1), stream);
  k_rowhist_all<<<NBK, 256, 0, stream>>>(binned, bBase, cnt);
  {
    int scan_n = GTOT + 1;
    int nb1 = (scan_n + 1023) / 1024;
    k_scan_block_pad<<<nb1, 256, 0, stream>>>(cnt, scan_n, rp, bsum);
    k_scan_bsum<<<1, 256, 0, stream>>>(bsum, nb1);
    k_scan_add<<<(scan_n + 255) / 256, 256, 0, stream>>>(rp, scan_n, bsum);
  }
  k_csrfill_all<<<NBK, 256, 0, stream>>>(binned, bBase, rp, colv);

  // ---- propagate (UI + UB merged per layer; fp8 operands) ----
  k_prescale_all<<<(int)(((long)GBI0 * 16 + 255) / 256), 256, 0, stream>>>(cnt, userF, bundF,
                                                                           itemF, X);
  k_spmm_g<<<(GBI0 + 3) / 4, 256, 0, stream>>>(rp, cnt, colv, X, M1, nullptr, INV1,
                                               nullptr, nullptr, nullptr, 0.5f, GBI0);
  // zero MACC dummy row before layer 2 writes the item mirror
  hipMemsetAsync(MACC8 + (size_t)NIc * 16, 0, 64, stream);
  k_spmm_g<<<(GBI0 + 3) / 4, 256, 0, stream>>>(rp, cnt, colv, M1, nullptr, F2b, INV2,
                                               itemF, INV1, MACC8, 1.0f / 3.0f, GBI0);
  k_agg_batch<<<(2 * B + 3) / 4, 256, 0, stream>>>(rp, cnt, colv, MACC8, bundles, 2 * B,
                                                   ILb2, PN2);
  k_batch<<<(4 * B + 3) / 4, 256, 0, stream>>>(users, bundles, userF, bundF, cnt, M1, F2b,
                                               INV1, INV2, B, ILu, BLu, BLb2, PN1, AN1, AN2);

  // ---- losses ----
  hipMemsetAsync(out, 0, 2 * sizeof(float), stream);
  k_bpr<<<(B + 3) / 4, 256, 0, stream>>>(ILu, ILb2, BLu, BLb2, B, out);
  dim3 gg((B + 127) / 128, (B + 127) / 128, 2);
  k_gemm_lse<<<gg, 256, 0, stream>>>(PN1, AN1, PN2, AN2, Pm, Ps, Diag, B, 4.0f);  // 1/C_TEMP
  k_lse_final<<<(2 * B + 3) / 4, 256, 0, stream>>>(Pm, Ps, Diag, B, 0.5f / (float)B, out);
}